// Round 3
// baseline (5007.575 us; speedup 1.0000x reference)
//
#include <hip/hip_runtime.h>

#define NN 100000
#define NE 1600000
#define NG 1000
#define ETOT (NE + NN)

// ---------- feature_fc: h0[N,8] = x[N,4] @ W.T + b ----------
__global__ void k_feat(const float* __restrict__ x, const float* __restrict__ ffw,
                       const float* __restrict__ ffb, float* __restrict__ h0) {
    int n = blockIdx.x * 256 + threadIdx.x;
    if (n >= NN) return;
    float xv[4];
#pragma unroll
    for (int k = 0; k < 4; k++) xv[k] = x[n * 4 + k];
#pragma unroll
    for (int o = 0; o < 8; o++) {
        float a = ffb[o];
#pragma unroll
        for (int k = 0; k < 4; k++) a = fmaf(xv[k], ffw[o * 4 + k], a);
        h0[n * 8 + o] = a;
    }
}

// ---------- h1[N,128] = h0 @ gat1_w.T ----------
__global__ void k_h1(const float* __restrict__ h0, const float* __restrict__ g1w,
                     float* __restrict__ h1) {
    int tid = blockIdx.x * 256 + threadIdx.x;  // N*128 exact
    int n = tid >> 7, j = tid & 127;
    const float* w = g1w + j * 8;
    const float* h = h0 + n * 8;
    float a = 0.f;
#pragma unroll
    for (int k = 0; k < 8; k++) a = fmaf(h[k], w[k], a);
    h1[tid] = a;
}

// ---------- per-node attention coefficients a_s,a_d [N,4] ----------
template <int C>
__global__ void k_att(const float* __restrict__ hbuf, const float* __restrict__ asw,
                      const float* __restrict__ adw, float* __restrict__ as_,
                      float* __restrict__ ad_) {
    int tid = blockIdx.x * 256 + threadIdx.x;
    if (tid >= NN * 4) return;
    int n = tid >> 2, h = tid & 3;
    const float* hp = hbuf + (size_t)n * (4 * C) + h * C;
    const float* ws_ = asw + h * C;
    const float* wd_ = adw + h * C;
    float a = 0.f, d = 0.f;
#pragma unroll
    for (int c = 0; c < C; c++) { a = fmaf(hp[c], ws_[c], a); d = fmaf(hp[c], wd_[c], d); }
    as_[tid] = a; ad_[tid] = d;
}

// ---------- CSR build over dst (self-loops appended) ----------
__global__ void k_count(const int* __restrict__ ei, int* __restrict__ deg) {
    int e = blockIdx.x * 256 + threadIdx.x;
    if (e >= ETOT) return;
    int dst = (e < NE) ? ei[NE + e] : (e - NE);
    atomicAdd(&deg[dst], 1);
}

__global__ void k_scan1(const int* __restrict__ deg, int* __restrict__ offs, int* __restrict__ bsum) {
    __shared__ int s[1024];
    int tid = threadIdx.x;
    int i = blockIdx.x * 1024 + tid;
    int v = (i < NN) ? deg[i] : 0;
    s[tid] = v;
    __syncthreads();
    for (int d = 1; d < 1024; d <<= 1) {
        int t = 0;
        if (tid >= d) t = s[tid - d];
        __syncthreads();
        if (tid >= d) s[tid] += t;
        __syncthreads();
    }
    if (i < NN) offs[i] = s[tid] - v;   // exclusive
    if (tid == 1023) bsum[blockIdx.x] = s[tid];
}

__global__ void k_scan2(int* __restrict__ bsum) {  // 1 block, 128 threads, 98 used
    __shared__ int s[128];
    int tid = threadIdx.x;
    int v = (tid < 98) ? bsum[tid] : 0;
    s[tid] = v;
    __syncthreads();
    for (int d = 1; d < 128; d <<= 1) {
        int t = 0;
        if (tid >= d) t = s[tid - d];
        __syncthreads();
        if (tid >= d) s[tid] += t;
        __syncthreads();
    }
    bsum[tid] = s[tid] - v;  // exclusive
}

__global__ void k_scan3(int* __restrict__ offs, const int* __restrict__ bsum, int* __restrict__ cur) {
    int i = blockIdx.x * 1024 + threadIdx.x;
    if (i < NN) {
        int v = offs[i] + bsum[blockIdx.x];
        offs[i] = v; cur[i] = v;
    }
    if (i == 0) offs[NN] = ETOT;
}

__global__ void k_scatter(const int* __restrict__ ei, int* __restrict__ cur, int* __restrict__ srcs) {
    int e = blockIdx.x * 256 + threadIdx.x;
    if (e >= ETOT) return;
    int src, dst;
    if (e < NE) { src = ei[e]; dst = ei[NE + e]; } else { src = dst = e - NE; }
    int p = atomicAdd(&cur[dst], 1);
    srcs[p] = src;
}

// ---------- GAT softmax-aggregation, one wave per dst node ----------
template <int HC>  // 128 (H=4,C=32) or 64 (H=4,C=16)
__global__ void k_gat_agg(const int* __restrict__ offs, const int* __restrict__ srcs,
                          const float* __restrict__ as_, const float* __restrict__ ad_,
                          const float* __restrict__ hbuf, const float* __restrict__ bias,
                          float* __restrict__ outb) {
    int wid = (blockIdx.x * 256 + threadIdx.x) >> 6;
    int lane = threadIdx.x & 63;
    if (wid >= NN) return;
    int off = offs[wid];
    int deg = offs[wid + 1] - off;
    float adn[4];
#pragma unroll
    for (int h = 0; h < 4; h++) adn[h] = ad_[wid * 4 + h];
    float mx[4] = {-1e30f, -1e30f, -1e30f, -1e30f};
    for (int base = 0; base < deg; base += 64) {
        int i = base + lane;
        if (i < deg) {
            int s = srcs[off + i];
#pragma unroll
            for (int h = 0; h < 4; h++) {
                float e = as_[s * 4 + h] + adn[h];
                e = e > 0.f ? e : 0.2f * e;
                mx[h] = fmaxf(mx[h], e);
            }
        }
    }
#pragma unroll
    for (int h = 0; h < 4; h++)
#pragma unroll
        for (int d = 32; d; d >>= 1) mx[h] = fmaxf(mx[h], __shfl_xor(mx[h], d, 64));
    float sm[4] = {0.f, 0.f, 0.f, 0.f};
    for (int base = 0; base < deg; base += 64) {
        int i = base + lane;
        if (i < deg) {
            int s = srcs[off + i];
#pragma unroll
            for (int h = 0; h < 4; h++) {
                float e = as_[s * 4 + h] + adn[h];
                e = e > 0.f ? e : 0.2f * e;
                sm[h] += __expf(e - mx[h]);
            }
        }
    }
#pragma unroll
    for (int h = 0; h < 4; h++)
#pragma unroll
        for (int d = 32; d; d >>= 1) sm[h] += __shfl_xor(sm[h], d, 64);

    if constexpr (HC == 128) {
        int hA = lane >> 5;
        float mxA = hA ? mx[1] : mx[0], mxB = hA ? mx[3] : mx[2];
        float rdA = 1.f / (hA ? sm[1] : sm[0]), rdB = 1.f / (hA ? sm[3] : sm[2]);
        float adA = hA ? adn[1] : adn[0], adB = hA ? adn[3] : adn[2];
        float acc0 = 0.f, acc1 = 0.f;
        for (int k = 0; k < deg; k++) {
            int s = srcs[off + k];
            float e0 = as_[s * 4 + hA] + adA;       e0 = e0 > 0.f ? e0 : 0.2f * e0;
            float e1 = as_[s * 4 + hA + 2] + adB;   e1 = e1 > 0.f ? e1 : 0.2f * e1;
            float a0 = __expf(e0 - mxA) * rdA;
            float a1 = __expf(e1 - mxB) * rdB;
            const float* hr = hbuf + (size_t)s * 128;
            acc0 = fmaf(a0, hr[lane], acc0);
            acc1 = fmaf(a1, hr[lane + 64], acc1);
        }
        float v0 = acc0 + bias[lane];      v0 = v0 > 0.f ? v0 : 0.01f * v0;
        float v1 = acc1 + bias[lane + 64]; v1 = v1 > 0.f ? v1 : 0.01f * v1;
        outb[(size_t)wid * 128 + lane] = v0;
        outb[(size_t)wid * 128 + lane + 64] = v1;
    } else {
        int hd = lane >> 4;
        float mxA = (hd & 2) ? ((hd & 1) ? mx[3] : mx[2]) : ((hd & 1) ? mx[1] : mx[0]);
        float smA = (hd & 2) ? ((hd & 1) ? sm[3] : sm[2]) : ((hd & 1) ? sm[1] : sm[0]);
        float adA = (hd & 2) ? ((hd & 1) ? adn[3] : adn[2]) : ((hd & 1) ? adn[1] : adn[0]);
        float rdA = 1.f / smA;
        float acc0 = 0.f;
        for (int k = 0; k < deg; k++) {
            int s = srcs[off + k];
            float e0 = as_[s * 4 + hd] + adA; e0 = e0 > 0.f ? e0 : 0.2f * e0;
            float a0 = __expf(e0 - mxA) * rdA;
            acc0 = fmaf(a0, hbuf[(size_t)s * 64 + lane], acc0);
        }
        float v0 = acc0 + bias[lane]; v0 = v0 > 0.f ? v0 : 0.01f * v0;
        outb[(size_t)wid * 64 + lane] = v0;
    }
}

// ---------- h2[N,64] = g1 @ gat2_w.T ----------
__global__ void k_h2(const float* __restrict__ g1, const float* __restrict__ g2w,
                     float* __restrict__ h2) {
    int tid = blockIdx.x * 256 + threadIdx.x;  // N*64 exact
    int n = tid >> 6, j = tid & 63;
    const float* g = g1 + (size_t)n * 128;
    const float* w = g2w + j * 128;
    float a0 = 0.f, a1 = 0.f, a2 = 0.f, a3 = 0.f;
#pragma unroll
    for (int k = 0; k < 32; k++) {
        a0 = fmaf(g[4 * k], w[4 * k], a0);
        a1 = fmaf(g[4 * k + 1], w[4 * k + 1], a1);
        a2 = fmaf(g[4 * k + 2], w[4 * k + 2], a2);
        a3 = fmaf(g[4 * k + 3], w[4 * k + 3], a3);
    }
    h2[tid] = (a0 + a1) + (a2 + a3);
}

// ---------- precompute fused attention M^T (out@v) and bias ----------
__global__ void k_fuse(const float* __restrict__ enc_in_w, const float* __restrict__ enc_in_b,
                       const float* __restrict__ enc_out_w, const float* __restrict__ enc_out_b,
                       const float* __restrict__ sa_in_w, const float* __restrict__ sa_in_b,
                       const float* __restrict__ sa_out_w, const float* __restrict__ sa_out_b,
                       const float* __restrict__ ca_in_w, const float* __restrict__ ca_in_b,
                       const float* __restrict__ ca_out_w, const float* __restrict__ ca_out_b,
                       float* __restrict__ Mt, float* __restrict__ fb) {
    int tid = blockIdx.x * 256 + threadIdx.x;  // 6*64*64 = 24576 exact
    int p = tid >> 12, r = tid & 4095, j = r >> 6, k = r & 63;
    int li = p & 1;
    const float *iw, *ib, *ow, *ob;
    if (p < 2)      { iw = enc_in_w + li * 12288; ib = enc_in_b + li * 192; ow = enc_out_w + li * 4096; ob = enc_out_b + li * 64; }
    else if (p < 4) { iw = sa_in_w + li * 12288;  ib = sa_in_b + li * 192;  ow = sa_out_w + li * 4096;  ob = sa_out_b + li * 64; }
    else            { iw = ca_in_w + li * 12288;  ib = ca_in_b + li * 192;  ow = ca_out_w + li * 4096;  ob = ca_out_b + li * 64; }
    float a = 0.f;
    for (int m = 0; m < 64; m++) a = fmaf(ow[j * 64 + m], iw[(128 + m) * 64 + k], a);
    Mt[p * 4096 + k * 64 + j] = a;
    if (k == 0) {
        float fa = ob[j];
        for (int m = 0; m < 64; m++) fa = fmaf(ow[j * 64 + m], ib[128 + m], fa);
        fb[p * 64 + j] = fa;
    }
}

// ---------- transpose f2: f2t[pl][h*64+j] = f2[pl][j*256+h] ----------
__global__ void k_f2t(const float* __restrict__ enc_f2_w, const float* __restrict__ dec_f2_w,
                      float* __restrict__ f2t) {
    int tid = blockIdx.x * 256 + threadIdx.x;  // 4*16384 = 65536 exact
    int p = tid >> 14, r = tid & 16383;
    int h = r >> 6, j = r & 63;
    const float* src = (p < 2) ? enc_f2_w + p * 16384 : dec_f2_w + (p - 2) * 16384;
    f2t[tid] = src[j * 256 + h];
}

// ---------- transpose f1: f1t[pl][k*256+i] = f1[pl][i*64+k] ----------
__global__ void k_f1t(const float* __restrict__ enc_f1_w, const float* __restrict__ dec_f1_w,
                      float* __restrict__ f1t) {
    int tid = blockIdx.x * 256 + threadIdx.x;  // 4*16384 = 65536 exact
    int p = tid >> 14, r = tid & 16383;
    int k = r >> 8, i = r & 255;
    const float* src = (p < 2) ? enc_f1_w + p * 16384 : dec_f1_w + (p - 2) * 16384;
    f1t[tid] = src[i * 64 + k];
}

// ---------- fused per-node transformer: 4 threads/node, quad-local LDS ----------
struct XP {
    const float* Mt;   const float* fb;   const float* f1t;  const float* f2t;
    const float* ef1b; const float* ef2b; const float* df1b; const float* df2b;
    const float* el1g; const float* el1b; const float* el2g; const float* el2b;
    const float* dl1g; const float* dl1b; const float* dl2g; const float* dl2b;
    const float* dl3g; const float* dl3b;
};

__device__ __forceinline__ void ld16(float* d, const float* s) {
    const float4* p = (const float4*)s;
    float4 a = p[0], b = p[1], c = p[2], e = p[3];
    d[0]=a.x; d[1]=a.y; d[2]=a.z; d[3]=a.w;
    d[4]=b.x; d[5]=b.y; d[6]=b.z; d[7]=b.w;
    d[8]=c.x; d[9]=c.y; d[10]=c.z; d[11]=c.w;
    d[12]=e.x; d[13]=e.y; d[14]=e.z; d[15]=e.w;
}
__device__ __forceinline__ void st16(float* dst, const float* s) {
    float4* d = (float4*)dst;
    d[0] = make_float4(s[0], s[1], s[2], s[3]);
    d[1] = make_float4(s[4], s[5], s[6], s[7]);
    d[2] = make_float4(s[8], s[9], s[10], s[11]);
    d[3] = make_float4(s[12], s[13], s[14], s[15]);
}

// acc[16] += sum_k vec[k] * W[k*LD + j], W pre-offset to this thread's 16 cols
template <int LD>
__device__ __forceinline__ void mv64(float* acc, const float* vec, const float* W) {
#pragma unroll 4
    for (int k = 0; k < 64; k++) {
        float yk = vec[k];
        const float4* w = (const float4*)(W + k * LD);
        float4 a = w[0], b = w[1], c = w[2], d = w[3];
        acc[0]  = fmaf(yk, a.x, acc[0]);  acc[1]  = fmaf(yk, a.y, acc[1]);
        acc[2]  = fmaf(yk, a.z, acc[2]);  acc[3]  = fmaf(yk, a.w, acc[3]);
        acc[4]  = fmaf(yk, b.x, acc[4]);  acc[5]  = fmaf(yk, b.y, acc[5]);
        acc[6]  = fmaf(yk, b.z, acc[6]);  acc[7]  = fmaf(yk, b.w, acc[7]);
        acc[8]  = fmaf(yk, c.x, acc[8]);  acc[9]  = fmaf(yk, c.y, acc[9]);
        acc[10] = fmaf(yk, c.z, acc[10]); acc[11] = fmaf(yk, c.w, acc[11]);
        acc[12] = fmaf(yk, d.x, acc[12]); acc[13] = fmaf(yk, d.y, acc[13]);
        acc[14] = fmaf(yk, d.z, acc[14]); acc[15] = fmaf(yk, d.w, acc[15]);
    }
}

__device__ __forceinline__ void lnq(float* y, const float* g, const float* b) {
    float s = 0.f;
#pragma unroll
    for (int j = 0; j < 16; j++) s += y[j];
    s += __shfl_xor(s, 1, 64); s += __shfl_xor(s, 2, 64);
    float m = s * 0.015625f;
    float v = 0.f;
#pragma unroll
    for (int j = 0; j < 16; j++) { float d = y[j] - m; v = fmaf(d, d, v); }
    v += __shfl_xor(v, 1, 64); v += __shfl_xor(v, 2, 64);
    float r = rsqrtf(fmaf(v, 0.015625f, 1e-5f));
    float gg[16], bb[16];
    ld16(gg, g); ld16(bb, b);
#pragma unroll
    for (int j = 0; j < 16; j++) y[j] = fmaf((y[j] - m) * r, gg[j], bb[j]);
}

__global__ __launch_bounds__(256, 4) void k_xform(float* __restrict__ yio, XP P) {
    __shared__ float ys[64 * 68];
    __shared__ float hs[64 * 68];
    int t = threadIdx.x;
    int nl = t >> 2, q = t & 3;
    int node = blockIdx.x * 64 + nl;
    if (node >= NN) return;    // no __syncthreads anywhere: quad-local LDS only
    const int qb = q * 16;
    float* ysn = ys + nl * 68;
    float* hsn = hs + nl * 68;
    float y[16];
    ld16(y, yio + (size_t)node * 64 + qb);
    st16(ysn + qb, y);
#pragma unroll 1
    for (int layer = 0; layer < 4; layer++) {
        const bool enc = layer < 2;
        const int li = enc ? layer : layer - 2;
        const int nat = enc ? 1 : 2;
#pragma unroll 1
        for (int at = 0; at < nat; at++) {
            int p = enc ? layer : (at == 0 ? 2 + li : 4 + li);
            float acc[16];
            ld16(acc, P.fb + p * 64 + qb);
            mv64<64>(acc, ysn, P.Mt + p * 4096 + qb);
#pragma unroll
            for (int j = 0; j < 16; j++) y[j] += acc[j];
            const float *g, *b;
            if (enc)          { g = P.el1g + li * 64; b = P.el1b + li * 64; }
            else if (at == 0) { g = P.dl1g + li * 64; b = P.dl1b + li * 64; }
            else              { g = P.dl2g + li * 64; b = P.dl2b + li * 64; }
            lnq(y, g + qb, b + qb);
            st16(ysn + qb, y);
        }
        const int pl = enc ? layer : 2 + li;
        const float* f1tp = P.f1t + pl * 16384;
        const float* f1bp = (enc ? P.ef1b : P.df1b) + li * 256;
        const float* f2tp = P.f2t + pl * 16384;
        const float* f2bp = (enc ? P.ef2b : P.df2b) + li * 64;
        float acc[16];
        ld16(acc, f2bp + qb);
#pragma unroll 1
        for (int c = 0; c < 4; c++) {
            float h[16];
            ld16(h, f1bp + c * 64 + qb);
            mv64<256>(h, ysn, f1tp + c * 64 + qb);
#pragma unroll
            for (int m = 0; m < 16; m++) h[m] = fmaxf(h[m], 0.f);
            st16(hsn + qb, h);
            mv64<64>(acc, hsn, f2tp + c * 4096 + qb);
        }
#pragma unroll
        for (int j = 0; j < 16; j++) y[j] += acc[j];
        const float* g2 = (enc ? P.el2g : P.dl3g) + li * 64;
        const float* b2 = (enc ? P.el2b : P.dl3b) + li * 64;
        lnq(y, g2 + qb, b2 + qb);
        st16(ysn + qb, y);
    }
    st16(yio + (size_t)node * 64 + qb, y);
}

// ---------- global mean pool: one block per graph ----------
__global__ void k_pool(const float* __restrict__ y, const int* __restrict__ batch,
                       float* __restrict__ pooled) {
    int b = blockIdx.x;
    int t = threadIdx.x;
    int ch = t & 63, r = t >> 6;
    int lo = 0, hi = NN;
    while (lo < hi) { int mid = (lo + hi) >> 1; if (batch[mid] < b) lo = mid + 1; else hi = mid; }
    int st = lo;
    hi = NN;
    while (lo < hi) { int mid = (lo + hi) >> 1; if (batch[mid] < b + 1) lo = mid + 1; else hi = mid; }
    int en = lo;
    float s = 0.f;
    for (int i = st + r; i < en; i += 4) s += y[(size_t)i * 64 + ch];
    __shared__ float red[256];
    red[t] = s;
    __syncthreads();
    if (t < 64) {
        float tot = red[t] + red[t + 64] + red[t + 128] + red[t + 192];
        int cnt = en - st; if (cnt < 1) cnt = 1;
        pooled[b * 64 + t] = tot / (float)cnt;
    }
}

// ---------- final fc: out[G,33] = pooled @ fc_w.T + fc_b ----------
__global__ void k_fc(const float* __restrict__ pooled, const float* __restrict__ fcw,
                     const float* __restrict__ fcb, float* __restrict__ out) {
    int tid = blockIdx.x * 256 + threadIdx.x;
    if (tid >= NG * 33) return;
    int g = tid / 33, o = tid - g * 33;
    const float* p = pooled + g * 64;
    const float* w = fcw + o * 64;
    float a0 = 0.f, a1 = 0.f, a2 = 0.f, a3 = 0.f;
#pragma unroll
    for (int k = 0; k < 16; k++) {
        a0 = fmaf(p[4 * k], w[4 * k], a0);
        a1 = fmaf(p[4 * k + 1], w[4 * k + 1], a1);
        a2 = fmaf(p[4 * k + 2], w[4 * k + 2], a2);
        a3 = fmaf(p[4 * k + 3], w[4 * k + 3], a3);
    }
    out[tid] = fcb[o] + (a0 + a1) + (a2 + a3);
}

extern "C" void kernel_launch(void* const* d_in, const int* in_sizes, int n_in,
                              void* d_out, int out_size, void* d_ws, size_t ws_size,
                              hipStream_t stream) {
    (void)in_sizes; (void)n_in; (void)out_size; (void)ws_size;
    char* ws = (char*)d_ws;
    size_t o = 0;
    auto A = [&](size_t b) { size_t r = o; o += (b + 255) & ~(size_t)255; return r; };
    float* f_h0  = (float*)(ws + A((size_t)NN * 8 * 4));
    float* f_h1  = (float*)(ws + A((size_t)NN * 128 * 4));  // reused as h2 ([N,64])
    float* f_as1 = (float*)(ws + A((size_t)NN * 4 * 4));
    float* f_ad1 = (float*)(ws + A((size_t)NN * 4 * 4));
    float* f_as2 = (float*)(ws + A((size_t)NN * 4 * 4));
    float* f_ad2 = (float*)(ws + A((size_t)NN * 4 * 4));
    float* f_g1  = (float*)(ws + A((size_t)NN * 128 * 4));  // reused as g2out / y ([N,64])
    int* i_off   = (int*)(ws + A((size_t)(NN + 1) * 4));
    int* i_cur   = (int*)(ws + A((size_t)NN * 4));
    int* i_deg   = (int*)(ws + A((size_t)NN * 4));
    int* i_bsum  = (int*)(ws + A((size_t)1024 * 4));
    int* i_srcs  = (int*)(ws + A((size_t)ETOT * 4));
    float* f_Mt  = (float*)(ws + A((size_t)6 * 4096 * 4));
    float* f_fb  = (float*)(ws + A((size_t)6 * 64 * 4));
    float* f_f1t = (float*)(ws + A((size_t)4 * 16384 * 4));
    float* f_f2t = (float*)(ws + A((size_t)4 * 16384 * 4));
    float* f_pool= (float*)(ws + A((size_t)NG * 64 * 4));

    const float* x   = (const float*)d_in[0];
    const int* ei    = (const int*)d_in[1];
    const int* batch = (const int*)d_in[2];
    #define F32(i) ((const float*)d_in[i])

    hipMemsetAsync(i_deg, 0, (size_t)NN * 4, stream);
    k_feat<<<(NN + 255) / 256, 256, 0, stream>>>(x, F32(3), F32(4), f_h0);
    k_h1<<<NN * 128 / 256, 256, 0, stream>>>(f_h0, F32(5), f_h1);
    k_att<32><<<(NN * 4 + 255) / 256, 256, 0, stream>>>(f_h1, F32(6), F32(7), f_as1, f_ad1);
    k_count<<<(ETOT + 255) / 256, 256, 0, stream>>>(ei, i_deg);
    k_scan1<<<98, 1024, 0, stream>>>(i_deg, i_off, i_bsum);
    k_scan2<<<1, 128, 0, stream>>>(i_bsum);
    k_scan3<<<98, 1024, 0, stream>>>(i_off, i_bsum, i_cur);
    k_scatter<<<(ETOT + 255) / 256, 256, 0, stream>>>(ei, i_cur, i_srcs);
    k_gat_agg<128><<<NN * 64 / 256, 256, 0, stream>>>(i_off, i_srcs, f_as1, f_ad1, f_h1, F32(8), f_g1);
    k_h2<<<NN * 64 / 256, 256, 0, stream>>>(f_g1, F32(9), f_h1);  // h2 -> f_h1
    k_att<16><<<(NN * 4 + 255) / 256, 256, 0, stream>>>(f_h1, F32(10), F32(11), f_as2, f_ad2);
    k_gat_agg<64><<<NN * 64 / 256, 256, 0, stream>>>(i_off, i_srcs, f_as2, f_ad2, f_h1, F32(12), f_g1);
    k_fuse<<<24576 / 256, 256, 0, stream>>>(F32(13), F32(14), F32(15), F32(16),
                                            F32(25), F32(26), F32(27), F32(28),
                                            F32(29), F32(30), F32(31), F32(32),
                                            f_Mt, f_fb);
    k_f1t<<<65536 / 256, 256, 0, stream>>>(F32(17), F32(33), f_f1t);
    k_f2t<<<65536 / 256, 256, 0, stream>>>(F32(19), F32(35), f_f2t);
    XP P;
    P.Mt = f_Mt; P.fb = f_fb; P.f1t = f_f1t; P.f2t = f_f2t;
    P.ef1b = F32(18); P.ef2b = F32(20);
    P.df1b = F32(34); P.df2b = F32(36);
    P.el1g = F32(21); P.el1b = F32(22); P.el2g = F32(23); P.el2b = F32(24);
    P.dl1g = F32(37); P.dl1b = F32(38); P.dl2g = F32(39); P.dl2b = F32(40);
    P.dl3g = F32(41); P.dl3b = F32(42);
    k_xform<<<(NN + 63) / 64, 256, 0, stream>>>(f_g1, P);
    k_pool<<<NG, 256, 0, stream>>>(f_g1, batch, f_pool);
    k_fc<<<(NG * 33 + 255) / 256, 256, 0, stream>>>(f_pool, F32(43), F32(44), (float*)d_out);
    #undef F32
}

// Round 4
// 2832.698 us; speedup vs baseline: 1.7678x; 1.7678x over previous
//
#include <hip/hip_runtime.h>

#define NN 100000
#define NE 1600000
#define NG 1000
#define ETOT (NE + NN)

// ---------- feature_fc: h0[N,8] = x[N,4] @ W.T + b ----------
__global__ void k_feat(const float* __restrict__ x, const float* __restrict__ ffw,
                       const float* __restrict__ ffb, float* __restrict__ h0) {
    int n = blockIdx.x * 256 + threadIdx.x;
    if (n >= NN) return;
    float xv[4];
#pragma unroll
    for (int k = 0; k < 4; k++) xv[k] = x[n * 4 + k];
#pragma unroll
    for (int o = 0; o < 8; o++) {
        float a = ffb[o];
#pragma unroll
        for (int k = 0; k < 4; k++) a = fmaf(xv[k], ffw[o * 4 + k], a);
        h0[n * 8 + o] = a;
    }
}

// ---------- h1[N,128] = h0 @ gat1_w.T ----------
__global__ void k_h1(const float* __restrict__ h0, const float* __restrict__ g1w,
                     float* __restrict__ h1) {
    int tid = blockIdx.x * 256 + threadIdx.x;  // N*128 exact
    int n = tid >> 7, j = tid & 127;
    const float* w = g1w + j * 8;
    const float* h = h0 + n * 8;
    float a = 0.f;
#pragma unroll
    for (int k = 0; k < 8; k++) a = fmaf(h[k], w[k], a);
    h1[tid] = a;
}

// ---------- per-node attention coefficients a_s,a_d [N,4] ----------
template <int C>
__global__ void k_att(const float* __restrict__ hbuf, const float* __restrict__ asw,
                      const float* __restrict__ adw, float* __restrict__ as_,
                      float* __restrict__ ad_) {
    int tid = blockIdx.x * 256 + threadIdx.x;
    if (tid >= NN * 4) return;
    int n = tid >> 2, h = tid & 3;
    const float* hp = hbuf + (size_t)n * (4 * C) + h * C;
    const float* ws_ = asw + h * C;
    const float* wd_ = adw + h * C;
    float a = 0.f, d = 0.f;
#pragma unroll
    for (int c = 0; c < C; c++) { a = fmaf(hp[c], ws_[c], a); d = fmaf(hp[c], wd_[c], d); }
    as_[tid] = a; ad_[tid] = d;
}

// ---------- CSR build over dst (self-loops appended) ----------
__global__ void k_count(const int* __restrict__ ei, int* __restrict__ deg) {
    int e = blockIdx.x * 256 + threadIdx.x;
    if (e >= ETOT) return;
    int dst = (e < NE) ? ei[NE + e] : (e - NE);
    atomicAdd(&deg[dst], 1);
}

__global__ void k_scan1(const int* __restrict__ deg, int* __restrict__ offs, int* __restrict__ bsum) {
    __shared__ int s[1024];
    int tid = threadIdx.x;
    int i = blockIdx.x * 1024 + tid;
    int v = (i < NN) ? deg[i] : 0;
    s[tid] = v;
    __syncthreads();
    for (int d = 1; d < 1024; d <<= 1) {
        int t = 0;
        if (tid >= d) t = s[tid - d];
        __syncthreads();
        if (tid >= d) s[tid] += t;
        __syncthreads();
    }
    if (i < NN) offs[i] = s[tid] - v;   // exclusive
    if (tid == 1023) bsum[blockIdx.x] = s[tid];
}

__global__ void k_scan2(int* __restrict__ bsum) {  // 1 block, 128 threads, 98 used
    __shared__ int s[128];
    int tid = threadIdx.x;
    int v = (tid < 98) ? bsum[tid] : 0;
    s[tid] = v;
    __syncthreads();
    for (int d = 1; d < 128; d <<= 1) {
        int t = 0;
        if (tid >= d) t = s[tid - d];
        __syncthreads();
        if (tid >= d) s[tid] += t;
        __syncthreads();
    }
    bsum[tid] = s[tid] - v;  // exclusive
}

__global__ void k_scan3(int* __restrict__ offs, const int* __restrict__ bsum, int* __restrict__ cur) {
    int i = blockIdx.x * 1024 + threadIdx.x;
    if (i < NN) {
        int v = offs[i] + bsum[blockIdx.x];
        offs[i] = v; cur[i] = v;
    }
    if (i == 0) offs[NN] = ETOT;
}

__global__ void k_scatter(const int* __restrict__ ei, int* __restrict__ cur, int* __restrict__ srcs) {
    int e = blockIdx.x * 256 + threadIdx.x;
    if (e >= ETOT) return;
    int src, dst;
    if (e < NE) { src = ei[e]; dst = ei[NE + e]; } else { src = dst = e - NE; }
    int p = atomicAdd(&cur[dst], 1);
    srcs[p] = src;
}

// ---------- GAT softmax-aggregation, one wave per dst node ----------
template <int HC>  // 128 (H=4,C=32) or 64 (H=4,C=16)
__global__ void k_gat_agg(const int* __restrict__ offs, const int* __restrict__ srcs,
                          const float* __restrict__ as_, const float* __restrict__ ad_,
                          const float* __restrict__ hbuf, const float* __restrict__ bias,
                          float* __restrict__ outb) {
    int wid = (blockIdx.x * 256 + threadIdx.x) >> 6;
    int lane = threadIdx.x & 63;
    if (wid >= NN) return;
    int off = offs[wid];
    int deg = offs[wid + 1] - off;
    float adn[4];
#pragma unroll
    for (int h = 0; h < 4; h++) adn[h] = ad_[wid * 4 + h];
    float mx[4] = {-1e30f, -1e30f, -1e30f, -1e30f};
    for (int base = 0; base < deg; base += 64) {
        int i = base + lane;
        if (i < deg) {
            int s = srcs[off + i];
#pragma unroll
            for (int h = 0; h < 4; h++) {
                float e = as_[s * 4 + h] + adn[h];
                e = e > 0.f ? e : 0.2f * e;
                mx[h] = fmaxf(mx[h], e);
            }
        }
    }
#pragma unroll
    for (int h = 0; h < 4; h++)
#pragma unroll
        for (int d = 32; d; d >>= 1) mx[h] = fmaxf(mx[h], __shfl_xor(mx[h], d, 64));
    float sm[4] = {0.f, 0.f, 0.f, 0.f};
    for (int base = 0; base < deg; base += 64) {
        int i = base + lane;
        if (i < deg) {
            int s = srcs[off + i];
#pragma unroll
            for (int h = 0; h < 4; h++) {
                float e = as_[s * 4 + h] + adn[h];
                e = e > 0.f ? e : 0.2f * e;
                sm[h] += __expf(e - mx[h]);
            }
        }
    }
#pragma unroll
    for (int h = 0; h < 4; h++)
#pragma unroll
        for (int d = 32; d; d >>= 1) sm[h] += __shfl_xor(sm[h], d, 64);

    if constexpr (HC == 128) {
        int hA = lane >> 5;
        float mxA = hA ? mx[1] : mx[0], mxB = hA ? mx[3] : mx[2];
        float rdA = 1.f / (hA ? sm[1] : sm[0]), rdB = 1.f / (hA ? sm[3] : sm[2]);
        float adA = hA ? adn[1] : adn[0], adB = hA ? adn[3] : adn[2];
        float acc0 = 0.f, acc1 = 0.f;
        for (int k = 0; k < deg; k++) {
            int s = srcs[off + k];
            float e0 = as_[s * 4 + hA] + adA;       e0 = e0 > 0.f ? e0 : 0.2f * e0;
            float e1 = as_[s * 4 + hA + 2] + adB;   e1 = e1 > 0.f ? e1 : 0.2f * e1;
            float a0 = __expf(e0 - mxA) * rdA;
            float a1 = __expf(e1 - mxB) * rdB;
            const float* hr = hbuf + (size_t)s * 128;
            acc0 = fmaf(a0, hr[lane], acc0);
            acc1 = fmaf(a1, hr[lane + 64], acc1);
        }
        float v0 = acc0 + bias[lane];      v0 = v0 > 0.f ? v0 : 0.01f * v0;
        float v1 = acc1 + bias[lane + 64]; v1 = v1 > 0.f ? v1 : 0.01f * v1;
        outb[(size_t)wid * 128 + lane] = v0;
        outb[(size_t)wid * 128 + lane + 64] = v1;
    } else {
        int hd = lane >> 4;
        float mxA = (hd & 2) ? ((hd & 1) ? mx[3] : mx[2]) : ((hd & 1) ? mx[1] : mx[0]);
        float smA = (hd & 2) ? ((hd & 1) ? sm[3] : sm[2]) : ((hd & 1) ? sm[1] : sm[0]);
        float adA = (hd & 2) ? ((hd & 1) ? adn[3] : adn[2]) : ((hd & 1) ? adn[1] : adn[0]);
        float rdA = 1.f / smA;
        float acc0 = 0.f;
        for (int k = 0; k < deg; k++) {
            int s = srcs[off + k];
            float e0 = as_[s * 4 + hd] + adA; e0 = e0 > 0.f ? e0 : 0.2f * e0;
            float a0 = __expf(e0 - mxA) * rdA;
            acc0 = fmaf(a0, hbuf[(size_t)s * 64 + lane], acc0);
        }
        float v0 = acc0 + bias[lane]; v0 = v0 > 0.f ? v0 : 0.01f * v0;
        outb[(size_t)wid * 64 + lane] = v0;
    }
}

// ---------- h2[N,64] = g1 @ gat2_w.T ----------
__global__ void k_h2(const float* __restrict__ g1, const float* __restrict__ g2w,
                     float* __restrict__ h2) {
    int tid = blockIdx.x * 256 + threadIdx.x;  // N*64 exact
    int n = tid >> 6, j = tid & 63;
    const float* g = g1 + (size_t)n * 128;
    const float* w = g2w + j * 128;
    float a0 = 0.f, a1 = 0.f, a2 = 0.f, a3 = 0.f;
#pragma unroll
    for (int k = 0; k < 32; k++) {
        a0 = fmaf(g[4 * k], w[4 * k], a0);
        a1 = fmaf(g[4 * k + 1], w[4 * k + 1], a1);
        a2 = fmaf(g[4 * k + 2], w[4 * k + 2], a2);
        a3 = fmaf(g[4 * k + 3], w[4 * k + 3], a3);
    }
    h2[tid] = (a0 + a1) + (a2 + a3);
}

// ---------- precompute fused attention M^T (out@v) and bias ----------
__global__ void k_fuse(const float* __restrict__ enc_in_w, const float* __restrict__ enc_in_b,
                       const float* __restrict__ enc_out_w, const float* __restrict__ enc_out_b,
                       const float* __restrict__ sa_in_w, const float* __restrict__ sa_in_b,
                       const float* __restrict__ sa_out_w, const float* __restrict__ sa_out_b,
                       const float* __restrict__ ca_in_w, const float* __restrict__ ca_in_b,
                       const float* __restrict__ ca_out_w, const float* __restrict__ ca_out_b,
                       float* __restrict__ Mt, float* __restrict__ fb) {
    int tid = blockIdx.x * 256 + threadIdx.x;  // 6*64*64 = 24576 exact
    int p = tid >> 12, r = tid & 4095, j = r >> 6, k = r & 63;
    int li = p & 1;
    const float *iw, *ib, *ow, *ob;
    if (p < 2)      { iw = enc_in_w + li * 12288; ib = enc_in_b + li * 192; ow = enc_out_w + li * 4096; ob = enc_out_b + li * 64; }
    else if (p < 4) { iw = sa_in_w + li * 12288;  ib = sa_in_b + li * 192;  ow = sa_out_w + li * 4096;  ob = sa_out_b + li * 64; }
    else            { iw = ca_in_w + li * 12288;  ib = ca_in_b + li * 192;  ow = ca_out_w + li * 4096;  ob = ca_out_b + li * 64; }
    float a = 0.f;
    for (int m = 0; m < 64; m++) a = fmaf(ow[j * 64 + m], iw[(128 + m) * 64 + k], a);
    Mt[p * 4096 + k * 64 + j] = a;
    if (k == 0) {
        float fa = ob[j];
        for (int m = 0; m < 64; m++) fa = fmaf(ow[j * 64 + m], ib[128 + m], fa);
        fb[p * 64 + j] = fa;
    }
}

// ---------- transpose f2: f2t[pl][h*64+j] = f2[pl][j*256+h] ----------
__global__ void k_f2t(const float* __restrict__ enc_f2_w, const float* __restrict__ dec_f2_w,
                      float* __restrict__ f2t) {
    int tid = blockIdx.x * 256 + threadIdx.x;  // 4*16384 = 65536 exact
    int p = tid >> 14, r = tid & 16383;
    int h = r >> 6, j = r & 63;
    const float* src = (p < 2) ? enc_f2_w + p * 16384 : dec_f2_w + (p - 2) * 16384;
    f2t[tid] = src[j * 256 + h];
}

// ---------- transpose f1: f1t[pl][k*256+i] = f1[pl][i*64+k] ----------
__global__ void k_f1t(const float* __restrict__ enc_f1_w, const float* __restrict__ dec_f1_w,
                      float* __restrict__ f1t) {
    int tid = blockIdx.x * 256 + threadIdx.x;  // 4*16384 = 65536 exact
    int p = tid >> 14, r = tid & 16383;
    int k = r >> 8, i = r & 255;
    const float* src = (p < 2) ? enc_f1_w + p * 16384 : dec_f1_w + (p - 2) * 16384;
    f1t[tid] = src[i * 64 + k];
}

// ---------- fused per-node transformer: 4 WAVES per 64-node group ----------
// wave w owns channels [16w,16w+16) of nodes block*64..block*64+63 (lane = node).
// Weight addresses depend only on w (SGPR via readfirstlane) -> scalar s_load,
// broadcast to all lanes. LDS stride 65 -> (l+k)%32 banks, conflict-free.
struct XP {
    const float* Mt;   const float* fb;   const float* f1t;  const float* f2t;
    const float* ef1b; const float* ef2b; const float* df1b; const float* df2b;
    const float* el1g; const float* el1b; const float* el2g; const float* el2b;
    const float* dl1g; const float* dl1b; const float* dl2g; const float* dl2b;
    const float* dl3g; const float* dl3b;
};

__device__ __forceinline__ void ld16(float* d, const float* s) {
    const float4* p = (const float4*)s;
    float4 a = p[0], b = p[1], c = p[2], e = p[3];
    d[0]=a.x; d[1]=a.y; d[2]=a.z; d[3]=a.w;
    d[4]=b.x; d[5]=b.y; d[6]=b.z; d[7]=b.w;
    d[8]=c.x; d[9]=c.y; d[10]=c.z; d[11]=c.w;
    d[12]=e.x; d[13]=e.y; d[14]=e.z; d[15]=e.w;
}
__device__ __forceinline__ void st16(float* dst, const float* s) {
    float4* d = (float4*)dst;
    d[0] = make_float4(s[0], s[1], s[2], s[3]);
    d[1] = make_float4(s[4], s[5], s[6], s[7]);
    d[2] = make_float4(s[8], s[9], s[10], s[11]);
    d[3] = make_float4(s[12], s[13], s[14], s[15]);
}

// acc[16] += sum_{k=0}^{63} lv[k] * W[k*LD + j]; lv = per-lane LDS row,
// W wave-uniform (s_load + broadcast)
template <int LD>
__device__ __forceinline__ void mvj(float* acc, const float* lv, const float* W) {
#pragma unroll
    for (int k = 0; k < 64; k++) {
        float yk = lv[k];
#pragma unroll
        for (int j = 0; j < 16; j++) acc[j] = fmaf(yk, W[k * LD + j], acc[j]);
    }
}

__device__ __forceinline__ void lnq(float* y, const float* g, const float* b,
                                    float* pS, float* pQ, int w, int l) {
    float s = 0.f, q = 0.f;
#pragma unroll
    for (int j = 0; j < 16; j++) { s += y[j]; q = fmaf(y[j], y[j], q); }
    pS[w * 64 + l] = s; pQ[w * 64 + l] = q;
    __syncthreads();
    float S = (pS[l] + pS[64 + l]) + (pS[128 + l] + pS[192 + l]);
    float Q = (pQ[l] + pQ[64 + l]) + (pQ[128 + l] + pQ[192 + l]);
    float m = S * 0.015625f;
    float v = fmaf(Q, 0.015625f, -m * m);
    float r = rsqrtf(v + 1e-5f);
    float gg[16], bb[16];
    ld16(gg, g); ld16(bb, b);
#pragma unroll
    for (int j = 0; j < 16; j++) y[j] = fmaf((y[j] - m) * r, gg[j], bb[j]);
}

__global__ __launch_bounds__(256, 4) void k_xform(float* __restrict__ yio, XP P) {
    __shared__ float ys[64 * 65];
    __shared__ float hs[64 * 65];
    __shared__ float pS[4 * 64];
    __shared__ float pQ[4 * 64];
    const int t = threadIdx.x;
    const int w = __builtin_amdgcn_readfirstlane(t >> 6);  // wave id, SGPR
    const int l = t & 63;                                  // lane = node-local
    const int cb = w * 16;                                 // channel base (SGPR)
    int node = blockIdx.x * 64 + l;
    const bool valid = node < NN;
    const int nc = valid ? node : NN - 1;
    float* lv = ys + l * 65;
    float* lh = hs + l * 65;
    float y[16];
    ld16(y, yio + (size_t)nc * 64 + cb);
#pragma unroll
    for (int j = 0; j < 16; j++) lv[cb + j] = y[j];
    __syncthreads();
#pragma unroll 1
    for (int layer = 0; layer < 4; layer++) {
        const bool enc = layer < 2;
        const int li = enc ? layer : layer - 2;
        const int nat = enc ? 1 : 2;
#pragma unroll 1
        for (int at = 0; at < nat; at++) {
            int p = enc ? layer : (at == 0 ? 2 + li : 4 + li);
            float acc[16];
            ld16(acc, P.fb + p * 64 + cb);
            mvj<64>(acc, lv, P.Mt + p * 4096 + cb);
#pragma unroll
            for (int j = 0; j < 16; j++) y[j] += acc[j];
            const float *g, *b;
            if (enc)          { g = P.el1g + li * 64; b = P.el1b + li * 64; }
            else if (at == 0) { g = P.dl1g + li * 64; b = P.dl1b + li * 64; }
            else              { g = P.dl2g + li * 64; b = P.dl2b + li * 64; }
            lnq(y, g + cb, b + cb, pS, pQ, w, l);   // has internal barrier
#pragma unroll
            for (int j = 0; j < 16; j++) lv[cb + j] = y[j];
            __syncthreads();
        }
        // FFN 64 -> 256 -> 64, hidden processed in 4 chunks of 64
        const int pl = enc ? layer : 2 + li;
        const float* f1tp = P.f1t + pl * 16384;
        const float* f1bp = (enc ? P.ef1b : P.df1b) + li * 256;
        const float* f2tp = P.f2t + pl * 16384;
        const float* f2bp = (enc ? P.ef2b : P.df2b) + li * 64;
        float acc[16];
        ld16(acc, f2bp + cb);
#pragma unroll 1
        for (int c = 0; c < 4; c++) {
            float h[16];
            ld16(h, f1bp + c * 64 + cb);
            mvj<256>(h, lv, f1tp + c * 64 + cb);
#pragma unroll
            for (int m = 0; m < 16; m++) h[m] = fmaxf(h[m], 0.f);
            __syncthreads();   // prior readers of hs are done
#pragma unroll
            for (int j = 0; j < 16; j++) lh[cb + j] = h[j];
            __syncthreads();   // hs chunk visible to all waves
            mvj<64>(acc, lh, f2tp + c * 4096 + cb);
        }
#pragma unroll
        for (int j = 0; j < 16; j++) y[j] += acc[j];
        const float* g2 = (enc ? P.el2g : P.dl3g) + li * 64;
        const float* b2 = (enc ? P.el2b : P.dl3b) + li * 64;
        lnq(y, g2 + cb, b2 + cb, pS, pQ, w, l);
#pragma unroll
        for (int j = 0; j < 16; j++) lv[cb + j] = y[j];
        __syncthreads();
    }
    if (valid) st16(yio + (size_t)node * 64 + cb, y);
}

// ---------- global mean pool: one block per graph ----------
__global__ void k_pool(const float* __restrict__ y, const int* __restrict__ batch,
                       float* __restrict__ pooled) {
    int b = blockIdx.x;
    int t = threadIdx.x;
    int ch = t & 63, r = t >> 6;
    int lo = 0, hi = NN;
    while (lo < hi) { int mid = (lo + hi) >> 1; if (batch[mid] < b) lo = mid + 1; else hi = mid; }
    int st = lo;
    hi = NN;
    while (lo < hi) { int mid = (lo + hi) >> 1; if (batch[mid] < b + 1) lo = mid + 1; else hi = mid; }
    int en = lo;
    float s = 0.f;
    for (int i = st + r; i < en; i += 4) s += y[(size_t)i * 64 + ch];
    __shared__ float red[256];
    red[t] = s;
    __syncthreads();
    if (t < 64) {
        float tot = red[t] + red[t + 64] + red[t + 128] + red[t + 192];
        int cnt = en - st; if (cnt < 1) cnt = 1;
        pooled[b * 64 + t] = tot / (float)cnt;
    }
}

// ---------- final fc: out[G,33] = pooled @ fc_w.T + fc_b ----------
__global__ void k_fc(const float* __restrict__ pooled, const float* __restrict__ fcw,
                     const float* __restrict__ fcb, float* __restrict__ out) {
    int tid = blockIdx.x * 256 + threadIdx.x;
    if (tid >= NG * 33) return;
    int g = tid / 33, o = tid - g * 33;
    const float* p = pooled + g * 64;
    const float* w = fcw + o * 64;
    float a0 = 0.f, a1 = 0.f, a2 = 0.f, a3 = 0.f;
#pragma unroll
    for (int k = 0; k < 16; k++) {
        a0 = fmaf(p[4 * k], w[4 * k], a0);
        a1 = fmaf(p[4 * k + 1], w[4 * k + 1], a1);
        a2 = fmaf(p[4 * k + 2], w[4 * k + 2], a2);
        a3 = fmaf(p[4 * k + 3], w[4 * k + 3], a3);
    }
    out[tid] = fcb[o] + (a0 + a1) + (a2 + a3);
}

extern "C" void kernel_launch(void* const* d_in, const int* in_sizes, int n_in,
                              void* d_out, int out_size, void* d_ws, size_t ws_size,
                              hipStream_t stream) {
    (void)in_sizes; (void)n_in; (void)out_size; (void)ws_size;
    char* ws = (char*)d_ws;
    size_t o = 0;
    auto A = [&](size_t b) { size_t r = o; o += (b + 255) & ~(size_t)255; return r; };
    float* f_h0  = (float*)(ws + A((size_t)NN * 8 * 4));
    float* f_h1  = (float*)(ws + A((size_t)NN * 128 * 4));  // reused as h2 ([N,64])
    float* f_as1 = (float*)(ws + A((size_t)NN * 4 * 4));
    float* f_ad1 = (float*)(ws + A((size_t)NN * 4 * 4));
    float* f_as2 = (float*)(ws + A((size_t)NN * 4 * 4));
    float* f_ad2 = (float*)(ws + A((size_t)NN * 4 * 4));
    float* f_g1  = (float*)(ws + A((size_t)NN * 128 * 4));  // reused as g2out / y ([N,64])
    int* i_off   = (int*)(ws + A((size_t)(NN + 1) * 4));
    int* i_cur   = (int*)(ws + A((size_t)NN * 4));
    int* i_deg   = (int*)(ws + A((size_t)NN * 4));
    int* i_bsum  = (int*)(ws + A((size_t)1024 * 4));
    int* i_srcs  = (int*)(ws + A((size_t)ETOT * 4));
    float* f_Mt  = (float*)(ws + A((size_t)6 * 4096 * 4));
    float* f_fb  = (float*)(ws + A((size_t)6 * 64 * 4));
    float* f_f1t = (float*)(ws + A((size_t)4 * 16384 * 4));
    float* f_f2t = (float*)(ws + A((size_t)4 * 16384 * 4));
    float* f_pool= (float*)(ws + A((size_t)NG * 64 * 4));

    const float* x   = (const float*)d_in[0];
    const int* ei    = (const int*)d_in[1];
    const int* batch = (const int*)d_in[2];
    #define F32(i) ((const float*)d_in[i])

    hipMemsetAsync(i_deg, 0, (size_t)NN * 4, stream);
    k_feat<<<(NN + 255) / 256, 256, 0, stream>>>(x, F32(3), F32(4), f_h0);
    k_h1<<<NN * 128 / 256, 256, 0, stream>>>(f_h0, F32(5), f_h1);
    k_att<32><<<(NN * 4 + 255) / 256, 256, 0, stream>>>(f_h1, F32(6), F32(7), f_as1, f_ad1);
    k_count<<<(ETOT + 255) / 256, 256, 0, stream>>>(ei, i_deg);
    k_scan1<<<98, 1024, 0, stream>>>(i_deg, i_off, i_bsum);
    k_scan2<<<1, 128, 0, stream>>>(i_bsum);
    k_scan3<<<98, 1024, 0, stream>>>(i_off, i_bsum, i_cur);
    k_scatter<<<(ETOT + 255) / 256, 256, 0, stream>>>(ei, i_cur, i_srcs);
    k_gat_agg<128><<<NN * 64 / 256, 256, 0, stream>>>(i_off, i_srcs, f_as1, f_ad1, f_h1, F32(8), f_g1);
    k_h2<<<NN * 64 / 256, 256, 0, stream>>>(f_g1, F32(9), f_h1);  // h2 -> f_h1
    k_att<16><<<(NN * 4 + 255) / 256, 256, 0, stream>>>(f_h1, F32(10), F32(11), f_as2, f_ad2);
    k_gat_agg<64><<<NN * 64 / 256, 256, 0, stream>>>(i_off, i_srcs, f_as2, f_ad2, f_h1, F32(12), f_g1);
    k_fuse<<<24576 / 256, 256, 0, stream>>>(F32(13), F32(14), F32(15), F32(16),
                                            F32(25), F32(26), F32(27), F32(28),
                                            F32(29), F32(30), F32(31), F32(32),
                                            f_Mt, f_fb);
    k_f1t<<<65536 / 256, 256, 0, stream>>>(F32(17), F32(33), f_f1t);
    k_f2t<<<65536 / 256, 256, 0, stream>>>(F32(19), F32(35), f_f2t);
    XP P;
    P.Mt = f_Mt; P.fb = f_fb; P.f1t = f_f1t; P.f2t = f_f2t;
    P.ef1b = F32(18); P.ef2b = F32(20);
    P.df1b = F32(34); P.df2b = F32(36);
    P.el1g = F32(21); P.el1b = F32(22); P.el2g = F32(23); P.el2b = F32(24);
    P.dl1g = F32(37); P.dl1b = F32(38); P.dl2g = F32(39); P.dl2b = F32(40);
    P.dl3g = F32(41); P.dl3b = F32(42);
    k_xform<<<(NN + 63) / 64, 256, 0, stream>>>(f_g1, P);
    k_pool<<<NG, 256, 0, stream>>>(f_g1, batch, f_pool);
    k_fc<<<(NG * 33 + 255) / 256, 256, 0, stream>>>(f_pool, F32(43), F32(44), (float*)d_out);
    #undef F32
}

// Round 5
// 1353.402 us; speedup vs baseline: 3.7000x; 2.0930x over previous
//
#include <hip/hip_runtime.h>

#define NN 100000
#define NE 1600000
#define NG 1000
#define ETOT (NE + NN)

typedef _Float16 f16x8 __attribute__((ext_vector_type(8)));
typedef _Float16 f16x4 __attribute__((ext_vector_type(4)));
typedef float f32x16 __attribute__((ext_vector_type(16)));
#define XROW 72  // LDS row stride in halves (144B: 16B-aligned, 4-way worst conflicts)

// ---------- feature_fc ----------
__global__ void k_feat(const float* __restrict__ x, const float* __restrict__ ffw,
                       const float* __restrict__ ffb, float* __restrict__ h0) {
    int n = blockIdx.x * 256 + threadIdx.x;
    if (n >= NN) return;
    float xv[4];
#pragma unroll
    for (int k = 0; k < 4; k++) xv[k] = x[n * 4 + k];
#pragma unroll
    for (int o = 0; o < 8; o++) {
        float a = ffb[o];
#pragma unroll
        for (int k = 0; k < 4; k++) a = fmaf(xv[k], ffw[o * 4 + k], a);
        h0[n * 8 + o] = a;
    }
}

// ---------- h1[N,128] = h0 @ gat1_w.T ----------
__global__ void k_h1(const float* __restrict__ h0, const float* __restrict__ g1w,
                     float* __restrict__ h1) {
    int tid = blockIdx.x * 256 + threadIdx.x;
    int n = tid >> 7, j = tid & 127;
    const float* w = g1w + j * 8;
    const float* h = h0 + n * 8;
    float a = 0.f;
#pragma unroll
    for (int k = 0; k < 8; k++) a = fmaf(h[k], w[k], a);
    h1[tid] = a;
}

// ---------- per-node attention coefficients ----------
template <int C>
__global__ void k_att(const float* __restrict__ hbuf, const float* __restrict__ asw,
                      const float* __restrict__ adw, float* __restrict__ as_,
                      float* __restrict__ ad_) {
    int tid = blockIdx.x * 256 + threadIdx.x;
    if (tid >= NN * 4) return;
    int n = tid >> 2, h = tid & 3;
    const float* hp = hbuf + (size_t)n * (4 * C) + h * C;
    const float* ws_ = asw + h * C;
    const float* wd_ = adw + h * C;
    float a = 0.f, d = 0.f;
#pragma unroll
    for (int c = 0; c < C; c++) { a = fmaf(hp[c], ws_[c], a); d = fmaf(hp[c], wd_[c], d); }
    as_[tid] = a; ad_[tid] = d;
}

// ---------- CSR build ----------
__global__ void k_count(const int* __restrict__ ei, int* __restrict__ deg) {
    int e = blockIdx.x * 256 + threadIdx.x;
    if (e >= ETOT) return;
    int dst = (e < NE) ? ei[NE + e] : (e - NE);
    atomicAdd(&deg[dst], 1);
}

__global__ void k_scan1(const int* __restrict__ deg, int* __restrict__ offs, int* __restrict__ bsum) {
    __shared__ int s[1024];
    int tid = threadIdx.x;
    int i = blockIdx.x * 1024 + tid;
    int v = (i < NN) ? deg[i] : 0;
    s[tid] = v;
    __syncthreads();
    for (int d = 1; d < 1024; d <<= 1) {
        int t = 0;
        if (tid >= d) t = s[tid - d];
        __syncthreads();
        if (tid >= d) s[tid] += t;
        __syncthreads();
    }
    if (i < NN) offs[i] = s[tid] - v;
    if (tid == 1023) bsum[blockIdx.x] = s[tid];
}

__global__ void k_scan2(int* __restrict__ bsum) {
    __shared__ int s[128];
    int tid = threadIdx.x;
    int v = (tid < 98) ? bsum[tid] : 0;
    s[tid] = v;
    __syncthreads();
    for (int d = 1; d < 128; d <<= 1) {
        int t = 0;
        if (tid >= d) t = s[tid - d];
        __syncthreads();
        if (tid >= d) s[tid] += t;
        __syncthreads();
    }
    bsum[tid] = s[tid] - v;
}

__global__ void k_scan3(int* __restrict__ offs, const int* __restrict__ bsum, int* __restrict__ cur) {
    int i = blockIdx.x * 1024 + threadIdx.x;
    if (i < NN) {
        int v = offs[i] + bsum[blockIdx.x];
        offs[i] = v; cur[i] = v;
    }
    if (i == 0) offs[NN] = ETOT;
}

__global__ void k_scatter(const int* __restrict__ ei, int* __restrict__ cur, int* __restrict__ srcs) {
    int e = blockIdx.x * 256 + threadIdx.x;
    if (e >= ETOT) return;
    int src, dst;
    if (e < NE) { src = ei[e]; dst = ei[NE + e]; } else { src = dst = e - NE; }
    int p = atomicAdd(&cur[dst], 1);
    srcs[p] = src;
}

// ---------- GAT softmax-aggregation, one wave per dst node ----------
template <int HC>
__global__ void k_gat_agg(const int* __restrict__ offs, const int* __restrict__ srcs,
                          const float* __restrict__ as_, const float* __restrict__ ad_,
                          const float* __restrict__ hbuf, const float* __restrict__ bias,
                          float* __restrict__ outb) {
    int wid = (blockIdx.x * 256 + threadIdx.x) >> 6;
    int lane = threadIdx.x & 63;
    if (wid >= NN) return;
    int off = offs[wid];
    int deg = offs[wid + 1] - off;
    float adn[4];
#pragma unroll
    for (int h = 0; h < 4; h++) adn[h] = ad_[wid * 4 + h];
    float mx[4] = {-1e30f, -1e30f, -1e30f, -1e30f};
    for (int base = 0; base < deg; base += 64) {
        int i = base + lane;
        if (i < deg) {
            int s = srcs[off + i];
#pragma unroll
            for (int h = 0; h < 4; h++) {
                float e = as_[s * 4 + h] + adn[h];
                e = e > 0.f ? e : 0.2f * e;
                mx[h] = fmaxf(mx[h], e);
            }
        }
    }
#pragma unroll
    for (int h = 0; h < 4; h++)
#pragma unroll
        for (int d = 32; d; d >>= 1) mx[h] = fmaxf(mx[h], __shfl_xor(mx[h], d, 64));
    float sm[4] = {0.f, 0.f, 0.f, 0.f};
    for (int base = 0; base < deg; base += 64) {
        int i = base + lane;
        if (i < deg) {
            int s = srcs[off + i];
#pragma unroll
            for (int h = 0; h < 4; h++) {
                float e = as_[s * 4 + h] + adn[h];
                e = e > 0.f ? e : 0.2f * e;
                sm[h] += __expf(e - mx[h]);
            }
        }
    }
#pragma unroll
    for (int h = 0; h < 4; h++)
#pragma unroll
        for (int d = 32; d; d >>= 1) sm[h] += __shfl_xor(sm[h], d, 64);

    if constexpr (HC == 128) {
        int hA = lane >> 5;
        float mxA = hA ? mx[1] : mx[0], mxB = hA ? mx[3] : mx[2];
        float rdA = 1.f / (hA ? sm[1] : sm[0]), rdB = 1.f / (hA ? sm[3] : sm[2]);
        float adA = hA ? adn[1] : adn[0], adB = hA ? adn[3] : adn[2];
        float acc0 = 0.f, acc1 = 0.f;
        for (int k = 0; k < deg; k++) {
            int s = srcs[off + k];
            float e0 = as_[s * 4 + hA] + adA;       e0 = e0 > 0.f ? e0 : 0.2f * e0;
            float e1 = as_[s * 4 + hA + 2] + adB;   e1 = e1 > 0.f ? e1 : 0.2f * e1;
            float a0 = __expf(e0 - mxA) * rdA;
            float a1 = __expf(e1 - mxB) * rdB;
            const float* hr = hbuf + (size_t)s * 128;
            acc0 = fmaf(a0, hr[lane], acc0);
            acc1 = fmaf(a1, hr[lane + 64], acc1);
        }
        float v0 = acc0 + bias[lane];      v0 = v0 > 0.f ? v0 : 0.01f * v0;
        float v1 = acc1 + bias[lane + 64]; v1 = v1 > 0.f ? v1 : 0.01f * v1;
        outb[(size_t)wid * 128 + lane] = v0;
        outb[(size_t)wid * 128 + lane + 64] = v1;
    } else {
        int hd = lane >> 4;
        float mxA = (hd & 2) ? ((hd & 1) ? mx[3] : mx[2]) : ((hd & 1) ? mx[1] : mx[0]);
        float smA = (hd & 2) ? ((hd & 1) ? sm[3] : sm[2]) : ((hd & 1) ? sm[1] : sm[0]);
        float adA = (hd & 2) ? ((hd & 1) ? adn[3] : adn[2]) : ((hd & 1) ? adn[1] : adn[0]);
        float rdA = 1.f / smA;
        float acc0 = 0.f;
        for (int k = 0; k < deg; k++) {
            int s = srcs[off + k];
            float e0 = as_[s * 4 + hd] + adA; e0 = e0 > 0.f ? e0 : 0.2f * e0;
            float a0 = __expf(e0 - mxA) * rdA;
            acc0 = fmaf(a0, hbuf[(size_t)s * 64 + lane], acc0);
        }
        float v0 = acc0 + bias[lane]; v0 = v0 > 0.f ? v0 : 0.01f * v0;
        outb[(size_t)wid * 64 + lane] = v0;
    }
}

// ---------- h2[N,64] = g1 @ gat2_w.T ----------
__global__ void k_h2(const float* __restrict__ g1, const float* __restrict__ g2w,
                     float* __restrict__ h2) {
    int tid = blockIdx.x * 256 + threadIdx.x;
    int n = tid >> 6, j = tid & 63;
    const float* g = g1 + (size_t)n * 128;
    const float* w = g2w + j * 128;
    float a0 = 0.f, a1 = 0.f, a2 = 0.f, a3 = 0.f;
#pragma unroll
    for (int k = 0; k < 32; k++) {
        a0 = fmaf(g[4 * k], w[4 * k], a0);
        a1 = fmaf(g[4 * k + 1], w[4 * k + 1], a1);
        a2 = fmaf(g[4 * k + 2], w[4 * k + 2], a2);
        a3 = fmaf(g[4 * k + 3], w[4 * k + 3], a3);
    }
    h2[tid] = (a0 + a1) + (a2 + a3);
}

// ---------- fused attention Mt[k][j] (fp32) + fused bias ----------
__global__ void k_fuse(const float* __restrict__ enc_in_w, const float* __restrict__ enc_in_b,
                       const float* __restrict__ enc_out_w, const float* __restrict__ enc_out_b,
                       const float* __restrict__ sa_in_w, const float* __restrict__ sa_in_b,
                       const float* __restrict__ sa_out_w, const float* __restrict__ sa_out_b,
                       const float* __restrict__ ca_in_w, const float* __restrict__ ca_in_b,
                       const float* __restrict__ ca_out_w, const float* __restrict__ ca_out_b,
                       float* __restrict__ Mt, float* __restrict__ fb) {
    int tid = blockIdx.x * 256 + threadIdx.x;
    int p = tid >> 12, r = tid & 4095, j = r >> 6, k = r & 63;
    int li = p & 1;
    const float *iw, *ib, *ow, *ob;
    if (p < 2)      { iw = enc_in_w + li * 12288; ib = enc_in_b + li * 192; ow = enc_out_w + li * 4096; ob = enc_out_b + li * 64; }
    else if (p < 4) { iw = sa_in_w + li * 12288;  ib = sa_in_b + li * 192;  ow = sa_out_w + li * 4096;  ob = sa_out_b + li * 64; }
    else            { iw = ca_in_w + li * 12288;  ib = ca_in_b + li * 192;  ow = ca_out_w + li * 4096;  ob = ca_out_b + li * 64; }
    float a = 0.f;
    for (int m = 0; m < 64; m++) a = fmaf(ow[j * 64 + m], iw[(128 + m) * 64 + k], a);
    Mt[p * 4096 + k * 64 + j] = a;
    if (k == 0) {
        float fa = ob[j];
        for (int m = 0; m < 64; m++) fa = fmaf(ow[j * 64 + m], ib[128 + m], fa);
        fb[p * 64 + j] = fa;
    }
}

// ---------- transpose f2: f2t[pl][h*64+j] ----------
__global__ void k_f2t(const float* __restrict__ enc_f2_w, const float* __restrict__ dec_f2_w,
                      float* __restrict__ f2t) {
    int tid = blockIdx.x * 256 + threadIdx.x;
    int p = tid >> 14, r = tid & 16383;
    int h = r >> 6, j = r & 63;
    const float* src = (p < 2) ? enc_f2_w + p * 16384 : dec_f2_w + (p - 2) * 16384;
    f2t[tid] = src[j * 256 + h];
}

// ---------- transpose f1: f1t[pl][k*256+i] ----------
__global__ void k_f1t(const float* __restrict__ enc_f1_w, const float* __restrict__ dec_f1_w,
                      float* __restrict__ f1t) {
    int tid = blockIdx.x * 256 + threadIdx.x;
    int p = tid >> 14, r = tid & 16383;
    int k = r >> 8, i = r & 255;
    const float* src = (p < 2) ? enc_f1_w + p * 16384 : dec_f1_w + (p - 2) * 16384;
    f1t[tid] = src[i * 64 + k];
}

// ---------- pack all transformer weights into fp16 MFMA A-fragment order ----------
// A-frag (32x32x16 f16): lane l holds A[m][k], m = mt*32+(l&31), k = ks*16+(l>>5)*8+d.
// attn (6 stages, 64x64):   dst p*4096    + ((mt*4+ks)*64+l)*8+d   src Mt[p][k*64+m]
// f1   (4 stages, 256x64):  dst F1+pl*16384+((mt*4+ks)*64+l)*8+d  src f1t[pl][k*256+m]
// f2   (4 stages, 64x256):  dst F2+pl*16384+((mt*16+ks)*64+l)*8+d src f2t[pl][k*64+m]
#define APK_F1 24576
#define APK_F2 90112
#define APK_TOT 155648
__global__ void k_apack(const float* __restrict__ Mt, const float* __restrict__ f1t,
                        const float* __restrict__ f2t, _Float16* __restrict__ apk) {
    int tid = blockIdx.x * 256 + threadIdx.x;  // 608*256 = 155648 exact
    float v;
    if (tid < APK_F1) {
        int p = tid >> 12, idx = tid & 4095;
        int mt = idx >> 11, ks = (idx >> 9) & 3, l = (idx >> 3) & 63, d = idx & 7;
        int m = mt * 32 + (l & 31), k = ks * 16 + (l >> 5) * 8 + d;
        v = Mt[p * 4096 + k * 64 + m];
    } else if (tid < APK_F2) {
        int r = tid - APK_F1; int pl = r >> 14, idx = r & 16383;
        int mt = idx >> 11, ks = (idx >> 9) & 3, l = (idx >> 3) & 63, d = idx & 7;
        int m = mt * 32 + (l & 31), k = ks * 16 + (l >> 5) * 8 + d;
        v = f1t[pl * 16384 + k * 256 + m];
    } else {
        int r = tid - APK_F2; int pl = r >> 14, idx = r & 16383;
        int mt = idx >> 13, ks = (idx >> 9) & 15, l = (idx >> 3) & 63, d = idx & 7;
        int m = mt * 32 + (l & 31), k = ks * 16 + (l >> 5) * 8 + d;
        v = f2t[pl * 16384 + k * 64 + m];
    }
    apk[tid] = (_Float16)v;
}

// ---------- MFMA transformer: 1 wave = 64 nodes, no barriers ----------
// C orientation: C[ch row][node col]. col=l&31 -> node (per n-tile), row=(r&3)+8*(r>>2)+4*hf.
// B = y fragments from per-wave LDS transpose buffer; A = packed fp16 weights (L1-hot).
struct XQ {
    const _Float16* apk; const float* fb;
    const float* ef1b; const float* ef2b; const float* df1b; const float* df2b;
    const float* el1g; const float* el1b; const float* el2g; const float* el2b;
    const float* dl1g; const float* dl1b; const float* dl2g; const float* dl2b;
    const float* dl3g; const float* dl3b;
};

__device__ __forceinline__ void xstore(_Float16* xw, const float y[4][16], int col, int hf) {
#pragma unroll
    for (int nt = 0; nt < 2; nt++)
#pragma unroll
        for (int mt = 0; mt < 2; mt++)
#pragma unroll
            for (int rg = 0; rg < 4; rg++) {
                f16x4 h4;
#pragma unroll
                for (int i = 0; i < 4; i++) h4[i] = (_Float16)y[mt * 2 + nt][rg * 4 + i];
                *(f16x4*)(xw + (nt * 32 + col) * XROW + mt * 32 + rg * 8 + hf * 4) = h4;
            }
}

__device__ __forceinline__ void loadbf(const _Float16* xw, f16x8 bf[2][4], int col, int hf) {
#pragma unroll
    for (int nt = 0; nt < 2; nt++)
#pragma unroll
        for (int ks = 0; ks < 4; ks++)
            bf[nt][ks] = *(const f16x8*)(xw + (nt * 32 + col) * XROW + ks * 16 + hf * 8);
}

__device__ __forceinline__ void lnw(float y[4][16], const float* g, const float* b, int hf) {
#pragma unroll
    for (int nt = 0; nt < 2; nt++) {
        float s = 0.f, q = 0.f;
#pragma unroll
        for (int mt = 0; mt < 2; mt++)
#pragma unroll
            for (int r = 0; r < 16; r++) { float v = y[mt * 2 + nt][r]; s += v; q = fmaf(v, v, q); }
        s += __shfl_xor(s, 32, 64);
        q += __shfl_xor(q, 32, 64);
        float m = s * 0.015625f;
        float var = fmaf(q, 0.015625f, -m * m);
        float rs = rsqrtf(var + 1e-5f);
#pragma unroll
        for (int mt = 0; mt < 2; mt++)
#pragma unroll
            for (int rg = 0; rg < 4; rg++) {
                float4 g4 = *(const float4*)(g + mt * 32 + rg * 8 + hf * 4);
                float4 b4 = *(const float4*)(b + mt * 32 + rg * 8 + hf * 4);
                float* yp = &y[mt * 2 + nt][rg * 4];
                yp[0] = fmaf((yp[0] - m) * rs, g4.x, b4.x);
                yp[1] = fmaf((yp[1] - m) * rs, g4.y, b4.y);
                yp[2] = fmaf((yp[2] - m) * rs, g4.z, b4.z);
                yp[3] = fmaf((yp[3] - m) * rs, g4.w, b4.w);
            }
    }
}

__global__ __launch_bounds__(256, 2) void k_xform(float* __restrict__ yio, XQ P) {
    __shared__ _Float16 xs[4 * 64 * XROW];
    const int t = threadIdx.x;
    const int w = t >> 6, l = t & 63;
    const int col = l & 31, hf = l >> 5;
    _Float16* xw = xs + w * (64 * XROW);
    const int nb = blockIdx.x * 256 + w * 64;
    const int nn0 = nb + col, nn1 = nb + 32 + col;
    const int nc0 = nn0 < NN ? nn0 : NN - 1;
    const int nc1 = nn1 < NN ? nn1 : NN - 1;

    float y[4][16];
#pragma unroll
    for (int mt = 0; mt < 2; mt++)
#pragma unroll
        for (int nt = 0; nt < 2; nt++) {
            const float* src = yio + (size_t)(nt ? nc1 : nc0) * 64 + mt * 32 + hf * 4;
#pragma unroll
            for (int rg = 0; rg < 4; rg++) {
                float4 v = *(const float4*)(src + rg * 8);
                float* yp = &y[mt * 2 + nt][rg * 4];
                yp[0] = v.x; yp[1] = v.y; yp[2] = v.z; yp[3] = v.w;
            }
        }
    f16x8 bf[2][4];
    xstore(xw, y, col, hf);
    loadbf(xw, bf, col, hf);

#pragma unroll 1
    for (int layer = 0; layer < 4; layer++) {
        const bool enc = layer < 2;
        const int li = enc ? layer : layer - 2;
        const int nat = enc ? 1 : 2;
#pragma unroll 1
        for (int at = 0; at < nat; at++) {
            const int p = enc ? layer : (at == 0 ? 2 + li : 4 + li);
            const _Float16* apA = P.apk + p * 4096;
            const float* fbp = P.fb + p * 64;
            f32x16 acc[4];
#pragma unroll
            for (int mt = 0; mt < 2; mt++) {
                f32x16 a;
#pragma unroll
                for (int rg = 0; rg < 4; rg++) {
                    float4 b4 = *(const float4*)(fbp + mt * 32 + rg * 8 + hf * 4);
                    a[rg * 4 + 0] = b4.x; a[rg * 4 + 1] = b4.y; a[rg * 4 + 2] = b4.z; a[rg * 4 + 3] = b4.w;
                }
                acc[mt * 2 + 0] = a; acc[mt * 2 + 1] = a;
            }
#pragma unroll
            for (int mt = 0; mt < 2; mt++)
#pragma unroll
                for (int ks = 0; ks < 4; ks++) {
                    f16x8 af = *(const f16x8*)(apA + ((mt * 4 + ks) * 64 + l) * 8);
                    acc[mt * 2 + 0] = __builtin_amdgcn_mfma_f32_32x32x16_f16(af, bf[0][ks], acc[mt * 2 + 0], 0, 0, 0);
                    acc[mt * 2 + 1] = __builtin_amdgcn_mfma_f32_32x32x16_f16(af, bf[1][ks], acc[mt * 2 + 1], 0, 0, 0);
                }
#pragma unroll
            for (int ti = 0; ti < 4; ti++)
#pragma unroll
                for (int r = 0; r < 16; r++) y[ti][r] += acc[ti][r];
            const float *g, *b;
            if (enc)          { g = P.el1g + li * 64; b = P.el1b + li * 64; }
            else if (at == 0) { g = P.dl1g + li * 64; b = P.dl1b + li * 64; }
            else              { g = P.dl2g + li * 64; b = P.dl2b + li * 64; }
            lnw(y, g, b, hf);
            xstore(xw, y, col, hf);
            loadbf(xw, bf, col, hf);
        }
        // FFN 64 -> 256 -> 64 in 4 hidden chunks of 64 (LDS buffer reused for h)
        const int pl = enc ? layer : 2 + li;
        const _Float16* apF1 = P.apk + APK_F1 + pl * 16384;
        const _Float16* apF2 = P.apk + APK_F2 + pl * 16384;
        const float* f1bp = (enc ? P.ef1b : P.df1b) + li * 256;
        const float* f2bp = (enc ? P.ef2b : P.df2b) + li * 64;
        f32x16 out[4];
#pragma unroll
        for (int mt = 0; mt < 2; mt++) {
            f32x16 a;
#pragma unroll
            for (int rg = 0; rg < 4; rg++) {
                float4 b4 = *(const float4*)(f2bp + mt * 32 + rg * 8 + hf * 4);
                a[rg * 4 + 0] = b4.x; a[rg * 4 + 1] = b4.y; a[rg * 4 + 2] = b4.z; a[rg * 4 + 3] = b4.w;
            }
            out[mt * 2 + 0] = a; out[mt * 2 + 1] = a;
        }
#pragma unroll 1
        for (int c = 0; c < 4; c++) {
            f32x16 ha[4];
#pragma unroll
            for (int hmt = 0; hmt < 2; hmt++) {
                f32x16 a;
#pragma unroll
                for (int rg = 0; rg < 4; rg++) {
                    float4 b4 = *(const float4*)(f1bp + c * 64 + hmt * 32 + rg * 8 + hf * 4);
                    a[rg * 4 + 0] = b4.x; a[rg * 4 + 1] = b4.y; a[rg * 4 + 2] = b4.z; a[rg * 4 + 3] = b4.w;
                }
                ha[hmt * 2 + 0] = a; ha[hmt * 2 + 1] = a;
            }
#pragma unroll
            for (int hmt = 0; hmt < 2; hmt++)
#pragma unroll
                for (int ks = 0; ks < 4; ks++) {
                    f16x8 af = *(const f16x8*)(apF1 + (((2 * c + hmt) * 4 + ks) * 64 + l) * 8);
                    ha[hmt * 2 + 0] = __builtin_amdgcn_mfma_f32_32x32x16_f16(af, bf[0][ks], ha[hmt * 2 + 0], 0, 0, 0);
                    ha[hmt * 2 + 1] = __builtin_amdgcn_mfma_f32_32x32x16_f16(af, bf[1][ks], ha[hmt * 2 + 1], 0, 0, 0);
                }
            // ReLU + transpose chunk through LDS (overwrites y-copy; bf regs keep y)
#pragma unroll
            for (int nt = 0; nt < 2; nt++)
#pragma unroll
                for (int hmt = 0; hmt < 2; hmt++)
#pragma unroll
                    for (int rg = 0; rg < 4; rg++) {
                        f16x4 h4;
#pragma unroll
                        for (int i = 0; i < 4; i++)
                            h4[i] = (_Float16)fmaxf(ha[hmt * 2 + nt][rg * 4 + i], 0.f);
                        *(f16x4*)(xw + (nt * 32 + col) * XROW + hmt * 32 + rg * 8 + hf * 4) = h4;
                    }
#pragma unroll
            for (int ksl = 0; ksl < 4; ksl++) {
                f16x8 hbf0 = *(const f16x8*)(xw + col * XROW + ksl * 16 + hf * 8);
                f16x8 hbf1 = *(const f16x8*)(xw + (32 + col) * XROW + ksl * 16 + hf * 8);
#pragma unroll
                for (int mt = 0; mt < 2; mt++) {
                    f16x8 af = *(const f16x8*)(apF2 + ((mt * 16 + c * 4 + ksl) * 64 + l) * 8);
                    out[mt * 2 + 0] = __builtin_amdgcn_mfma_f32_32x32x16_f16(af, hbf0, out[mt * 2 + 0], 0, 0, 0);
                    out[mt * 2 + 1] = __builtin_amdgcn_mfma_f32_32x32x16_f16(af, hbf1, out[mt * 2 + 1], 0, 0, 0);
                }
            }
        }
#pragma unroll
        for (int ti = 0; ti < 4; ti++)
#pragma unroll
            for (int r = 0; r < 16; r++) y[ti][r] += out[ti][r];
        const float* g2 = (enc ? P.el2g : P.dl3g) + li * 64;
        const float* b2 = (enc ? P.el2b : P.dl3b) + li * 64;
        lnw(y, g2, b2, hf);
        if (layer < 3) {
            xstore(xw, y, col, hf);
            loadbf(xw, bf, col, hf);
        }
    }
    // store back
#pragma unroll
    for (int mt = 0; mt < 2; mt++)
#pragma unroll
        for (int nt = 0; nt < 2; nt++) {
            int n = nt ? nn1 : nn0;
            if (n < NN) {
                float* dst = yio + (size_t)n * 64 + mt * 32 + hf * 4;
#pragma unroll
                for (int rg = 0; rg < 4; rg++) {
                    const float* yp = &y[mt * 2 + nt][rg * 4];
                    *(float4*)(dst + rg * 8) = make_float4(yp[0], yp[1], yp[2], yp[3]);
                }
            }
        }
}

// ---------- global mean pool ----------
__global__ void k_pool(const float* __restrict__ y, const int* __restrict__ batch,
                       float* __restrict__ pooled) {
    int b = blockIdx.x;
    int t = threadIdx.x;
    int ch = t & 63, r = t >> 6;
    int lo = 0, hi = NN;
    while (lo < hi) { int mid = (lo + hi) >> 1; if (batch[mid] < b) lo = mid + 1; else hi = mid; }
    int st = lo;
    hi = NN;
    while (lo < hi) { int mid = (lo + hi) >> 1; if (batch[mid] < b + 1) lo = mid + 1; else hi = mid; }
    int en = lo;
    float s = 0.f;
    for (int i = st + r; i < en; i += 4) s += y[(size_t)i * 64 + ch];
    __shared__ float red[256];
    red[t] = s;
    __syncthreads();
    if (t < 64) {
        float tot = red[t] + red[t + 64] + red[t + 128] + red[t + 192];
        int cnt = en - st; if (cnt < 1) cnt = 1;
        pooled[b * 64 + t] = tot / (float)cnt;
    }
}

// ---------- final fc ----------
__global__ void k_fc(const float* __restrict__ pooled, const float* __restrict__ fcw,
                     const float* __restrict__ fcb, float* __restrict__ out) {
    int tid = blockIdx.x * 256 + threadIdx.x;
    if (tid >= NG * 33) return;
    int g = tid / 33, o = tid - g * 33;
    const float* p = pooled + g * 64;
    const float* w = fcw + o * 64;
    float a0 = 0.f, a1 = 0.f, a2 = 0.f, a3 = 0.f;
#pragma unroll
    for (int k = 0; k < 16; k++) {
        a0 = fmaf(p[4 * k], w[4 * k], a0);
        a1 = fmaf(p[4 * k + 1], w[4 * k + 1], a1);
        a2 = fmaf(p[4 * k + 2], w[4 * k + 2], a2);
        a3 = fmaf(p[4 * k + 3], w[4 * k + 3], a3);
    }
    out[tid] = fcb[o] + (a0 + a1) + (a2 + a3);
}

extern "C" void kernel_launch(void* const* d_in, const int* in_sizes, int n_in,
                              void* d_out, int out_size, void* d_ws, size_t ws_size,
                              hipStream_t stream) {
    (void)in_sizes; (void)n_in; (void)out_size; (void)ws_size;
    char* ws = (char*)d_ws;
    size_t o = 0;
    auto A = [&](size_t b) { size_t r = o; o += (b + 255) & ~(size_t)255; return r; };
    float* f_h0  = (float*)(ws + A((size_t)NN * 8 * 4));
    float* f_h1  = (float*)(ws + A((size_t)NN * 128 * 4));
    float* f_as1 = (float*)(ws + A((size_t)NN * 4 * 4));
    float* f_ad1 = (float*)(ws + A((size_t)NN * 4 * 4));
    float* f_as2 = (float*)(ws + A((size_t)NN * 4 * 4));
    float* f_ad2 = (float*)(ws + A((size_t)NN * 4 * 4));
    float* f_g1  = (float*)(ws + A((size_t)NN * 128 * 4));
    int* i_off   = (int*)(ws + A((size_t)(NN + 1) * 4));
    int* i_cur   = (int*)(ws + A((size_t)NN * 4));
    int* i_deg   = (int*)(ws + A((size_t)NN * 4));
    int* i_bsum  = (int*)(ws + A((size_t)1024 * 4));
    int* i_srcs  = (int*)(ws + A((size_t)ETOT * 4));
    float* f_Mt  = (float*)(ws + A((size_t)6 * 4096 * 4));
    float* f_fb  = (float*)(ws + A((size_t)6 * 64 * 4));
    float* f_f1t = (float*)(ws + A((size_t)4 * 16384 * 4));
    float* f_f2t = (float*)(ws + A((size_t)4 * 16384 * 4));
    _Float16* f_apk = (_Float16*)(ws + A((size_t)APK_TOT * 2));
    float* f_pool= (float*)(ws + A((size_t)NG * 64 * 4));

    const float* x   = (const float*)d_in[0];
    const int* ei    = (const int*)d_in[1];
    const int* batch = (const int*)d_in[2];
    #define F32(i) ((const float*)d_in[i])

    hipMemsetAsync(i_deg, 0, (size_t)NN * 4, stream);
    k_feat<<<(NN + 255) / 256, 256, 0, stream>>>(x, F32(3), F32(4), f_h0);
    k_h1<<<NN * 128 / 256, 256, 0, stream>>>(f_h0, F32(5), f_h1);
    k_att<32><<<(NN * 4 + 255) / 256, 256, 0, stream>>>(f_h1, F32(6), F32(7), f_as1, f_ad1);
    k_count<<<(ETOT + 255) / 256, 256, 0, stream>>>(ei, i_deg);
    k_scan1<<<98, 1024, 0, stream>>>(i_deg, i_off, i_bsum);
    k_scan2<<<1, 128, 0, stream>>>(i_bsum);
    k_scan3<<<98, 1024, 0, stream>>>(i_off, i_bsum, i_cur);
    k_scatter<<<(ETOT + 255) / 256, 256, 0, stream>>>(ei, i_cur, i_srcs);
    k_gat_agg<128><<<NN * 64 / 256, 256, 0, stream>>>(i_off, i_srcs, f_as1, f_ad1, f_h1, F32(8), f_g1);
    k_h2<<<NN * 64 / 256, 256, 0, stream>>>(f_g1, F32(9), f_h1);
    k_att<16><<<(NN * 4 + 255) / 256, 256, 0, stream>>>(f_h1, F32(10), F32(11), f_as2, f_ad2);
    k_gat_agg<64><<<NN * 64 / 256, 256, 0, stream>>>(i_off, i_srcs, f_as2, f_ad2, f_h1, F32(12), f_g1);
    k_fuse<<<24576 / 256, 256, 0, stream>>>(F32(13), F32(14), F32(15), F32(16),
                                            F32(25), F32(26), F32(27), F32(28),
                                            F32(29), F32(30), F32(31), F32(32),
                                            f_Mt, f_fb);
    k_f1t<<<65536 / 256, 256, 0, stream>>>(F32(17), F32(33), f_f1t);
    k_f2t<<<65536 / 256, 256, 0, stream>>>(F32(19), F32(35), f_f2t);
    k_apack<<<APK_TOT / 256, 256, 0, stream>>>(f_Mt, f_f1t, f_f2t, f_apk);
    XQ Q;
    Q.apk = f_apk; Q.fb = f_fb;
    Q.ef1b = F32(18); Q.ef2b = F32(20);
    Q.df1b = F32(34); Q.df2b = F32(36);
    Q.el1g = F32(21); Q.el1b = F32(22); Q.el2g = F32(23); Q.el2b = F32(24);
    Q.dl1g = F32(37); Q.dl1b = F32(38); Q.dl2g = F32(39); Q.dl2b = F32(40);
    Q.dl3g = F32(41); Q.dl3b = F32(42);
    k_xform<<<(NN + 255) / 256, 256, 0, stream>>>(f_g1, Q);
    k_pool<<<NG, 256, 0, stream>>>(f_g1, batch, f_pool);
    k_fc<<<(NG * 33 + 255) / 256, 256, 0, stream>>>(f_pool, F32(43), F32(44), (float*)d_out);
    #undef F32
}

// Round 6
// 890.777 us; speedup vs baseline: 5.6216x; 1.5193x over previous
//
#include <hip/hip_runtime.h>

#define NN 100000
#define NE 1600000
#define NG 1000
#define ETOT (NE + NN)

typedef _Float16 f16x8 __attribute__((ext_vector_type(8)));
typedef _Float16 f16x4 __attribute__((ext_vector_type(4)));
typedef _Float16 f16x2 __attribute__((ext_vector_type(2)));
typedef float f32x16 __attribute__((ext_vector_type(16)));
#define XROW 72  // xform LDS row stride (halves)

// ---------- h1[N,128] (fp16) = leakyless matmul of (x@ffw.T+ffb) @ gat1_w.T ----------
// feature_fc fused in: h0 recomputed per thread from wave-uniform x row (s_load).
__global__ void k_h1(const float* __restrict__ x, const float* __restrict__ ffw,
                     const float* __restrict__ ffb, const float* __restrict__ g1w,
                     _Float16* __restrict__ h1h) {
    int tid = blockIdx.x * 256 + threadIdx.x;  // NN*64 exact
    int n = tid >> 6, jp = tid & 63;
    float xv[4];
#pragma unroll
    for (int k = 0; k < 4; k++) xv[k] = x[n * 4 + k];
    float h0[8];
#pragma unroll
    for (int o = 0; o < 8; o++) {
        float a = ffb[o];
#pragma unroll
        for (int k = 0; k < 4; k++) a = fmaf(xv[k], ffw[o * 4 + k], a);
        h0[o] = a;
    }
    f16x2 r;
#pragma unroll
    for (int p = 0; p < 2; p++) {
        const float* w = g1w + (2 * jp + p) * 8;
        float a = 0.f;
#pragma unroll
        for (int k = 0; k < 8; k++) a = fmaf(h0[k], w[k], a);
        r[p] = (_Float16)a;
    }
    *(f16x2*)(h1h + (size_t)n * 128 + 2 * jp) = r;
}

// ---------- per-node attention coefficients from fp16 h ----------
template <int C>
__global__ void k_att(const _Float16* __restrict__ hbuf, const float* __restrict__ asw,
                      const float* __restrict__ adw, float* __restrict__ as_,
                      float* __restrict__ ad_) {
    int tid = blockIdx.x * 256 + threadIdx.x;
    if (tid >= NN * 4) return;
    int n = tid >> 2, h = tid & 3;
    const _Float16* hp = hbuf + (size_t)n * (4 * C) + h * C;
    const float* ws_ = asw + h * C;
    const float* wd_ = adw + h * C;
    float a = 0.f, d = 0.f;
#pragma unroll
    for (int c = 0; c < C; c++) {
        float hv = (float)hp[c];
        a = fmaf(hv, ws_[c], a); d = fmaf(hv, wd_[c], d);
    }
    as_[tid] = a; ad_[tid] = d;
}

// ---------- CSR build ----------
__global__ void k_count(const int* __restrict__ ei, int* __restrict__ deg) {
    int e = blockIdx.x * 256 + threadIdx.x;
    if (e >= ETOT) return;
    int dst = (e < NE) ? ei[NE + e] : (e - NE);
    atomicAdd(&deg[dst], 1);
}

__global__ void k_scan1(const int* __restrict__ deg, int* __restrict__ offs, int* __restrict__ bsum) {
    __shared__ int s[1024];
    int tid = threadIdx.x;
    int i = blockIdx.x * 1024 + tid;
    int v = (i < NN) ? deg[i] : 0;
    s[tid] = v;
    __syncthreads();
    for (int d = 1; d < 1024; d <<= 1) {
        int t = 0;
        if (tid >= d) t = s[tid - d];
        __syncthreads();
        if (tid >= d) s[tid] += t;
        __syncthreads();
    }
    if (i < NN) offs[i] = s[tid] - v;
    if (tid == 1023) bsum[blockIdx.x] = s[tid];
}

__global__ void k_scan2(int* __restrict__ bsum) {
    __shared__ int s[128];
    int tid = threadIdx.x;
    int v = (tid < 98) ? bsum[tid] : 0;
    s[tid] = v;
    __syncthreads();
    for (int d = 1; d < 128; d <<= 1) {
        int t = 0;
        if (tid >= d) t = s[tid - d];
        __syncthreads();
        if (tid >= d) s[tid] += t;
        __syncthreads();
    }
    bsum[tid] = s[tid] - v;
}

__global__ void k_scan3(int* __restrict__ offs, const int* __restrict__ bsum, int* __restrict__ cur) {
    int i = blockIdx.x * 1024 + threadIdx.x;
    if (i < NN) {
        int v = offs[i] + bsum[blockIdx.x];
        offs[i] = v; cur[i] = v;
    }
    if (i == 0) offs[NN] = ETOT;
}

__global__ void k_scatter(const int* __restrict__ ei, int* __restrict__ cur, int* __restrict__ srcs) {
    int e = blockIdx.x * 256 + threadIdx.x;
    if (e >= ETOT) return;
    int src, dst;
    if (e < NE) { src = ei[e]; dst = ei[NE + e]; } else { src = dst = e - NE; }
    int p = atomicAdd(&cur[dst], 1);
    srcs[p] = src;
}

// ---------- GAT layer 1: fused single-pass softmax+aggregate, fp16 gathers ----------
// softmax is shift-invariant: out = sum(exp(e)*h)/sum(exp(e)); e tiny (~0.05) so exp safe.
__global__ void k_gat1(const int* __restrict__ offs, const int* __restrict__ srcs,
                       const float* __restrict__ as_, const float* __restrict__ ad_,
                       const _Float16* __restrict__ h1h, const float* __restrict__ bias,
                       float* __restrict__ g1) {
    int wid = (blockIdx.x * 256 + threadIdx.x) >> 6;
    int lane = threadIdx.x & 63;
    if (wid >= NN) return;
    int off = offs[wid];
    int deg = offs[wid + 1] - off;
    int hA = lane >> 5;  // head of channel `lane`; channel lane+64 -> head hA+2
    float adA = hA ? ad_[wid * 4 + 1] : ad_[wid * 4 + 0];
    float adB = hA ? ad_[wid * 4 + 3] : ad_[wid * 4 + 2];
    float ws0 = 0.f, ws1 = 0.f, ac0 = 0.f, ac1 = 0.f;
    for (int k = 0; k < deg; k++) {
        int s = srcs[off + k];
        float e0 = as_[s * 4 + hA] + adA;     e0 = e0 > 0.f ? e0 : 0.2f * e0;
        float e1 = as_[s * 4 + hA + 2] + adB; e1 = e1 > 0.f ? e1 : 0.2f * e1;
        float w0 = __expf(e0), w1 = __expf(e1);
        const _Float16* hr = h1h + (size_t)s * 128;
        ac0 = fmaf(w0, (float)hr[lane], ac0);      ws0 += w0;
        ac1 = fmaf(w1, (float)hr[lane + 64], ac1); ws1 += w1;
    }
    float v0 = ac0 / ws0 + bias[lane];      v0 = v0 > 0.f ? v0 : 0.01f * v0;
    float v1 = ac1 / ws1 + bias[lane + 64]; v1 = v1 > 0.f ? v1 : 0.01f * v1;
    g1[(size_t)wid * 128 + lane] = v0;
    g1[(size_t)wid * 128 + lane + 64] = v1;
}

// ---------- GAT layer 2: same, 64 channels ----------
__global__ void k_gat2(const int* __restrict__ offs, const int* __restrict__ srcs,
                       const float* __restrict__ as_, const float* __restrict__ ad_,
                       const _Float16* __restrict__ h2h, const float* __restrict__ bias,
                       float* __restrict__ g2) {
    int wid = (blockIdx.x * 256 + threadIdx.x) >> 6;
    int lane = threadIdx.x & 63;
    if (wid >= NN) return;
    int off = offs[wid];
    int deg = offs[wid + 1] - off;
    int hd = lane >> 4;
    float adA = (hd & 2) ? ((hd & 1) ? ad_[wid * 4 + 3] : ad_[wid * 4 + 2])
                         : ((hd & 1) ? ad_[wid * 4 + 1] : ad_[wid * 4 + 0]);
    float ws = 0.f, ac = 0.f;
    for (int k = 0; k < deg; k++) {
        int s = srcs[off + k];
        float e = as_[s * 4 + hd] + adA; e = e > 0.f ? e : 0.2f * e;
        float w = __expf(e);
        ac = fmaf(w, (float)h2h[(size_t)s * 64 + lane], ac);
        ws += w;
    }
    float v = ac / ws + bias[lane]; v = v > 0.f ? v : 0.01f * v;
    g2[(size_t)wid * 64 + lane] = v;
}

// ---------- pack gat2_w into MFMA A-fragments (fp16) ----------
// A-frag 32x32x16: lane l holds A[m][k], m=mt*32+(l&31), k=ks*16+(l>>5)*8+d
__global__ void k_wpack(const float* __restrict__ g2w, _Float16* __restrict__ apw2) {
    int tid = blockIdx.x * 256 + threadIdx.x;  // 8192 exact
    int mtks = tid >> 9, l = (tid >> 3) & 63, d = tid & 7;
    int mt = mtks >> 3, ks = mtks & 7;
    int m = mt * 32 + (l & 31), k = ks * 16 + (l >> 5) * 8 + d;
    apw2[tid] = (_Float16)g2w[m * 128 + k];
}

// ---------- h2[N,64] fp16 = g1[N,128] @ gat2_w.T via MFMA, 1 wave = 32 nodes ----------
#define GROW 136  // staging stride (halves), 272B = 16*17 -> 16B-aligned f16x8 reads
#define CROW 72   // C-store stride (halves), 144B = 16*9
__global__ __launch_bounds__(256, 2) void k_h2m(const float* __restrict__ g1,
                                                const _Float16* __restrict__ apw2,
                                                _Float16* __restrict__ h2h) {
    __shared__ _Float16 ls[4 * 32 * GROW];
    const int t = threadIdx.x;
    const int w = t >> 6, l = t & 63;
    const int col = l & 31, hf = l >> 5;
    const int wv = blockIdx.x * 4 + w;
    const int nb = wv * 32;
    if (nb >= NN) return;
    _Float16* g16 = ls + w * (32 * GROW);
    // stage 32 g1 rows (fp32 -> fp16), 2 lanes per row
    const int r = l >> 1, hb = l & 1;
    {
        int nr = nb + r; if (nr >= NN) nr = NN - 1;
        const float* src = g1 + (size_t)nr * 128 + hb * 64;
        _Float16* dst = g16 + r * GROW + hb * 64;
#pragma unroll
        for (int q = 0; q < 16; q++) {
            float4 v = *(const float4*)(src + q * 4);
            f16x4 hv; hv[0] = (_Float16)v.x; hv[1] = (_Float16)v.y;
            hv[2] = (_Float16)v.z; hv[3] = (_Float16)v.w;
            *(f16x4*)(dst + q * 4) = hv;
        }
    }
    // B fragments: B[k][n], n=col, k=ks*16+hf*8+d  (same-wave LDS: in-order, no barrier)
    f16x8 bf[8];
#pragma unroll
    for (int ks = 0; ks < 8; ks++)
        bf[ks] = *(const f16x8*)(g16 + col * GROW + ks * 16 + hf * 8);
    f32x16 acc0, acc1;
#pragma unroll
    for (int i = 0; i < 16; i++) { acc0[i] = 0.f; acc1[i] = 0.f; }
#pragma unroll
    for (int ks = 0; ks < 8; ks++) {
        f16x8 a0 = *(const f16x8*)(apw2 + ((0 * 8 + ks) * 64 + l) * 8);
        f16x8 a1 = *(const f16x8*)(apw2 + ((1 * 8 + ks) * 64 + l) * 8);
        acc0 = __builtin_amdgcn_mfma_f32_32x32x16_f16(a0, bf[ks], acc0, 0, 0, 0);
        acc1 = __builtin_amdgcn_mfma_f32_32x32x16_f16(a1, bf[ks], acc1, 0, 0, 0);
    }
    // C -> LDS (j = mt*32 + (reg&3)+8*(reg>>2)+4*hf), then coalesced fp16 row stores
    _Float16* c16 = g16;
#pragma unroll
    for (int rg = 0; rg < 4; rg++) {
        f16x4 h0, h1;
#pragma unroll
        for (int i = 0; i < 4; i++) { h0[i] = (_Float16)acc0[rg * 4 + i]; h1[i] = (_Float16)acc1[rg * 4 + i]; }
        *(f16x4*)(c16 + col * CROW + rg * 8 + hf * 4) = h0;
        *(f16x4*)(c16 + col * CROW + 32 + rg * 8 + hf * 4) = h1;
    }
    if (nb + r < NN) {
        _Float16* dst = h2h + (size_t)(nb + r) * 64 + hb * 32;
        const _Float16* srow = c16 + r * CROW + hb * 32;
#pragma unroll
        for (int q = 0; q < 4; q++)
            *(f16x8*)(dst + q * 8) = *(const f16x8*)(srow + q * 8);
    }
}

// ---------- fused attention Mt[k][j] (fp32) + fused bias ----------
__global__ void k_fuse(const float* __restrict__ enc_in_w, const float* __restrict__ enc_in_b,
                       const float* __restrict__ enc_out_w, const float* __restrict__ enc_out_b,
                       const float* __restrict__ sa_in_w, const float* __restrict__ sa_in_b,
                       const float* __restrict__ sa_out_w, const float* __restrict__ sa_out_b,
                       const float* __restrict__ ca_in_w, const float* __restrict__ ca_in_b,
                       const float* __restrict__ ca_out_w, const float* __restrict__ ca_out_b,
                       float* __restrict__ Mt, float* __restrict__ fb) {
    int tid = blockIdx.x * 256 + threadIdx.x;
    int p = tid >> 12, r = tid & 4095, j = r >> 6, k = r & 63;
    int li = p & 1;
    const float *iw, *ib, *ow, *ob;
    if (p < 2)      { iw = enc_in_w + li * 12288; ib = enc_in_b + li * 192; ow = enc_out_w + li * 4096; ob = enc_out_b + li * 64; }
    else if (p < 4) { iw = sa_in_w + li * 12288;  ib = sa_in_b + li * 192;  ow = sa_out_w + li * 4096;  ob = sa_out_b + li * 64; }
    else            { iw = ca_in_w + li * 12288;  ib = ca_in_b + li * 192;  ow = ca_out_w + li * 4096;  ob = ca_out_b + li * 64; }
    float a = 0.f;
    for (int m = 0; m < 64; m++) a = fmaf(ow[j * 64 + m], iw[(128 + m) * 64 + k], a);
    Mt[p * 4096 + k * 64 + j] = a;
    if (k == 0) {
        float fa = ob[j];
        for (int m = 0; m < 64; m++) fa = fmaf(ow[j * 64 + m], ib[128 + m], fa);
        fb[p * 64 + j] = fa;
    }
}

// ---------- transpose f2: f2t[pl][h*64+j] ----------
__global__ void k_f2t(const float* __restrict__ enc_f2_w, const float* __restrict__ dec_f2_w,
                      float* __restrict__ f2t) {
    int tid = blockIdx.x * 256 + threadIdx.x;
    int p = tid >> 14, r = tid & 16383;
    int h = r >> 6, j = r & 63;
    const float* src = (p < 2) ? enc_f2_w + p * 16384 : dec_f2_w + (p - 2) * 16384;
    f2t[tid] = src[j * 256 + h];
}

// ---------- transpose f1: f1t[pl][k*256+i] ----------
__global__ void k_f1t(const float* __restrict__ enc_f1_w, const float* __restrict__ dec_f1_w,
                      float* __restrict__ f1t) {
    int tid = blockIdx.x * 256 + threadIdx.x;
    int p = tid >> 14, r = tid & 16383;
    int k = r >> 8, i = r & 255;
    const float* src = (p < 2) ? enc_f1_w + p * 16384 : dec_f1_w + (p - 2) * 16384;
    f1t[tid] = src[i * 64 + k];
}

// ---------- pack transformer weights into fp16 MFMA A-fragment order ----------
#define APK_F1 24576
#define APK_F2 90112
#define APK_TOT 155648
__global__ void k_apack(const float* __restrict__ Mt, const float* __restrict__ f1t,
                        const float* __restrict__ f2t, _Float16* __restrict__ apk) {
    int tid = blockIdx.x * 256 + threadIdx.x;
    float v;
    if (tid < APK_F1) {
        int p = tid >> 12, idx = tid & 4095;
        int mt = idx >> 11, ks = (idx >> 9) & 3, l = (idx >> 3) & 63, d = idx & 7;
        int m = mt * 32 + (l & 31), k = ks * 16 + (l >> 5) * 8 + d;
        v = Mt[p * 4096 + k * 64 + m];
    } else if (tid < APK_F2) {
        int r = tid - APK_F1; int pl = r >> 14, idx = r & 16383;
        int mt = idx >> 11, ks = (idx >> 9) & 3, l = (idx >> 3) & 63, d = idx & 7;
        int m = mt * 32 + (l & 31), k = ks * 16 + (l >> 5) * 8 + d;
        v = f1t[pl * 16384 + k * 256 + m];
    } else {
        int r = tid - APK_F2; int pl = r >> 14, idx = r & 16383;
        int mt = idx >> 13, ks = (idx >> 9) & 15, l = (idx >> 3) & 63, d = idx & 7;
        int m = mt * 32 + (l & 31), k = ks * 16 + (l >> 5) * 8 + d;
        v = f2t[pl * 16384 + k * 64 + m];
    }
    apk[tid] = (_Float16)v;
}

// ---------- MFMA transformer: 1 wave = 64 nodes, no barriers ----------
struct XQ {
    const _Float16* apk; const float* fb;
    const float* ef1b; const float* ef2b; const float* df1b; const float* df2b;
    const float* el1g; const float* el1b; const float* el2g; const float* el2b;
    const float* dl1g; const float* dl1b; const float* dl2g; const float* dl2b;
    const float* dl3g; const float* dl3b;
};

__device__ __forceinline__ void xstore(_Float16* xw, const float y[4][16], int col, int hf) {
#pragma unroll
    for (int nt = 0; nt < 2; nt++)
#pragma unroll
        for (int mt = 0; mt < 2; mt++)
#pragma unroll
            for (int rg = 0; rg < 4; rg++) {
                f16x4 h4;
#pragma unroll
                for (int i = 0; i < 4; i++) h4[i] = (_Float16)y[mt * 2 + nt][rg * 4 + i];
                *(f16x4*)(xw + (nt * 32 + col) * XROW + mt * 32 + rg * 8 + hf * 4) = h4;
            }
}

__device__ __forceinline__ void loadbf(const _Float16* xw, f16x8 bf[2][4], int col, int hf) {
#pragma unroll
    for (int nt = 0; nt < 2; nt++)
#pragma unroll
        for (int ks = 0; ks < 4; ks++)
            bf[nt][ks] = *(const f16x8*)(xw + (nt * 32 + col) * XROW + ks * 16 + hf * 8);
}

__device__ __forceinline__ void lnw(float y[4][16], const float* g, const float* b, int hf) {
#pragma unroll
    for (int nt = 0; nt < 2; nt++) {
        float s = 0.f, q = 0.f;
#pragma unroll
        for (int mt = 0; mt < 2; mt++)
#pragma unroll
            for (int r = 0; r < 16; r++) { float v = y[mt * 2 + nt][r]; s += v; q = fmaf(v, v, q); }
        s += __shfl_xor(s, 32, 64);
        q += __shfl_xor(q, 32, 64);
        float m = s * 0.015625f;
        float var = fmaf(q, 0.015625f, -m * m);
        float rs = rsqrtf(var + 1e-5f);
#pragma unroll
        for (int mt = 0; mt < 2; mt++)
#pragma unroll
            for (int rg = 0; rg < 4; rg++) {
                float4 g4 = *(const float4*)(g + mt * 32 + rg * 8 + hf * 4);
                float4 b4 = *(const float4*)(b + mt * 32 + rg * 8 + hf * 4);
                float* yp = &y[mt * 2 + nt][rg * 4];
                yp[0] = fmaf((yp[0] - m) * rs, g4.x, b4.x);
                yp[1] = fmaf((yp[1] - m) * rs, g4.y, b4.y);
                yp[2] = fmaf((yp[2] - m) * rs, g4.z, b4.z);
                yp[3] = fmaf((yp[3] - m) * rs, g4.w, b4.w);
            }
    }
}

__global__ __launch_bounds__(256, 2) void k_xform(float* __restrict__ yio, XQ P) {
    __shared__ _Float16 xs[4 * 64 * XROW];
    const int t = threadIdx.x;
    const int w = t >> 6, l = t & 63;
    const int col = l & 31, hf = l >> 5;
    _Float16* xw = xs + w * (64 * XROW);
    const int nb = blockIdx.x * 256 + w * 64;
    const int nn0 = nb + col, nn1 = nb + 32 + col;
    const int nc0 = nn0 < NN ? nn0 : NN - 1;
    const int nc1 = nn1 < NN ? nn1 : NN - 1;

    float y[4][16];
#pragma unroll
    for (int mt = 0; mt < 2; mt++)
#pragma unroll
        for (int nt = 0; nt < 2; nt++) {
            const float* src = yio + (size_t)(nt ? nc1 : nc0) * 64 + mt * 32 + hf * 4;
#pragma unroll
            for (int rg = 0; rg < 4; rg++) {
                float4 v = *(const float4*)(src + rg * 8);
                float* yp = &y[mt * 2 + nt][rg * 4];
                yp[0] = v.x; yp[1] = v.y; yp[2] = v.z; yp[3] = v.w;
            }
        }
    f16x8 bf[2][4];
    xstore(xw, y, col, hf);
    loadbf(xw, bf, col, hf);

#pragma unroll 1
    for (int layer = 0; layer < 4; layer++) {
        const bool enc = layer < 2;
        const int li = enc ? layer : layer - 2;
        const int nat = enc ? 1 : 2;
#pragma unroll 1
        for (int at = 0; at < nat; at++) {
            const int p = enc ? layer : (at == 0 ? 2 + li : 4 + li);
            const _Float16* apA = P.apk + p * 4096;
            const float* fbp = P.fb + p * 64;
            f32x16 acc[4];
#pragma unroll
            for (int mt = 0; mt < 2; mt++) {
                f32x16 a;
#pragma unroll
                for (int rg = 0; rg < 4; rg++) {
                    float4 b4 = *(const float4*)(fbp + mt * 32 + rg * 8 + hf * 4);
                    a[rg * 4 + 0] = b4.x; a[rg * 4 + 1] = b4.y; a[rg * 4 + 2] = b4.z; a[rg * 4 + 3] = b4.w;
                }
                acc[mt * 2 + 0] = a; acc[mt * 2 + 1] = a;
            }
#pragma unroll
            for (int mt = 0; mt < 2; mt++)
#pragma unroll
                for (int ks = 0; ks < 4; ks++) {
                    f16x8 af = *(const f16x8*)(apA + ((mt * 4 + ks) * 64 + l) * 8);
                    acc[mt * 2 + 0] = __builtin_amdgcn_mfma_f32_32x32x16_f16(af, bf[0][ks], acc[mt * 2 + 0], 0, 0, 0);
                    acc[mt * 2 + 1] = __builtin_amdgcn_mfma_f32_32x32x16_f16(af, bf[1][ks], acc[mt * 2 + 1], 0, 0, 0);
                }
#pragma unroll
            for (int ti = 0; ti < 4; ti++)
#pragma unroll
                for (int r = 0; r < 16; r++) y[ti][r] += acc[ti][r];
            const float *g, *b;
            if (enc)          { g = P.el1g + li * 64; b = P.el1b + li * 64; }
            else if (at == 0) { g = P.dl1g + li * 64; b = P.dl1b + li * 64; }
            else              { g = P.dl2g + li * 64; b = P.dl2b + li * 64; }
            lnw(y, g, b, hf);
            xstore(xw, y, col, hf);
            loadbf(xw, bf, col, hf);
        }
        const int pl = enc ? layer : 2 + li;
        const _Float16* apF1 = P.apk + APK_F1 + pl * 16384;
        const _Float16* apF2 = P.apk + APK_F2 + pl * 16384;
        const float* f1bp = (enc ? P.ef1b : P.df1b) + li * 256;
        const float* f2bp = (enc ? P.ef2b : P.df2b) + li * 64;
        f32x16 out[4];
#pragma unroll
        for (int mt = 0; mt < 2; mt++) {
            f32x16 a;
#pragma unroll
            for (int rg = 0; rg < 4; rg++) {
                float4 b4 = *(const float4*)(f2bp + mt * 32 + rg * 8 + hf * 4);
                a[rg * 4 + 0] = b4.x; a[rg * 4 + 1] = b4.y; a[rg * 4 + 2] = b4.z; a[rg * 4 + 3] = b4.w;
            }
            out[mt * 2 + 0] = a; out[mt * 2 + 1] = a;
        }
#pragma unroll 1
        for (int c = 0; c < 4; c++) {
            f32x16 ha[4];
#pragma unroll
            for (int hmt = 0; hmt < 2; hmt++) {
                f32x16 a;
#pragma unroll
                for (int rg = 0; rg < 4; rg++) {
                    float4 b4 = *(const float4*)(f1bp + c * 64 + hmt * 32 + rg * 8 + hf * 4);
                    a[rg * 4 + 0] = b4.x; a[rg * 4 + 1] = b4.y; a[rg * 4 + 2] = b4.z; a[rg * 4 + 3] = b4.w;
                }
                ha[hmt * 2 + 0] = a; ha[hmt * 2 + 1] = a;
            }
#pragma unroll
            for (int hmt = 0; hmt < 2; hmt++)
#pragma unroll
                for (int ks = 0; ks < 4; ks++) {
                    f16x8 af = *(const f16x8*)(apF1 + (((2 * c + hmt) * 4 + ks) * 64 + l) * 8);
                    ha[hmt * 2 + 0] = __builtin_amdgcn_mfma_f32_32x32x16_f16(af, bf[0][ks], ha[hmt * 2 + 0], 0, 0, 0);
                    ha[hmt * 2 + 1] = __builtin_amdgcn_mfma_f32_32x32x16_f16(af, bf[1][ks], ha[hmt * 2 + 1], 0, 0, 0);
                }
#pragma unroll
            for (int nt = 0; nt < 2; nt++)
#pragma unroll
                for (int hmt = 0; hmt < 2; hmt++)
#pragma unroll
                    for (int rg = 0; rg < 4; rg++) {
                        f16x4 h4;
#pragma unroll
                        for (int i = 0; i < 4; i++)
                            h4[i] = (_Float16)fmaxf(ha[hmt * 2 + nt][rg * 4 + i], 0.f);
                        *(f16x4*)(xw + (nt * 32 + col) * XROW + hmt * 32 + rg * 8 + hf * 4) = h4;
                    }
#pragma unroll
            for (int ksl = 0; ksl < 4; ksl++) {
                f16x8 hbf0 = *(const f16x8*)(xw + col * XROW + ksl * 16 + hf * 8);
                f16x8 hbf1 = *(const f16x8*)(xw + (32 + col) * XROW + ksl * 16 + hf * 8);
#pragma unroll
                for (int mt = 0; mt < 2; mt++) {
                    f16x8 af = *(const f16x8*)(apF2 + ((mt * 16 + c * 4 + ksl) * 64 + l) * 8);
                    out[mt * 2 + 0] = __builtin_amdgcn_mfma_f32_32x32x16_f16(af, hbf0, out[mt * 2 + 0], 0, 0, 0);
                    out[mt * 2 + 1] = __builtin_amdgcn_mfma_f32_32x32x16_f16(af, hbf1, out[mt * 2 + 1], 0, 0, 0);
                }
            }
        }
#pragma unroll
        for (int ti = 0; ti < 4; ti++)
#pragma unroll
            for (int r = 0; r < 16; r++) y[ti][r] += out[ti][r];
        const float* g2 = (enc ? P.el2g : P.dl3g) + li * 64;
        const float* b2 = (enc ? P.el2b : P.dl3b) + li * 64;
        lnw(y, g2, b2, hf);
        if (layer < 3) {
            xstore(xw, y, col, hf);
            loadbf(xw, bf, col, hf);
        }
    }
#pragma unroll
    for (int mt = 0; mt < 2; mt++)
#pragma unroll
        for (int nt = 0; nt < 2; nt++) {
            int n = nt ? nn1 : nn0;
            if (n < NN) {
                float* dst = yio + (size_t)n * 64 + mt * 32 + hf * 4;
#pragma unroll
                for (int rg = 0; rg < 4; rg++) {
                    const float* yp = &y[mt * 2 + nt][rg * 4];
                    *(float4*)(dst + rg * 8) = make_float4(yp[0], yp[1], yp[2], yp[3]);
                }
            }
        }
}

// ---------- global mean pool ----------
__global__ void k_pool(const float* __restrict__ y, const int* __restrict__ batch,
                       float* __restrict__ pooled) {
    int b = blockIdx.x;
    int t = threadIdx.x;
    int ch = t & 63, r = t >> 6;
    int lo = 0, hi = NN;
    while (lo < hi) { int mid = (lo + hi) >> 1; if (batch[mid] < b) lo = mid + 1; else hi = mid; }
    int st = lo;
    hi = NN;
    while (lo < hi) { int mid = (lo + hi) >> 1; if (batch[mid] < b + 1) lo = mid + 1; else hi = mid; }
    int en = lo;
    float s = 0.f;
    for (int i = st + r; i < en; i += 4) s += y[(size_t)i * 64 + ch];
    __shared__ float red[256];
    red[t] = s;
    __syncthreads();
    if (t < 64) {
        float tot = red[t] + red[t + 64] + red[t + 128] + red[t + 192];
        int cnt = en - st; if (cnt < 1) cnt = 1;
        pooled[b * 64 + t] = tot / (float)cnt;
    }
}

// ---------- final fc ----------
__global__ void k_fc(const float* __restrict__ pooled, const float* __restrict__ fcw,
                     const float* __restrict__ fcb, float* __restrict__ out) {
    int tid = blockIdx.x * 256 + threadIdx.x;
    if (tid >= NG * 33) return;
    int g = tid / 33, o = tid - g * 33;
    const float* p = pooled + g * 64;
    const float* w = fcw + o * 64;
    float a0 = 0.f, a1 = 0.f, a2 = 0.f, a3 = 0.f;
#pragma unroll
    for (int k = 0; k < 16; k++) {
        a0 = fmaf(p[4 * k], w[4 * k], a0);
        a1 = fmaf(p[4 * k + 1], w[4 * k + 1], a1);
        a2 = fmaf(p[4 * k + 2], w[4 * k + 2], a2);
        a3 = fmaf(p[4 * k + 3], w[4 * k + 3], a3);
    }
    out[tid] = fcb[o] + (a0 + a1) + (a2 + a3);
}

extern "C" void kernel_launch(void* const* d_in, const int* in_sizes, int n_in,
                              void* d_out, int out_size, void* d_ws, size_t ws_size,
                              hipStream_t stream) {
    (void)in_sizes; (void)n_in; (void)out_size; (void)ws_size;
    char* ws = (char*)d_ws;
    size_t o = 0;
    auto A = [&](size_t b) { size_t r = o; o += (b + 255) & ~(size_t)255; return r; };
    _Float16* h1h = (_Float16*)(ws + A((size_t)NN * 128 * 2));
    _Float16* h2h = (_Float16*)(ws + A((size_t)NN * 64 * 2));
    float* f_g1  = (float*)(ws + A((size_t)NN * 128 * 4));
    float* f_g2  = (float*)(ws + A((size_t)NN * 64 * 4));
    float* f_as1 = (float*)(ws + A((size_t)NN * 4 * 4));
    float* f_ad1 = (float*)(ws + A((size_t)NN * 4 * 4));
    float* f_as2 = (float*)(ws + A((size_t)NN * 4 * 4));
    float* f_ad2 = (float*)(ws + A((size_t)NN * 4 * 4));
    int* i_off   = (int*)(ws + A((size_t)(NN + 1) * 4));
    int* i_cur   = (int*)(ws + A((size_t)NN * 4));
    int* i_deg   = (int*)(ws + A((size_t)NN * 4));
    int* i_bsum  = (int*)(ws + A((size_t)1024 * 4));
    int* i_srcs  = (int*)(ws + A((size_t)ETOT * 4));
    float* f_Mt  = (float*)(ws + A((size_t)6 * 4096 * 4));
    float* f_fb  = (float*)(ws + A((size_t)6 * 64 * 4));
    float* f_f1t = (float*)(ws + A((size_t)4 * 16384 * 4));
    float* f_f2t = (float*)(ws + A((size_t)4 * 16384 * 4));
    _Float16* f_apk = (_Float16*)(ws + A((size_t)APK_TOT * 2));
    _Float16* apw2  = (_Float16*)(ws + A((size_t)8192 * 2));
    float* f_pool= (float*)(ws + A((size_t)NG * 64 * 4));

    const float* x   = (const float*)d_in[0];
    const int* ei    = (const int*)d_in[1];
    const int* batch = (const int*)d_in[2];
    #define F32(i) ((const float*)d_in[i])

    hipMemsetAsync(i_deg, 0, (size_t)NN * 4, stream);
    k_h1<<<NN * 64 / 256, 256, 0, stream>>>(x, F32(3), F32(4), F32(5), h1h);
    k_att<32><<<(NN * 4 + 255) / 256, 256, 0, stream>>>(h1h, F32(6), F32(7), f_as1, f_ad1);
    k_count<<<(ETOT + 255) / 256, 256, 0, stream>>>(ei, i_deg);
    k_scan1<<<98, 1024, 0, stream>>>(i_deg, i_off, i_bsum);
    k_scan2<<<1, 128, 0, stream>>>(i_bsum);
    k_scan3<<<98, 1024, 0, stream>>>(i_off, i_bsum, i_cur);
    k_scatter<<<(ETOT + 255) / 256, 256, 0, stream>>>(ei, i_cur, i_srcs);
    k_gat1<<<NN * 64 / 256, 256, 0, stream>>>(i_off, i_srcs, f_as1, f_ad1, h1h, F32(8), f_g1);
    k_wpack<<<32, 256, 0, stream>>>(F32(9), apw2);
    k_h2m<<<(NN / 32 + 3) / 4, 256, 0, stream>>>(f_g1, apw2, h2h);
    k_att<16><<<(NN * 4 + 255) / 256, 256, 0, stream>>>(h2h, F32(10), F32(11), f_as2, f_ad2);
    k_gat2<<<NN * 64 / 256, 256, 0, stream>>>(i_off, i_srcs, f_as2, f_ad2, h2h, F32(12), f_g2);
    k_fuse<<<24576 / 256, 256, 0, stream>>>(F32(13), F32(14), F32(15), F32(16),
                                            F32(25), F32(26), F32(27), F32(28),
                                            F32(29), F32(30), F32(31), F32(32),
                                            f_Mt, f_fb);
    k_f1t<<<65536 / 256, 256, 0, stream>>>(F32(17), F32(33), f_f1t);
    k_f2t<<<65536 / 256, 256, 0, stream>>>(F32(19), F32(35), f_f2t);
    k_apack<<<APK_TOT / 256, 256, 0, stream>>>(f_Mt, f_f1t, f_f2t, f_apk);
    XQ Q;
    Q.apk = f_apk; Q.fb = f_fb;
    Q.ef1b = F32(18); Q.ef2b = F32(20);
    Q.df1b = F32(34); Q.df2b = F32(36);
    Q.el1g = F32(21); Q.el1b = F32(22); Q.el2g = F32(23); Q.el2b = F32(24);
    Q.dl1g = F32(37); Q.dl1b = F32(38); Q.dl2g = F32(39); Q.dl2b = F32(40);
    Q.dl3g = F32(41); Q.dl3b = F32(42);
    k_xform<<<(NN + 255) / 256, 256, 0, stream>>>(f_g2, Q);
    k_pool<<<NG, 256, 0, stream>>>(f_g2, batch, f_pool);
    k_fc<<<(NG * 33 + 255) / 256, 256, 0, stream>>>(f_pool, F32(43), F32(44), (float*)d_out);
    #undef F32
}

// Round 7
// 719.162 us; speedup vs baseline: 6.9631x; 1.2386x over previous
//
#include <hip/hip_runtime.h>

#define NN 100000
#define NE 1600000
#define NG 1000
#define ETOT (NE + NN)

typedef _Float16 f16x8 __attribute__((ext_vector_type(8)));
typedef _Float16 f16x4 __attribute__((ext_vector_type(4)));
typedef _Float16 f16x2 __attribute__((ext_vector_type(2)));
typedef float f32x16 __attribute__((ext_vector_type(16)));
#define XROW 72  // xform LDS row stride (halves)

// ---------- h1 paired fp16: h1p[n][jp] = (ch jp, ch jp+64); feature_fc fused ----------
__global__ void k_h1(const float* __restrict__ x, const float* __restrict__ ffw,
                     const float* __restrict__ ffb, const float* __restrict__ g1w,
                     _Float16* __restrict__ h1p) {
    int tid = blockIdx.x * 256 + threadIdx.x;  // NN*64 exact
    int n = tid >> 6, jp = tid & 63;
    float xv[4];
#pragma unroll
    for (int k = 0; k < 4; k++) xv[k] = x[n * 4 + k];
    float h0[8];
#pragma unroll
    for (int o = 0; o < 8; o++) {
        float a = ffb[o];
#pragma unroll
        for (int k = 0; k < 4; k++) a = fmaf(xv[k], ffw[o * 4 + k], a);
        h0[o] = a;
    }
    const float* w0 = g1w + jp * 8;
    const float* w1 = g1w + (jp + 64) * 8;
    float a0 = 0.f, a1 = 0.f;
#pragma unroll
    for (int k = 0; k < 8; k++) { a0 = fmaf(h0[k], w0[k], a0); a1 = fmaf(h0[k], w1[k], a1); }
    f16x2 r; r[0] = (_Float16)a0; r[1] = (_Float16)a1;
    *(f16x2*)(h1p + ((size_t)n * 64 + jp) * 2) = r;
}

// ---------- layer-1 attention coeffs from paired h1; asp packed {h0,h2,h1,h3} ----------
__global__ void k_att1(const _Float16* __restrict__ h1p, const float* __restrict__ asw,
                       const float* __restrict__ adw, float* __restrict__ asp,
                       float* __restrict__ ad_) {
    int tid = blockIdx.x * 256 + threadIdx.x;
    if (tid >= NN * 4) return;
    int n = tid >> 2, h = tid & 3;
    const _Float16* base = h1p + (size_t)n * 128;
    const float* ws_ = asw + h * 32;
    const float* wd_ = adw + h * 32;
    int slot = h >> 1, poff = (h & 1) * 32;
    float a = 0.f, d = 0.f;
#pragma unroll
    for (int c = 0; c < 32; c++) {
        float hv = (float)base[(poff + c) * 2 + slot];
        a = fmaf(hv, ws_[c], a); d = fmaf(hv, wd_[c], d);
    }
    asp[n * 4 + ((h >> 1) + ((h & 1) << 1))] = a;
    ad_[n * 4 + h] = d;
}

// ---------- layer-2 attention coeffs (standard layout) ----------
__global__ void k_att2(const _Float16* __restrict__ h2h, const float* __restrict__ asw,
                       const float* __restrict__ adw, float* __restrict__ as_,
                       float* __restrict__ ad_) {
    int tid = blockIdx.x * 256 + threadIdx.x;
    if (tid >= NN * 4) return;
    int n = tid >> 2, h = tid & 3;
    const _Float16* hp = h2h + (size_t)n * 64 + h * 16;
    const float* ws_ = asw + h * 16;
    const float* wd_ = adw + h * 16;
    float a = 0.f, d = 0.f;
#pragma unroll
    for (int c = 0; c < 16; c++) {
        float hv = (float)hp[c];
        a = fmaf(hv, ws_[c], a); d = fmaf(hv, wd_[c], d);
    }
    as_[tid] = a; ad_[tid] = d;
}

// ---------- CSR build ----------
__global__ void k_count(const int* __restrict__ ei, int* __restrict__ deg) {
    int e = blockIdx.x * 256 + threadIdx.x;
    if (e >= ETOT) return;
    int dst = (e < NE) ? ei[NE + e] : (e - NE);
    atomicAdd(&deg[dst], 1);
}

__global__ void k_scan1(const int* __restrict__ deg, int* __restrict__ offs, int* __restrict__ bsum) {
    __shared__ int s[1024];
    int tid = threadIdx.x;
    int i = blockIdx.x * 1024 + tid;
    int v = (i < NN) ? deg[i] : 0;
    s[tid] = v;
    __syncthreads();
    for (int d = 1; d < 1024; d <<= 1) {
        int t = 0;
        if (tid >= d) t = s[tid - d];
        __syncthreads();
        if (tid >= d) s[tid] += t;
        __syncthreads();
    }
    if (i < NN) offs[i] = s[tid] - v;
    if (tid == 1023) bsum[blockIdx.x] = s[tid];
}

__global__ void k_scan2(int* __restrict__ bsum) {
    __shared__ int s[128];
    int tid = threadIdx.x;
    int v = (tid < 98) ? bsum[tid] : 0;
    s[tid] = v;
    __syncthreads();
    for (int d = 1; d < 128; d <<= 1) {
        int t = 0;
        if (tid >= d) t = s[tid - d];
        __syncthreads();
        if (tid >= d) s[tid] += t;
        __syncthreads();
    }
    bsum[tid] = s[tid] - v;
}

__global__ void k_scan3(int* __restrict__ offs, const int* __restrict__ bsum, int* __restrict__ cur) {
    int i = blockIdx.x * 1024 + threadIdx.x;
    if (i < NN) {
        int v = offs[i] + bsum[blockIdx.x];
        offs[i] = v; cur[i] = v;
    }
    if (i == 0) offs[NN] = ETOT;
}

__global__ void k_scatter(const int* __restrict__ ei, int* __restrict__ cur, int* __restrict__ srcs) {
    int e = blockIdx.x * 256 + threadIdx.x;
    if (e >= ETOT) return;
    int src, dst;
    if (e < NE) { src = ei[e]; dst = ei[NE + e]; } else { src = dst = e - NE; }
    int p = atomicAdd(&cur[dst], 1);
    srcs[p] = src;
}

// ---------- GAT layer 1: single-pass softmax+aggregate, paired fp16 gathers ----------
__global__ void k_gat1(const int* __restrict__ offs, const int* __restrict__ srcs,
                       const float* __restrict__ asp, const float* __restrict__ ad_,
                       const _Float16* __restrict__ h1p, const float* __restrict__ bias,
                       _Float16* __restrict__ g1h) {
    int wid = (blockIdx.x * 256 + threadIdx.x) >> 6;
    int lane = threadIdx.x & 63;
    if (wid >= NN) return;
    int off = offs[wid];
    int deg = offs[wid + 1] - off;
    int hA = lane >> 5;
    float adA = ad_[wid * 4 + hA];
    float adB = ad_[wid * 4 + hA + 2];
    float ws0 = 0.f, ws1 = 0.f, ac0 = 0.f, ac1 = 0.f;
    float ws0b = 0.f, ws1b = 0.f, ac0b = 0.f, ac1b = 0.f;
    for (int base = 0; base < deg; base += 64) {
        int idx = off + base + lane; if (idx >= ETOT) idx = ETOT - 1;
        int sv = srcs[idx];
        int cnt = deg - base; if (cnt > 64) cnt = 64;
        int j = 0;
        for (; j + 2 <= cnt; j += 2) {
            int sa = __shfl(sv, j, 64), sb = __shfl(sv, j + 1, 64);
            float2 aa = *(const float2*)(asp + sa * 4 + 2 * hA);
            float2 ab = *(const float2*)(asp + sb * 4 + 2 * hA);
            f16x2 hpa = *(const f16x2*)(h1p + ((size_t)sa * 64 + lane) * 2);
            f16x2 hpb = *(const f16x2*)(h1p + ((size_t)sb * 64 + lane) * 2);
            float e0 = aa.x + adA; e0 = fmaxf(e0, 0.2f * e0);
            float e1 = aa.y + adB; e1 = fmaxf(e1, 0.2f * e1);
            float w0 = __expf(e0), w1 = __expf(e1);
            ws0 += w0; ws1 += w1;
            ac0 = fmaf(w0, (float)hpa[0], ac0); ac1 = fmaf(w1, (float)hpa[1], ac1);
            float e0b = ab.x + adA; e0b = fmaxf(e0b, 0.2f * e0b);
            float e1b = ab.y + adB; e1b = fmaxf(e1b, 0.2f * e1b);
            float w0b = __expf(e0b), w1b = __expf(e1b);
            ws0b += w0b; ws1b += w1b;
            ac0b = fmaf(w0b, (float)hpb[0], ac0b); ac1b = fmaf(w1b, (float)hpb[1], ac1b);
        }
        if (j < cnt) {
            int sa = __shfl(sv, j, 64);
            float2 aa = *(const float2*)(asp + sa * 4 + 2 * hA);
            f16x2 hpa = *(const f16x2*)(h1p + ((size_t)sa * 64 + lane) * 2);
            float e0 = aa.x + adA; e0 = fmaxf(e0, 0.2f * e0);
            float e1 = aa.y + adB; e1 = fmaxf(e1, 0.2f * e1);
            float w0 = __expf(e0), w1 = __expf(e1);
            ws0 += w0; ws1 += w1;
            ac0 = fmaf(w0, (float)hpa[0], ac0); ac1 = fmaf(w1, (float)hpa[1], ac1);
        }
    }
    ws0 += ws0b; ws1 += ws1b; ac0 += ac0b; ac1 += ac1b;
    float v0 = ac0 / ws0 + bias[lane];      v0 = fmaxf(v0, 0.01f * v0);
    float v1 = ac1 / ws1 + bias[lane + 64]; v1 = fmaxf(v1, 0.01f * v1);
    g1h[(size_t)wid * 128 + lane] = (_Float16)v0;
    g1h[(size_t)wid * 128 + lane + 64] = (_Float16)v1;
}

// ---------- GAT layer 2 ----------
__global__ void k_gat2(const int* __restrict__ offs, const int* __restrict__ srcs,
                       const float* __restrict__ as_, const float* __restrict__ ad_,
                       const _Float16* __restrict__ h2h, const float* __restrict__ bias,
                       float* __restrict__ g2) {
    int wid = (blockIdx.x * 256 + threadIdx.x) >> 6;
    int lane = threadIdx.x & 63;
    if (wid >= NN) return;
    int off = offs[wid];
    int deg = offs[wid + 1] - off;
    int hd = lane >> 4;
    float adA = ad_[wid * 4 + hd];
    float ws = 0.f, ac = 0.f, wsb = 0.f, acb = 0.f;
    for (int base = 0; base < deg; base += 64) {
        int idx = off + base + lane; if (idx >= ETOT) idx = ETOT - 1;
        int sv = srcs[idx];
        int cnt = deg - base; if (cnt > 64) cnt = 64;
        int j = 0;
        for (; j + 2 <= cnt; j += 2) {
            int sa = __shfl(sv, j, 64), sb = __shfl(sv, j + 1, 64);
            float ea = as_[sa * 4 + hd] + adA; ea = fmaxf(ea, 0.2f * ea);
            float eb = as_[sb * 4 + hd] + adA; eb = fmaxf(eb, 0.2f * eb);
            float ha = (float)h2h[(size_t)sa * 64 + lane];
            float hb = (float)h2h[(size_t)sb * 64 + lane];
            float wa = __expf(ea), wb = __expf(eb);
            ws += wa; ac = fmaf(wa, ha, ac);
            wsb += wb; acb = fmaf(wb, hb, acb);
        }
        if (j < cnt) {
            int sa = __shfl(sv, j, 64);
            float ea = as_[sa * 4 + hd] + adA; ea = fmaxf(ea, 0.2f * ea);
            float wa = __expf(ea);
            ws += wa; ac = fmaf(wa, (float)h2h[(size_t)sa * 64 + lane], ac);
        }
    }
    ws += wsb; ac += acb;
    float v = ac / ws + bias[lane]; v = fmaxf(v, 0.01f * v);
    g2[(size_t)wid * 64 + lane] = v;
}

// ---------- pack gat2_w into MFMA A-fragments (fp16) ----------
__global__ void k_wpack(const float* __restrict__ g2w, _Float16* __restrict__ apw2) {
    int tid = blockIdx.x * 256 + threadIdx.x;  // 8192 exact
    int mtks = tid >> 9, l = (tid >> 3) & 63, d = tid & 7;
    int mt = mtks >> 3, ks = mtks & 7;
    int m = mt * 32 + (l & 31), k = ks * 16 + (l >> 5) * 8 + d;
    apw2[tid] = (_Float16)g2w[m * 128 + k];
}

// ---------- h2[N,64] fp16 = g1h[N,128] @ gat2_w.T via MFMA, 1 wave = 32 nodes ----------
#define GROW 136
#define CROW 72
__global__ __launch_bounds__(256, 2) void k_h2m(const _Float16* __restrict__ g1h,
                                                const _Float16* __restrict__ apw2,
                                                _Float16* __restrict__ h2h) {
    __shared__ _Float16 ls[4 * 32 * GROW];
    const int t = threadIdx.x;
    const int w = t >> 6, l = t & 63;
    const int col = l & 31, hf = l >> 5;
    const int wv = blockIdx.x * 4 + w;
    const int nb = wv * 32;
    if (nb >= NN) return;
    _Float16* g16 = ls + w * (32 * GROW);
    const int r = l >> 1, hb = l & 1;
    {
        int nr = nb + r; if (nr >= NN) nr = NN - 1;
        const _Float16* src = g1h + (size_t)nr * 128 + hb * 64;
        _Float16* dst = g16 + r * GROW + hb * 64;
#pragma unroll
        for (int q = 0; q < 8; q++)
            *(f16x8*)(dst + q * 8) = *(const f16x8*)(src + q * 8);
    }
    f16x8 bf[8];
#pragma unroll
    for (int ks = 0; ks < 8; ks++)
        bf[ks] = *(const f16x8*)(g16 + col * GROW + ks * 16 + hf * 8);
    f32x16 acc0, acc1;
#pragma unroll
    for (int i = 0; i < 16; i++) { acc0[i] = 0.f; acc1[i] = 0.f; }
#pragma unroll
    for (int ks = 0; ks < 8; ks++) {
        f16x8 a0 = *(const f16x8*)(apw2 + ((0 * 8 + ks) * 64 + l) * 8);
        f16x8 a1 = *(const f16x8*)(apw2 + ((1 * 8 + ks) * 64 + l) * 8);
        acc0 = __builtin_amdgcn_mfma_f32_32x32x16_f16(a0, bf[ks], acc0, 0, 0, 0);
        acc1 = __builtin_amdgcn_mfma_f32_32x32x16_f16(a1, bf[ks], acc1, 0, 0, 0);
    }
    _Float16* c16 = g16;
#pragma unroll
    for (int rg = 0; rg < 4; rg++) {
        f16x4 h0, h1;
#pragma unroll
        for (int i = 0; i < 4; i++) { h0[i] = (_Float16)acc0[rg * 4 + i]; h1[i] = (_Float16)acc1[rg * 4 + i]; }
        *(f16x4*)(c16 + col * CROW + rg * 8 + hf * 4) = h0;
        *(f16x4*)(c16 + col * CROW + 32 + rg * 8 + hf * 4) = h1;
    }
    if (nb + r < NN) {
        _Float16* dst = h2h + (size_t)(nb + r) * 64 + hb * 32;
        const _Float16* srow = c16 + r * CROW + hb * 32;
#pragma unroll
        for (int q = 0; q < 4; q++)
            *(f16x8*)(dst + q * 8) = *(const f16x8*)(srow + q * 8);
    }
}

// ---------- fused attention Mt[k][j] (fp32) + fused bias ----------
__global__ void k_fuse(const float* __restrict__ enc_in_w, const float* __restrict__ enc_in_b,
                       const float* __restrict__ enc_out_w, const float* __restrict__ enc_out_b,
                       const float* __restrict__ sa_in_w, const float* __restrict__ sa_in_b,
                       const float* __restrict__ sa_out_w, const float* __restrict__ sa_out_b,
                       const float* __restrict__ ca_in_w, const float* __restrict__ ca_in_b,
                       const float* __restrict__ ca_out_w, const float* __restrict__ ca_out_b,
                       float* __restrict__ Mt, float* __restrict__ fb) {
    int tid = blockIdx.x * 256 + threadIdx.x;
    int p = tid >> 12, r = tid & 4095, j = r >> 6, k = r & 63;
    int li = p & 1;
    const float *iw, *ib, *ow, *ob;
    if (p < 2)      { iw = enc_in_w + li * 12288; ib = enc_in_b + li * 192; ow = enc_out_w + li * 4096; ob = enc_out_b + li * 64; }
    else if (p < 4) { iw = sa_in_w + li * 12288;  ib = sa_in_b + li * 192;  ow = sa_out_w + li * 4096;  ob = sa_out_b + li * 64; }
    else            { iw = ca_in_w + li * 12288;  ib = ca_in_b + li * 192;  ow = ca_out_w + li * 4096;  ob = ca_out_b + li * 64; }
    float a = 0.f;
    for (int m = 0; m < 64; m++) a = fmaf(ow[j * 64 + m], iw[(128 + m) * 64 + k], a);
    Mt[p * 4096 + k * 64 + j] = a;
    if (k == 0) {
        float fa = ob[j];
        for (int m = 0; m < 64; m++) fa = fmaf(ow[j * 64 + m], ib[128 + m], fa);
        fb[p * 64 + j] = fa;
    }
}

// ---------- transpose f2 / f1 ----------
__global__ void k_f2t(const float* __restrict__ enc_f2_w, const float* __restrict__ dec_f2_w,
                      float* __restrict__ f2t) {
    int tid = blockIdx.x * 256 + threadIdx.x;
    int p = tid >> 14, r = tid & 16383;
    int h = r >> 6, j = r & 63;
    const float* src = (p < 2) ? enc_f2_w + p * 16384 : dec_f2_w + (p - 2) * 16384;
    f2t[tid] = src[j * 256 + h];
}

__global__ void k_f1t(const float* __restrict__ enc_f1_w, const float* __restrict__ dec_f1_w,
                      float* __restrict__ f1t) {
    int tid = blockIdx.x * 256 + threadIdx.x;
    int p = tid >> 14, r = tid & 16383;
    int k = r >> 8, i = r & 255;
    const float* src = (p < 2) ? enc_f1_w + p * 16384 : dec_f1_w + (p - 2) * 16384;
    f1t[tid] = src[i * 64 + k];
}

// ---------- pack transformer weights into fp16 MFMA A-fragment order ----------
#define APK_F1 24576
#define APK_F2 90112
#define APK_TOT 155648
__global__ void k_apack(const float* __restrict__ Mt, const float* __restrict__ f1t,
                        const float* __restrict__ f2t, _Float16* __restrict__ apk) {
    int tid = blockIdx.x * 256 + threadIdx.x;
    float v;
    if (tid < APK_F1) {
        int p = tid >> 12, idx = tid & 4095;
        int mt = idx >> 11, ks = (idx >> 9) & 3, l = (idx >> 3) & 63, d = idx & 7;
        int m = mt * 32 + (l & 31), k = ks * 16 + (l >> 5) * 8 + d;
        v = Mt[p * 4096 + k * 64 + m];
    } else if (tid < APK_F2) {
        int r = tid - APK_F1; int pl = r >> 14, idx = r & 16383;
        int mt = idx >> 11, ks = (idx >> 9) & 3, l = (idx >> 3) & 63, d = idx & 7;
        int m = mt * 32 + (l & 31), k = ks * 16 + (l >> 5) * 8 + d;
        v = f1t[pl * 16384 + k * 256 + m];
    } else {
        int r = tid - APK_F2; int pl = r >> 14, idx = r & 16383;
        int mt = idx >> 13, ks = (idx >> 9) & 15, l = (idx >> 3) & 63, d = idx & 7;
        int m = mt * 32 + (l & 31), k = ks * 16 + (l >> 5) * 8 + d;
        v = f2t[pl * 16384 + k * 64 + m];
    }
    apk[tid] = (_Float16)v;
}

// ---------- MFMA transformer: 1 wave = 64 nodes, no barriers ----------
struct XQ {
    const _Float16* apk; const float* fb;
    const float* ef1b; const float* ef2b; const float* df1b; const float* df2b;
    const float* el1g; const float* el1b; const float* el2g; const float* el2b;
    const float* dl1g; const float* dl1b; const float* dl2g; const float* dl2b;
    const float* dl3g; const float* dl3b;
};

__device__ __forceinline__ void xstore(_Float16* xw, const float y[4][16], int col, int hf) {
#pragma unroll
    for (int nt = 0; nt < 2; nt++)
#pragma unroll
        for (int mt = 0; mt < 2; mt++)
#pragma unroll
            for (int rg = 0; rg < 4; rg++) {
                f16x4 h4;
#pragma unroll
                for (int i = 0; i < 4; i++) h4[i] = (_Float16)y[mt * 2 + nt][rg * 4 + i];
                *(f16x4*)(xw + (nt * 32 + col) * XROW + mt * 32 + rg * 8 + hf * 4) = h4;
            }
}

__device__ __forceinline__ void loadbf(const _Float16* xw, f16x8 bf[2][4], int col, int hf) {
#pragma unroll
    for (int nt = 0; nt < 2; nt++)
#pragma unroll
        for (int ks = 0; ks < 4; ks++)
            bf[nt][ks] = *(const f16x8*)(xw + (nt * 32 + col) * XROW + ks * 16 + hf * 8);
}

__device__ __forceinline__ void lnw(float y[4][16], const float* g, const float* b, int hf) {
#pragma unroll
    for (int nt = 0; nt < 2; nt++) {
        float s = 0.f, q = 0.f;
#pragma unroll
        for (int mt = 0; mt < 2; mt++)
#pragma unroll
            for (int r = 0; r < 16; r++) { float v = y[mt * 2 + nt][r]; s += v; q = fmaf(v, v, q); }
        s += __shfl_xor(s, 32, 64);
        q += __shfl_xor(q, 32, 64);
        float m = s * 0.015625f;
        float var = fmaf(q, 0.015625f, -m * m);
        float rs = rsqrtf(var + 1e-5f);
#pragma unroll
        for (int mt = 0; mt < 2; mt++)
#pragma unroll
            for (int rg = 0; rg < 4; rg++) {
                float4 g4 = *(const float4*)(g + mt * 32 + rg * 8 + hf * 4);
                float4 b4 = *(const float4*)(b + mt * 32 + rg * 8 + hf * 4);
                float* yp = &y[mt * 2 + nt][rg * 4];
                yp[0] = fmaf((yp[0] - m) * rs, g4.x, b4.x);
                yp[1] = fmaf((yp[1] - m) * rs, g4.y, b4.y);
                yp[2] = fmaf((yp[2] - m) * rs, g4.z, b4.z);
                yp[3] = fmaf((yp[3] - m) * rs, g4.w, b4.w);
            }
    }
}

__global__ __launch_bounds__(256, 2) void k_xform(float* __restrict__ yio, XQ P) {
    __shared__ _Float16 xs[4 * 64 * XROW];
    const int t = threadIdx.x;
    const int w = t >> 6, l = t & 63;
    const int col = l & 31, hf = l >> 5;
    _Float16* xw = xs + w * (64 * XROW);
    const int nb = blockIdx.x * 256 + w * 64;
    const int nn0 = nb + col, nn1 = nb + 32 + col;
    const int nc0 = nn0 < NN ? nn0 : NN - 1;
    const int nc1 = nn1 < NN ? nn1 : NN - 1;

    float y[4][16];
#pragma unroll
    for (int mt = 0; mt < 2; mt++)
#pragma unroll
        for (int nt = 0; nt < 2; nt++) {
            const float* src = yio + (size_t)(nt ? nc1 : nc0) * 64 + mt * 32 + hf * 4;
#pragma unroll
            for (int rg = 0; rg < 4; rg++) {
                float4 v = *(const float4*)(src + rg * 8);
                float* yp = &y[mt * 2 + nt][rg * 4];
                yp[0] = v.x; yp[1] = v.y; yp[2] = v.z; yp[3] = v.w;
            }
        }
    f16x8 bf[2][4];
    xstore(xw, y, col, hf);
    loadbf(xw, bf, col, hf);

#pragma unroll 1
    for (int layer = 0; layer < 4; layer++) {
        const bool enc = layer < 2;
        const int li = enc ? layer : layer - 2;
        const int nat = enc ? 1 : 2;
#pragma unroll 1
        for (int at = 0; at < nat; at++) {
            const int p = enc ? layer : (at == 0 ? 2 + li : 4 + li);
            const _Float16* apA = P.apk + p * 4096;
            const float* fbp = P.fb + p * 64;
            f32x16 acc[4];
#pragma unroll
            for (int mt = 0; mt < 2; mt++) {
                f32x16 a;
#pragma unroll
                for (int rg = 0; rg < 4; rg++) {
                    float4 b4 = *(const float4*)(fbp + mt * 32 + rg * 8 + hf * 4);
                    a[rg * 4 + 0] = b4.x; a[rg * 4 + 1] = b4.y; a[rg * 4 + 2] = b4.z; a[rg * 4 + 3] = b4.w;
                }
                acc[mt * 2 + 0] = a; acc[mt * 2 + 1] = a;
            }
#pragma unroll
            for (int mt = 0; mt < 2; mt++)
#pragma unroll
                for (int ks = 0; ks < 4; ks++) {
                    f16x8 af = *(const f16x8*)(apA + ((mt * 4 + ks) * 64 + l) * 8);
                    acc[mt * 2 + 0] = __builtin_amdgcn_mfma_f32_32x32x16_f16(af, bf[0][ks], acc[mt * 2 + 0], 0, 0, 0);
                    acc[mt * 2 + 1] = __builtin_amdgcn_mfma_f32_32x32x16_f16(af, bf[1][ks], acc[mt * 2 + 1], 0, 0, 0);
                }
#pragma unroll
            for (int ti = 0; ti < 4; ti++)
#pragma unroll
                for (int r = 0; r < 16; r++) y[ti][r] += acc[ti][r];
            const float *g, *b;
            if (enc)          { g = P.el1g + li * 64; b = P.el1b + li * 64; }
            else if (at == 0) { g = P.dl1g + li * 64; b = P.dl1b + li * 64; }
            else              { g = P.dl2g + li * 64; b = P.dl2b + li * 64; }
            lnw(y, g, b, hf);
            xstore(xw, y, col, hf);
            loadbf(xw, bf, col, hf);
        }
        const int pl = enc ? layer : 2 + li;
        const _Float16* apF1 = P.apk + APK_F1 + pl * 16384;
        const _Float16* apF2 = P.apk + APK_F2 + pl * 16384;
        const float* f1bp = (enc ? P.ef1b : P.df1b) + li * 256;
        const float* f2bp = (enc ? P.ef2b : P.df2b) + li * 64;
        f32x16 out[4];
#pragma unroll
        for (int mt = 0; mt < 2; mt++) {
            f32x16 a;
#pragma unroll
            for (int rg = 0; rg < 4; rg++) {
                float4 b4 = *(const float4*)(f2bp + mt * 32 + rg * 8 + hf * 4);
                a[rg * 4 + 0] = b4.x; a[rg * 4 + 1] = b4.y; a[rg * 4 + 2] = b4.z; a[rg * 4 + 3] = b4.w;
            }
            out[mt * 2 + 0] = a; out[mt * 2 + 1] = a;
        }
#pragma unroll 1
        for (int c = 0; c < 4; c++) {
            f32x16 ha[4];
#pragma unroll
            for (int hmt = 0; hmt < 2; hmt++) {
                f32x16 a;
#pragma unroll
                for (int rg = 0; rg < 4; rg++) {
                    float4 b4 = *(const float4*)(f1bp + c * 64 + hmt * 32 + rg * 8 + hf * 4);
                    a[rg * 4 + 0] = b4.x; a[rg * 4 + 1] = b4.y; a[rg * 4 + 2] = b4.z; a[rg * 4 + 3] = b4.w;
                }
                ha[hmt * 2 + 0] = a; ha[hmt * 2 + 1] = a;
            }
#pragma unroll
            for (int hmt = 0; hmt < 2; hmt++)
#pragma unroll
                for (int ks = 0; ks < 4; ks++) {
                    f16x8 af = *(const f16x8*)(apF1 + (((2 * c + hmt) * 4 + ks) * 64 + l) * 8);
                    ha[hmt * 2 + 0] = __builtin_amdgcn_mfma_f32_32x32x16_f16(af, bf[0][ks], ha[hmt * 2 + 0], 0, 0, 0);
                    ha[hmt * 2 + 1] = __builtin_amdgcn_mfma_f32_32x32x16_f16(af, bf[1][ks], ha[hmt * 2 + 1], 0, 0, 0);
                }
#pragma unroll
            for (int nt = 0; nt < 2; nt++)
#pragma unroll
                for (int hmt = 0; hmt < 2; hmt++)
#pragma unroll
                    for (int rg = 0; rg < 4; rg++) {
                        f16x4 h4;
#pragma unroll
                        for (int i = 0; i < 4; i++)
                            h4[i] = (_Float16)fmaxf(ha[hmt * 2 + nt][rg * 4 + i], 0.f);
                        *(f16x4*)(xw + (nt * 32 + col) * XROW + hmt * 32 + rg * 8 + hf * 4) = h4;
                    }
#pragma unroll
            for (int ksl = 0; ksl < 4; ksl++) {
                f16x8 hbf0 = *(const f16x8*)(xw + col * XROW + ksl * 16 + hf * 8);
                f16x8 hbf1 = *(const f16x8*)(xw + (32 + col) * XROW + ksl * 16 + hf * 8);
#pragma unroll
                for (int mt = 0; mt < 2; mt++) {
                    f16x8 af = *(const f16x8*)(apF2 + ((mt * 16 + c * 4 + ksl) * 64 + l) * 8);
                    out[mt * 2 + 0] = __builtin_amdgcn_mfma_f32_32x32x16_f16(af, hbf0, out[mt * 2 + 0], 0, 0, 0);
                    out[mt * 2 + 1] = __builtin_amdgcn_mfma_f32_32x32x16_f16(af, hbf1, out[mt * 2 + 1], 0, 0, 0);
                }
            }
        }
#pragma unroll
        for (int ti = 0; ti < 4; ti++)
#pragma unroll
            for (int r = 0; r < 16; r++) y[ti][r] += out[ti][r];
        const float* g2 = (enc ? P.el2g : P.dl3g) + li * 64;
        const float* b2 = (enc ? P.el2b : P.dl3b) + li * 64;
        lnw(y, g2, b2, hf);
        if (layer < 3) {
            xstore(xw, y, col, hf);
            loadbf(xw, bf, col, hf);
        }
    }
#pragma unroll
    for (int mt = 0; mt < 2; mt++)
#pragma unroll
        for (int nt = 0; nt < 2; nt++) {
            int n = nt ? nn1 : nn0;
            if (n < NN) {
                float* dst = yio + (size_t)n * 64 + mt * 32 + hf * 4;
#pragma unroll
                for (int rg = 0; rg < 4; rg++) {
                    const float* yp = &y[mt * 2 + nt][rg * 4];
                    *(float4*)(dst + rg * 8) = make_float4(yp[0], yp[1], yp[2], yp[3]);
                }
            }
        }
}

// ---------- global mean pool ----------
__global__ void k_pool(const float* __restrict__ y, const int* __restrict__ batch,
                       float* __restrict__ pooled) {
    int b = blockIdx.x;
    int t = threadIdx.x;
    int ch = t & 63, r = t >> 6;
    int lo = 0, hi = NN;
    while (lo < hi) { int mid = (lo + hi) >> 1; if (batch[mid] < b) lo = mid + 1; else hi = mid; }
    int st = lo;
    hi = NN;
    while (lo < hi) { int mid = (lo + hi) >> 1; if (batch[mid] < b + 1) lo = mid + 1; else hi = mid; }
    int en = lo;
    float s = 0.f;
    for (int i = st + r; i < en; i += 4) s += y[(size_t)i * 64 + ch];
    __shared__ float red[256];
    red[t] = s;
    __syncthreads();
    if (t < 64) {
        float tot = red[t] + red[t + 64] + red[t + 128] + red[t + 192];
        int cnt = en - st; if (cnt < 1) cnt = 1;
        pooled[b * 64 + t] = tot / (float)cnt;
    }
}

// ---------- final fc ----------
__global__ void k_fc(const float* __restrict__ pooled, const float* __restrict__ fcw,
                     const float* __restrict__ fcb, float* __restrict__ out) {
    int tid = blockIdx.x * 256 + threadIdx.x;
    if (tid >= NG * 33) return;
    int g = tid / 33, o = tid - g * 33;
    const float* p = pooled + g * 64;
    const float* w = fcw + o * 64;
    float a0 = 0.f, a1 = 0.f, a2 = 0.f, a3 = 0.f;
#pragma unroll
    for (int k = 0; k < 16; k++) {
        a0 = fmaf(p[4 * k], w[4 * k], a0);
        a1 = fmaf(p[4 * k + 1], w[4 * k + 1], a1);
        a2 = fmaf(p[4 * k + 2], w[4 * k + 2], a2);
        a3 = fmaf(p[4 * k + 3], w[4 * k + 3], a3);
    }
    out[tid] = fcb[o] + (a0 + a1) + (a2 + a3);
}

extern "C" void kernel_launch(void* const* d_in, const int* in_sizes, int n_in,
                              void* d_out, int out_size, void* d_ws, size_t ws_size,
                              hipStream_t stream) {
    (void)in_sizes; (void)n_in; (void)out_size; (void)ws_size;
    char* ws = (char*)d_ws;
    size_t o = 0;
    auto A = [&](size_t b) { size_t r = o; o += (b + 255) & ~(size_t)255; return r; };
    _Float16* h1p = (_Float16*)(ws + A((size_t)NN * 128 * 2));
    _Float16* h2h = (_Float16*)(ws + A((size_t)NN * 64 * 2));
    _Float16* g1h = (_Float16*)(ws + A((size_t)NN * 128 * 2));
    float* f_g2  = (float*)(ws + A((size_t)NN * 64 * 4));
    float* f_asp = (float*)(ws + A((size_t)NN * 4 * 4));
    float* f_ad1 = (float*)(ws + A((size_t)NN * 4 * 4));
    float* f_as2 = (float*)(ws + A((size_t)NN * 4 * 4));
    float* f_ad2 = (float*)(ws + A((size_t)NN * 4 * 4));
    int* i_off   = (int*)(ws + A((size_t)(NN + 1) * 4));
    int* i_cur   = (int*)(ws + A((size_t)NN * 4));
    int* i_deg   = (int*)(ws + A((size_t)NN * 4));
    int* i_bsum  = (int*)(ws + A((size_t)1024 * 4));
    int* i_srcs  = (int*)(ws + A((size_t)ETOT * 4));
    float* f_Mt  = (float*)(ws + A((size_t)6 * 4096 * 4));
    float* f_fb  = (float*)(ws + A((size_t)6 * 64 * 4));
    float* f_f1t = (float*)(ws + A((size_t)4 * 16384 * 4));
    float* f_f2t = (float*)(ws + A((size_t)4 * 16384 * 4));
    _Float16* f_apk = (_Float16*)(ws + A((size_t)APK_TOT * 2));
    _Float16* apw2  = (_Float16*)(ws + A((size_t)8192 * 2));
    float* f_pool= (float*)(ws + A((size_t)NG * 64 * 4));

    const float* x   = (const float*)d_in[0];
    const int* ei    = (const int*)d_in[1];
    const int* batch = (const int*)d_in[2];
    #define F32(i) ((const float*)d_in[i])

    hipMemsetAsync(i_deg, 0, (size_t)NN * 4, stream);
    k_h1<<<NN * 64 / 256, 256, 0, stream>>>(x, F32(3), F32(4), F32(5), h1p);
    k_att1<<<(NN * 4 + 255) / 256, 256, 0, stream>>>(h1p, F32(6), F32(7), f_asp, f_ad1);
    k_count<<<(ETOT + 255) / 256, 256, 0, stream>>>(ei, i_deg);
    k_scan1<<<98, 1024, 0, stream>>>(i_deg, i_off, i_bsum);
    k_scan2<<<1, 128, 0, stream>>>(i_bsum);
    k_scan3<<<98, 1024, 0, stream>>>(i_off, i_bsum, i_cur);
    k_scatter<<<(ETOT + 255) / 256, 256, 0, stream>>>(ei, i_cur, i_srcs);
    k_gat1<<<NN * 64 / 256, 256, 0, stream>>>(i_off, i_srcs, f_asp, f_ad1, h1p, F32(8), g1h);
    k_wpack<<<32, 256, 0, stream>>>(F32(9), apw2);
    k_h2m<<<(NN / 32 + 3) / 4, 256, 0, stream>>>(g1h, apw2, h2h);
    k_att2<<<(NN * 4 + 255) / 256, 256, 0, stream>>>(h2h, F32(10), F32(11), f_as2, f_ad2);
    k_gat2<<<NN * 64 / 256, 256, 0, stream>>>(i_off, i_srcs, f_as2, f_ad2, h2h, F32(12), f_g2);
    k_fuse<<<24576 / 256, 256, 0, stream>>>(F32(13), F32(14), F32(15), F32(16),
                                            F32(25), F32(26), F32(27), F32(28),
                                            F32(29), F32(30), F32(31), F32(32),
                                            f_Mt, f_fb);
    k_f1t<<<65536 / 256, 256, 0, stream>>>(F32(17), F32(33), f_f1t);
    k_f2t<<<65536 / 256, 256, 0, stream>>>(F32(19), F32(35), f_f2t);
    k_apack<<<APK_TOT / 256, 256, 0, stream>>>(f_Mt, f_f1t, f_f2t, f_apk);
    XQ Q;
    Q.apk = f_apk; Q.fb = f_fb;
    Q.ef1b = F32(18); Q.ef2b = F32(20);
    Q.df1b = F32(34); Q.df2b = F32(36);
    Q.el1g = F32(21); Q.el1b = F32(22); Q.el2g = F32(23); Q.el2b = F32(24);
    Q.dl1g = F32(37); Q.dl1b = F32(38); Q.dl2g = F32(39); Q.dl2b = F32(40);
    Q.dl3g = F32(41); Q.dl3b = F32(42);
    k_xform<<<(NN + 255) / 256, 256, 0, stream>>>(f_g2, Q);
    k_pool<<<NG, 256, 0, stream>>>(f_g2, batch, f_pool);
    k_fc<<<(NG * 33 + 255) / 256, 256, 0, stream>>>(f_pool, F32(43), F32(44), (float*)d_out);
    #undef F32
}

// Round 8
// 663.959 us; speedup vs baseline: 7.5420x; 1.0831x over previous
//
#include <hip/hip_runtime.h>

#define NN 100000
#define NE 1600000
#define NG 1000
#define ETOT (NE + NN)
#define NODES_PER_GRP 12500  // NN/8, XCD-affine binning for count/scatter

typedef _Float16 f16x8 __attribute__((ext_vector_type(8)));
typedef _Float16 f16x4 __attribute__((ext_vector_type(4)));
typedef _Float16 f16x2 __attribute__((ext_vector_type(2)));
typedef float f32x16 __attribute__((ext_vector_type(16)));
#define XROW 72  // xform LDS row stride (halves)

// ---------- h1 paired fp16: h1p[n][jp] = (ch jp, ch jp+64); feature_fc fused ----------
__global__ void k_h1(const float* __restrict__ x, const float* __restrict__ ffw,
                     const float* __restrict__ ffb, const float* __restrict__ g1w,
                     _Float16* __restrict__ h1p) {
    int tid = blockIdx.x * 256 + threadIdx.x;  // NN*64 exact
    int n = tid >> 6, jp = tid & 63;
    float xv[4];
#pragma unroll
    for (int k = 0; k < 4; k++) xv[k] = x[n * 4 + k];
    float h0[8];
#pragma unroll
    for (int o = 0; o < 8; o++) {
        float a = ffb[o];
#pragma unroll
        for (int k = 0; k < 4; k++) a = fmaf(xv[k], ffw[o * 4 + k], a);
        h0[o] = a;
    }
    const float* w0 = g1w + jp * 8;
    const float* w1 = g1w + (jp + 64) * 8;
    float a0 = 0.f, a1 = 0.f;
#pragma unroll
    for (int k = 0; k < 8; k++) { a0 = fmaf(h0[k], w0[k], a0); a1 = fmaf(h0[k], w1[k], a1); }
    f16x2 r; r[0] = (_Float16)a0; r[1] = (_Float16)a1;
    *(f16x2*)(h1p + ((size_t)n * 64 + jp) * 2) = r;
}

// ---------- layer-1 attention coeffs from paired h1; asp packed {h0,h2,h1,h3} ----------
__global__ void k_att1(const _Float16* __restrict__ h1p, const float* __restrict__ asw,
                       const float* __restrict__ adw, float* __restrict__ asp,
                       float* __restrict__ ad_) {
    int tid = blockIdx.x * 256 + threadIdx.x;
    if (tid >= NN * 4) return;
    int n = tid >> 2, h = tid & 3;
    const _Float16* base = h1p + (size_t)n * 128;
    const float* ws_ = asw + h * 32;
    const float* wd_ = adw + h * 32;
    int slot = h >> 1, poff = (h & 1) * 32;
    float a = 0.f, d = 0.f;
#pragma unroll
    for (int c = 0; c < 32; c++) {
        float hv = (float)base[(poff + c) * 2 + slot];
        a = fmaf(hv, ws_[c], a); d = fmaf(hv, wd_[c], d);
    }
    asp[n * 4 + ((h >> 1) + ((h & 1) << 1))] = a;
    ad_[n * 4 + h] = d;
}

// ---------- layer-2 attention coeffs ----------
__global__ void k_att2(const _Float16* __restrict__ h2h, const float* __restrict__ asw,
                       const float* __restrict__ adw, float* __restrict__ as_,
                       float* __restrict__ ad_) {
    int tid = blockIdx.x * 256 + threadIdx.x;
    if (tid >= NN * 4) return;
    int n = tid >> 2, h = tid & 3;
    const _Float16* hp = h2h + (size_t)n * 64 + h * 16;
    const float* ws_ = asw + h * 16;
    const float* wd_ = adw + h * 16;
    float a = 0.f, d = 0.f;
#pragma unroll
    for (int c = 0; c < 16; c++) {
        float hv = (float)hp[c];
        a = fmaf(hv, ws_[c], a); d = fmaf(hv, wd_[c], d);
    }
    as_[tid] = a; ad_[tid] = d;
}

// ---------- CSR build: XCD-affine binned count & scatter ----------
// group g = blockIdx&7 handles dst in [g*12500,(g+1)*12500): that group's counter
// slice (50KB) and CSR slice (~850KB) stay in one XCD's L2 -> no cross-XCD line
// bouncing, no 16x write amplification. Mapping blockIdx%8->XCD is a perf
// heuristic only; correctness is order-free (atomic slot allocation).
__global__ void k_count(const int* __restrict__ ei, int* __restrict__ deg) {
    int g = blockIdx.x & 7;
    int bi = blockIdx.x >> 3;
    int nb = gridDim.x >> 3;
    int lo = g * NODES_PER_GRP, hi = lo + NODES_PER_GRP;
    for (int e = bi * 256 + threadIdx.x; e < ETOT; e += nb * 256) {
        int dst = (e < NE) ? ei[NE + e] : (e - NE);
        if (dst >= lo && dst < hi) atomicAdd(&deg[dst], 1);
    }
}

__global__ void k_scan1(const int* __restrict__ deg, int* __restrict__ offs, int* __restrict__ bsum) {
    __shared__ int s[1024];
    int tid = threadIdx.x;
    int i = blockIdx.x * 1024 + tid;
    int v = (i < NN) ? deg[i] : 0;
    s[tid] = v;
    __syncthreads();
    for (int d = 1; d < 1024; d <<= 1) {
        int t = 0;
        if (tid >= d) t = s[tid - d];
        __syncthreads();
        if (tid >= d) s[tid] += t;
        __syncthreads();
    }
    if (i < NN) offs[i] = s[tid] - v;
    if (tid == 1023) bsum[blockIdx.x] = s[tid];
}

__global__ void k_scan2(int* __restrict__ bsum) {
    __shared__ int s[128];
    int tid = threadIdx.x;
    int v = (tid < 98) ? bsum[tid] : 0;
    s[tid] = v;
    __syncthreads();
    for (int d = 1; d < 128; d <<= 1) {
        int t = 0;
        if (tid >= d) t = s[tid - d];
        __syncthreads();
        if (tid >= d) s[tid] += t;
        __syncthreads();
    }
    bsum[tid] = s[tid] - v;
}

__global__ void k_scan3(int* __restrict__ offs, const int* __restrict__ bsum, int* __restrict__ cur) {
    int i = blockIdx.x * 1024 + threadIdx.x;
    if (i < NN) {
        int v = offs[i] + bsum[blockIdx.x];
        offs[i] = v; cur[i] = v;
    }
    if (i == 0) offs[NN] = ETOT;
}

__global__ void k_scatter(const int* __restrict__ ei, int* __restrict__ cur, int* __restrict__ srcs) {
    int g = blockIdx.x & 7;
    int bi = blockIdx.x >> 3;
    int nb = gridDim.x >> 3;
    int lo = g * NODES_PER_GRP, hi = lo + NODES_PER_GRP;
    for (int e = bi * 256 + threadIdx.x; e < ETOT; e += nb * 256) {
        int dst = (e < NE) ? ei[NE + e] : (e - NE);
        if (dst >= lo && dst < hi) {
            int src = (e < NE) ? ei[e] : dst;
            int p = atomicAdd(&cur[dst], 1);
            srcs[p] = src;
        }
    }
}

// ---------- GAT layer 1: single-pass softmax+aggregate, paired fp16 gathers ----------
__global__ void k_gat1(const int* __restrict__ offs, const int* __restrict__ srcs,
                       const float* __restrict__ asp, const float* __restrict__ ad_,
                       const _Float16* __restrict__ h1p, const float* __restrict__ bias,
                       _Float16* __restrict__ g1h) {
    int wid = (blockIdx.x * 256 + threadIdx.x) >> 6;
    int lane = threadIdx.x & 63;
    if (wid >= NN) return;
    int off = offs[wid];
    int deg = offs[wid + 1] - off;
    int hA = lane >> 5;
    float adA = ad_[wid * 4 + hA];
    float adB = ad_[wid * 4 + hA + 2];
    float ws0 = 0.f, ws1 = 0.f, ac0 = 0.f, ac1 = 0.f;
    float ws0b = 0.f, ws1b = 0.f, ac0b = 0.f, ac1b = 0.f;
    for (int base = 0; base < deg; base += 64) {
        int idx = off + base + lane; if (idx >= ETOT) idx = ETOT - 1;
        int sv = srcs[idx];
        int cnt = deg - base; if (cnt > 64) cnt = 64;
        int j = 0;
        for (; j + 2 <= cnt; j += 2) {
            int sa = __shfl(sv, j, 64), sb = __shfl(sv, j + 1, 64);
            float2 aa = *(const float2*)(asp + sa * 4 + 2 * hA);
            float2 ab = *(const float2*)(asp + sb * 4 + 2 * hA);
            f16x2 hpa = *(const f16x2*)(h1p + ((size_t)sa * 64 + lane) * 2);
            f16x2 hpb = *(const f16x2*)(h1p + ((size_t)sb * 64 + lane) * 2);
            float e0 = aa.x + adA; e0 = fmaxf(e0, 0.2f * e0);
            float e1 = aa.y + adB; e1 = fmaxf(e1, 0.2f * e1);
            float w0 = __expf(e0), w1 = __expf(e1);
            ws0 += w0; ws1 += w1;
            ac0 = fmaf(w0, (float)hpa[0], ac0); ac1 = fmaf(w1, (float)hpa[1], ac1);
            float e0b = ab.x + adA; e0b = fmaxf(e0b, 0.2f * e0b);
            float e1b = ab.y + adB; e1b = fmaxf(e1b, 0.2f * e1b);
            float w0b = __expf(e0b), w1b = __expf(e1b);
            ws0b += w0b; ws1b += w1b;
            ac0b = fmaf(w0b, (float)hpb[0], ac0b); ac1b = fmaf(w1b, (float)hpb[1], ac1b);
        }
        if (j < cnt) {
            int sa = __shfl(sv, j, 64);
            float2 aa = *(const float2*)(asp + sa * 4 + 2 * hA);
            f16x2 hpa = *(const f16x2*)(h1p + ((size_t)sa * 64 + lane) * 2);
            float e0 = aa.x + adA; e0 = fmaxf(e0, 0.2f * e0);
            float e1 = aa.y + adB; e1 = fmaxf(e1, 0.2f * e1);
            float w0 = __expf(e0), w1 = __expf(e1);
            ws0 += w0; ws1 += w1;
            ac0 = fmaf(w0, (float)hpa[0], ac0); ac1 = fmaf(w1, (float)hpa[1], ac1);
        }
    }
    ws0 += ws0b; ws1 += ws1b; ac0 += ac0b; ac1 += ac1b;
    float v0 = ac0 / ws0 + bias[lane];      v0 = fmaxf(v0, 0.01f * v0);
    float v1 = ac1 / ws1 + bias[lane + 64]; v1 = fmaxf(v1, 0.01f * v1);
    g1h[(size_t)wid * 128 + lane] = (_Float16)v0;
    g1h[(size_t)wid * 128 + lane + 64] = (_Float16)v1;
}

// ---------- GAT layer 2 ----------
__global__ void k_gat2(const int* __restrict__ offs, const int* __restrict__ srcs,
                       const float* __restrict__ as_, const float* __restrict__ ad_,
                       const _Float16* __restrict__ h2h, const float* __restrict__ bias,
                       float* __restrict__ g2) {
    int wid = (blockIdx.x * 256 + threadIdx.x) >> 6;
    int lane = threadIdx.x & 63;
    if (wid >= NN) return;
    int off = offs[wid];
    int deg = offs[wid + 1] - off;
    int hd = lane >> 4;
    float adA = ad_[wid * 4 + hd];
    float ws = 0.f, ac = 0.f, wsb = 0.f, acb = 0.f;
    for (int base = 0; base < deg; base += 64) {
        int idx = off + base + lane; if (idx >= ETOT) idx = ETOT - 1;
        int sv = srcs[idx];
        int cnt = deg - base; if (cnt > 64) cnt = 64;
        int j = 0;
        for (; j + 2 <= cnt; j += 2) {
            int sa = __shfl(sv, j, 64), sb = __shfl(sv, j + 1, 64);
            float ea = as_[sa * 4 + hd] + adA; ea = fmaxf(ea, 0.2f * ea);
            float eb = as_[sb * 4 + hd] + adA; eb = fmaxf(eb, 0.2f * eb);
            float ha = (float)h2h[(size_t)sa * 64 + lane];
            float hb = (float)h2h[(size_t)sb * 64 + lane];
            float wa = __expf(ea), wb = __expf(eb);
            ws += wa; ac = fmaf(wa, ha, ac);
            wsb += wb; acb = fmaf(wb, hb, acb);
        }
        if (j < cnt) {
            int sa = __shfl(sv, j, 64);
            float ea = as_[sa * 4 + hd] + adA; ea = fmaxf(ea, 0.2f * ea);
            float wa = __expf(ea);
            ws += wa; ac = fmaf(wa, (float)h2h[(size_t)sa * 64 + lane], ac);
        }
    }
    ws += wsb; ac += acb;
    float v = ac / ws + bias[lane]; v = fmaxf(v, 0.01f * v);
    g2[(size_t)wid * 64 + lane] = v;
}

// ---------- pack gat2_w into MFMA A-fragments (fp16) ----------
__global__ void k_wpack(const float* __restrict__ g2w, _Float16* __restrict__ apw2) {
    int tid = blockIdx.x * 256 + threadIdx.x;  // 8192 exact
    int mtks = tid >> 9, l = (tid >> 3) & 63, d = tid & 7;
    int mt = mtks >> 3, ks = mtks & 7;
    int m = mt * 32 + (l & 31), k = ks * 16 + (l >> 5) * 8 + d;
    apw2[tid] = (_Float16)g2w[m * 128 + k];
}

// ---------- h2[N,64] fp16 = g1h[N,128] @ gat2_w.T via MFMA, 1 wave = 32 nodes ----------
#define GROW 136
#define CROW 72
__global__ __launch_bounds__(256, 2) void k_h2m(const _Float16* __restrict__ g1h,
                                                const _Float16* __restrict__ apw2,
                                                _Float16* __restrict__ h2h) {
    __shared__ _Float16 ls[4 * 32 * GROW];
    const int t = threadIdx.x;
    const int w = t >> 6, l = t & 63;
    const int col = l & 31, hf = l >> 5;
    const int wv = blockIdx.x * 4 + w;
    const int nb = wv * 32;
    if (nb >= NN) return;
    _Float16* g16 = ls + w * (32 * GROW);
    const int r = l >> 1, hb = l & 1;
    {
        int nr = nb + r; if (nr >= NN) nr = NN - 1;
        const _Float16* src = g1h + (size_t)nr * 128 + hb * 64;
        _Float16* dst = g16 + r * GROW + hb * 64;
#pragma unroll
        for (int q = 0; q < 8; q++)
            *(f16x8*)(dst + q * 8) = *(const f16x8*)(src + q * 8);
    }
    f16x8 bf[8];
#pragma unroll
    for (int ks = 0; ks < 8; ks++)
        bf[ks] = *(const f16x8*)(g16 + col * GROW + ks * 16 + hf * 8);
    f32x16 acc0, acc1;
#pragma unroll
    for (int i = 0; i < 16; i++) { acc0[i] = 0.f; acc1[i] = 0.f; }
#pragma unroll
    for (int ks = 0; ks < 8; ks++) {
        f16x8 a0 = *(const f16x8*)(apw2 + ((0 * 8 + ks) * 64 + l) * 8);
        f16x8 a1 = *(const f16x8*)(apw2 + ((1 * 8 + ks) * 64 + l) * 8);
        acc0 = __builtin_amdgcn_mfma_f32_32x32x16_f16(a0, bf[ks], acc0, 0, 0, 0);
        acc1 = __builtin_amdgcn_mfma_f32_32x32x16_f16(a1, bf[ks], acc1, 0, 0, 0);
    }
    _Float16* c16 = g16;
#pragma unroll
    for (int rg = 0; rg < 4; rg++) {
        f16x4 h0, h1;
#pragma unroll
        for (int i = 0; i < 4; i++) { h0[i] = (_Float16)acc0[rg * 4 + i]; h1[i] = (_Float16)acc1[rg * 4 + i]; }
        *(f16x4*)(c16 + col * CROW + rg * 8 + hf * 4) = h0;
        *(f16x4*)(c16 + col * CROW + 32 + rg * 8 + hf * 4) = h1;
    }
    if (nb + r < NN) {
        _Float16* dst = h2h + (size_t)(nb + r) * 64 + hb * 32;
        const _Float16* srow = c16 + r * CROW + hb * 32;
#pragma unroll
        for (int q = 0; q < 4; q++)
            *(f16x8*)(dst + q * 8) = *(const f16x8*)(srow + q * 8);
    }
}

// ---------- fused attention Mt[k][j] (fp32) + fused bias ----------
__global__ void k_fuse(const float* __restrict__ enc_in_w, const float* __restrict__ enc_in_b,
                       const float* __restrict__ enc_out_w, const float* __restrict__ enc_out_b,
                       const float* __restrict__ sa_in_w, const float* __restrict__ sa_in_b,
                       const float* __restrict__ sa_out_w, const float* __restrict__ sa_out_b,
                       const float* __restrict__ ca_in_w, const float* __restrict__ ca_in_b,
                       const float* __restrict__ ca_out_w, const float* __restrict__ ca_out_b,
                       float* __restrict__ Mt, float* __restrict__ fb) {
    int tid = blockIdx.x * 256 + threadIdx.x;
    int p = tid >> 12, r = tid & 4095, j = r >> 6, k = r & 63;
    int li = p & 1;
    const float *iw, *ib, *ow, *ob;
    if (p < 2)      { iw = enc_in_w + li * 12288; ib = enc_in_b + li * 192; ow = enc_out_w + li * 4096; ob = enc_out_b + li * 64; }
    else if (p < 4) { iw = sa_in_w + li * 12288;  ib = sa_in_b + li * 192;  ow = sa_out_w + li * 4096;  ob = sa_out_b + li * 64; }
    else            { iw = ca_in_w + li * 12288;  ib = ca_in_b + li * 192;  ow = ca_out_w + li * 4096;  ob = ca_out_b + li * 64; }
    float a = 0.f;
    for (int m = 0; m < 64; m++) a = fmaf(ow[j * 64 + m], iw[(128 + m) * 64 + k], a);
    Mt[p * 4096 + k * 64 + j] = a;
    if (k == 0) {
        float fa = ob[j];
        for (int m = 0; m < 64; m++) fa = fmaf(ow[j * 64 + m], ib[128 + m], fa);
        fb[p * 64 + j] = fa;
    }
}

// ---------- transpose f2 / f1 ----------
__global__ void k_f2t(const float* __restrict__ enc_f2_w, const float* __restrict__ dec_f2_w,
                      float* __restrict__ f2t) {
    int tid = blockIdx.x * 256 + threadIdx.x;
    int p = tid >> 14, r = tid & 16383;
    int h = r >> 6, j = r & 63;
    const float* src = (p < 2) ? enc_f2_w + p * 16384 : dec_f2_w + (p - 2) * 16384;
    f2t[tid] = src[j * 256 + h];
}

__global__ void k_f1t(const float* __restrict__ enc_f1_w, const float* __restrict__ dec_f1_w,
                      float* __restrict__ f1t) {
    int tid = blockIdx.x * 256 + threadIdx.x;
    int p = tid >> 14, r = tid & 16383;
    int k = r >> 8, i = r & 255;
    const float* src = (p < 2) ? enc_f1_w + p * 16384 : dec_f1_w + (p - 2) * 16384;
    f1t[tid] = src[i * 64 + k];
}

// ---------- pack transformer weights into fp16 MFMA A-fragment order ----------
#define APK_F1 24576
#define APK_F2 90112
#define APK_TOT 155648
__global__ void k_apack(const float* __restrict__ Mt, const float* __restrict__ f1t,
                        const float* __restrict__ f2t, _Float16* __restrict__ apk) {
    int tid = blockIdx.x * 256 + threadIdx.x;
    float v;
    if (tid < APK_F1) {
        int p = tid >> 12, idx = tid & 4095;
        int mt = idx >> 11, ks = (idx >> 9) & 3, l = (idx >> 3) & 63, d = idx & 7;
        int m = mt * 32 + (l & 31), k = ks * 16 + (l >> 5) * 8 + d;
        v = Mt[p * 4096 + k * 64 + m];
    } else if (tid < APK_F2) {
        int r = tid - APK_F1; int pl = r >> 14, idx = r & 16383;
        int mt = idx >> 11, ks = (idx >> 9) & 3, l = (idx >> 3) & 63, d = idx & 7;
        int m = mt * 32 + (l & 31), k = ks * 16 + (l >> 5) * 8 + d;
        v = f1t[pl * 16384 + k * 256 + m];
    } else {
        int r = tid - APK_F2; int pl = r >> 14, idx = r & 16383;
        int mt = idx >> 13, ks = (idx >> 9) & 15, l = (idx >> 3) & 63, d = idx & 7;
        int m = mt * 32 + (l & 31), k = ks * 16 + (l >> 5) * 8 + d;
        v = f2t[pl * 16384 + k * 64 + m];
    }
    apk[tid] = (_Float16)v;
}

// ---------- MFMA transformer: 1 wave = 64 nodes, no barriers ----------
struct XQ {
    const _Float16* apk; const float* fb;
    const float* ef1b; const float* ef2b; const float* df1b; const float* df2b;
    const float* el1g; const float* el1b; const float* el2g; const float* el2b;
    const float* dl1g; const float* dl1b; const float* dl2g; const float* dl2b;
    const float* dl3g; const float* dl3b;
};

__device__ __forceinline__ void xstore(_Float16* xw, const float y[4][16], int col, int hf) {
#pragma unroll
    for (int nt = 0; nt < 2; nt++)
#pragma unroll
        for (int mt = 0; mt < 2; mt++)
#pragma unroll
            for (int rg = 0; rg < 4; rg++) {
                f16x4 h4;
#pragma unroll
                for (int i = 0; i < 4; i++) h4[i] = (_Float16)y[mt * 2 + nt][rg * 4 + i];
                *(f16x4*)(xw + (nt * 32 + col) * XROW + mt * 32 + rg * 8 + hf * 4) = h4;
            }
}

__device__ __forceinline__ void loadbf(const _Float16* xw, f16x8 bf[2][4], int col, int hf) {
#pragma unroll
    for (int nt = 0; nt < 2; nt++)
#pragma unroll
        for (int ks = 0; ks < 4; ks++)
            bf[nt][ks] = *(const f16x8*)(xw + (nt * 32 + col) * XROW + ks * 16 + hf * 8);
}

__device__ __forceinline__ void lnw(float y[4][16], const float* g, const float* b, int hf) {
#pragma unroll
    for (int nt = 0; nt < 2; nt++) {
        float s = 0.f, q = 0.f;
#pragma unroll
        for (int mt = 0; mt < 2; mt++)
#pragma unroll
            for (int r = 0; r < 16; r++) { float v = y[mt * 2 + nt][r]; s += v; q = fmaf(v, v, q); }
        s += __shfl_xor(s, 32, 64);
        q += __shfl_xor(q, 32, 64);
        float m = s * 0.015625f;
        float var = fmaf(q, 0.015625f, -m * m);
        float rs = rsqrtf(var + 1e-5f);
#pragma unroll
        for (int mt = 0; mt < 2; mt++)
#pragma unroll
            for (int rg = 0; rg < 4; rg++) {
                float4 g4 = *(const float4*)(g + mt * 32 + rg * 8 + hf * 4);
                float4 b4 = *(const float4*)(b + mt * 32 + rg * 8 + hf * 4);
                float* yp = &y[mt * 2 + nt][rg * 4];
                yp[0] = fmaf((yp[0] - m) * rs, g4.x, b4.x);
                yp[1] = fmaf((yp[1] - m) * rs, g4.y, b4.y);
                yp[2] = fmaf((yp[2] - m) * rs, g4.z, b4.z);
                yp[3] = fmaf((yp[3] - m) * rs, g4.w, b4.w);
            }
    }
}

__global__ __launch_bounds__(256, 2) void k_xform(float* __restrict__ yio, XQ P) {
    __shared__ _Float16 xs[4 * 64 * XROW];
    const int t = threadIdx.x;
    const int w = t >> 6, l = t & 63;
    const int col = l & 31, hf = l >> 5;
    _Float16* xw = xs + w * (64 * XROW);
    const int nb = blockIdx.x * 256 + w * 64;
    const int nn0 = nb + col, nn1 = nb + 32 + col;
    const int nc0 = nn0 < NN ? nn0 : NN - 1;
    const int nc1 = nn1 < NN ? nn1 : NN - 1;

    float y[4][16];
#pragma unroll
    for (int mt = 0; mt < 2; mt++)
#pragma unroll
        for (int nt = 0; nt < 2; nt++) {
            const float* src = yio + (size_t)(nt ? nc1 : nc0) * 64 + mt * 32 + hf * 4;
#pragma unroll
            for (int rg = 0; rg < 4; rg++) {
                float4 v = *(const float4*)(src + rg * 8);
                float* yp = &y[mt * 2 + nt][rg * 4];
                yp[0] = v.x; yp[1] = v.y; yp[2] = v.z; yp[3] = v.w;
            }
        }
    f16x8 bf[2][4];
    xstore(xw, y, col, hf);
    loadbf(xw, bf, col, hf);

#pragma unroll 1
    for (int layer = 0; layer < 4; layer++) {
        const bool enc = layer < 2;
        const int li = enc ? layer : layer - 2;
        const int nat = enc ? 1 : 2;
#pragma unroll 1
        for (int at = 0; at < nat; at++) {
            const int p = enc ? layer : (at == 0 ? 2 + li : 4 + li);
            const _Float16* apA = P.apk + p * 4096;
            const float* fbp = P.fb + p * 64;
            f32x16 acc[4];
#pragma unroll
            for (int mt = 0; mt < 2; mt++) {
                f32x16 a;
#pragma unroll
                for (int rg = 0; rg < 4; rg++) {
                    float4 b4 = *(const float4*)(fbp + mt * 32 + rg * 8 + hf * 4);
                    a[rg * 4 + 0] = b4.x; a[rg * 4 + 1] = b4.y; a[rg * 4 + 2] = b4.z; a[rg * 4 + 3] = b4.w;
                }
                acc[mt * 2 + 0] = a; acc[mt * 2 + 1] = a;
            }
#pragma unroll
            for (int mt = 0; mt < 2; mt++)
#pragma unroll
                for (int ks = 0; ks < 4; ks++) {
                    f16x8 af = *(const f16x8*)(apA + ((mt * 4 + ks) * 64 + l) * 8);
                    acc[mt * 2 + 0] = __builtin_amdgcn_mfma_f32_32x32x16_f16(af, bf[0][ks], acc[mt * 2 + 0], 0, 0, 0);
                    acc[mt * 2 + 1] = __builtin_amdgcn_mfma_f32_32x32x16_f16(af, bf[1][ks], acc[mt * 2 + 1], 0, 0, 0);
                }
#pragma unroll
            for (int ti = 0; ti < 4; ti++)
#pragma unroll
                for (int r = 0; r < 16; r++) y[ti][r] += acc[ti][r];
            const float *g, *b;
            if (enc)          { g = P.el1g + li * 64; b = P.el1b + li * 64; }
            else if (at == 0) { g = P.dl1g + li * 64; b = P.dl1b + li * 64; }
            else              { g = P.dl2g + li * 64; b = P.dl2b + li * 64; }
            lnw(y, g, b, hf);
            xstore(xw, y, col, hf);
            loadbf(xw, bf, col, hf);
        }
        const int pl = enc ? layer : 2 + li;
        const _Float16* apF1 = P.apk + APK_F1 + pl * 16384;
        const _Float16* apF2 = P.apk + APK_F2 + pl * 16384;
        const float* f1bp = (enc ? P.ef1b : P.df1b) + li * 256;
        const float* f2bp = (enc ? P.ef2b : P.df2b) + li * 64;
        f32x16 out[4];
#pragma unroll
        for (int mt = 0; mt < 2; mt++) {
            f32x16 a;
#pragma unroll
            for (int rg = 0; rg < 4; rg++) {
                float4 b4 = *(const float4*)(f2bp + mt * 32 + rg * 8 + hf * 4);
                a[rg * 4 + 0] = b4.x; a[rg * 4 + 1] = b4.y; a[rg * 4 + 2] = b4.z; a[rg * 4 + 3] = b4.w;
            }
            out[mt * 2 + 0] = a; out[mt * 2 + 1] = a;
        }
#pragma unroll 1
        for (int c = 0; c < 4; c++) {
            f32x16 ha[4];
#pragma unroll
            for (int hmt = 0; hmt < 2; hmt++) {
                f32x16 a;
#pragma unroll
                for (int rg = 0; rg < 4; rg++) {
                    float4 b4 = *(const float4*)(f1bp + c * 64 + hmt * 32 + rg * 8 + hf * 4);
                    a[rg * 4 + 0] = b4.x; a[rg * 4 + 1] = b4.y; a[rg * 4 + 2] = b4.z; a[rg * 4 + 3] = b4.w;
                }
                ha[hmt * 2 + 0] = a; ha[hmt * 2 + 1] = a;
            }
#pragma unroll
            for (int hmt = 0; hmt < 2; hmt++)
#pragma unroll
                for (int ks = 0; ks < 4; ks++) {
                    f16x8 af = *(const f16x8*)(apF1 + (((2 * c + hmt) * 4 + ks) * 64 + l) * 8);
                    ha[hmt * 2 + 0] = __builtin_amdgcn_mfma_f32_32x32x16_f16(af, bf[0][ks], ha[hmt * 2 + 0], 0, 0, 0);
                    ha[hmt * 2 + 1] = __builtin_amdgcn_mfma_f32_32x32x16_f16(af, bf[1][ks], ha[hmt * 2 + 1], 0, 0, 0);
                }
#pragma unroll
            for (int nt = 0; nt < 2; nt++)
#pragma unroll
                for (int hmt = 0; hmt < 2; hmt++)
#pragma unroll
                    for (int rg = 0; rg < 4; rg++) {
                        f16x4 h4;
#pragma unroll
                        for (int i = 0; i < 4; i++)
                            h4[i] = (_Float16)fmaxf(ha[hmt * 2 + nt][rg * 4 + i], 0.f);
                        *(f16x4*)(xw + (nt * 32 + col) * XROW + hmt * 32 + rg * 8 + hf * 4) = h4;
                    }
#pragma unroll
            for (int ksl = 0; ksl < 4; ksl++) {
                f16x8 hbf0 = *(const f16x8*)(xw + col * XROW + ksl * 16 + hf * 8);
                f16x8 hbf1 = *(const f16x8*)(xw + (32 + col) * XROW + ksl * 16 + hf * 8);
#pragma unroll
                for (int mt = 0; mt < 2; mt++) {
                    f16x8 af = *(const f16x8*)(apF2 + ((mt * 16 + c * 4 + ksl) * 64 + l) * 8);
                    out[mt * 2 + 0] = __builtin_amdgcn_mfma_f32_32x32x16_f16(af, hbf0, out[mt * 2 + 0], 0, 0, 0);
                    out[mt * 2 + 1] = __builtin_amdgcn_mfma_f32_32x32x16_f16(af, hbf1, out[mt * 2 + 1], 0, 0, 0);
                }
            }
        }
#pragma unroll
        for (int ti = 0; ti < 4; ti++)
#pragma unroll
            for (int r = 0; r < 16; r++) y[ti][r] += out[ti][r];
        const float* g2 = (enc ? P.el2g : P.dl3g) + li * 64;
        const float* b2 = (enc ? P.el2b : P.dl3b) + li * 64;
        lnw(y, g2, b2, hf);
        if (layer < 3) {
            xstore(xw, y, col, hf);
            loadbf(xw, bf, col, hf);
        }
    }
#pragma unroll
    for (int mt = 0; mt < 2; mt++)
#pragma unroll
        for (int nt = 0; nt < 2; nt++) {
            int n = nt ? nn1 : nn0;
            if (n < NN) {
                float* dst = yio + (size_t)n * 64 + mt * 32 + hf * 4;
#pragma unroll
                for (int rg = 0; rg < 4; rg++) {
                    const float* yp = &y[mt * 2 + nt][rg * 4];
                    *(float4*)(dst + rg * 8) = make_float4(yp[0], yp[1], yp[2], yp[3]);
                }
            }
        }
}

// ---------- global mean pool ----------
__global__ void k_pool(const float* __restrict__ y, const int* __restrict__ batch,
                       float* __restrict__ pooled) {
    int b = blockIdx.x;
    int t = threadIdx.x;
    int ch = t & 63, r = t >> 6;
    int lo = 0, hi = NN;
    while (lo < hi) { int mid = (lo + hi) >> 1; if (batch[mid] < b) lo = mid + 1; else hi = mid; }
    int st = lo;
    hi = NN;
    while (lo < hi) { int mid = (lo + hi) >> 1; if (batch[mid] < b + 1) lo = mid + 1; else hi = mid; }
    int en = lo;
    float s = 0.f;
    for (int i = st + r; i < en; i += 4) s += y[(size_t)i * 64 + ch];
    __shared__ float red[256];
    red[t] = s;
    __syncthreads();
    if (t < 64) {
        float tot = red[t] + red[t + 64] + red[t + 128] + red[t + 192];
        int cnt = en - st; if (cnt < 1) cnt = 1;
        pooled[b * 64 + t] = tot / (float)cnt;
    }
}

// ---------- final fc ----------
__global__ void k_fc(const float* __restrict__ pooled, const float* __restrict__ fcw,
                     const float* __restrict__ fcb, float* __restrict__ out) {
    int tid = blockIdx.x * 256 + threadIdx.x;
    if (tid >= NG * 33) return;
    int g = tid / 33, o = tid - g * 33;
    const float* p = pooled + g * 64;
    const float* w = fcw + o * 64;
    float a0 = 0.f, a1 = 0.f, a2 = 0.f, a3 = 0.f;
#pragma unroll
    for (int k = 0; k < 16; k++) {
        a0 = fmaf(p[4 * k], w[4 * k], a0);
        a1 = fmaf(p[4 * k + 1], w[4 * k + 1], a1);
        a2 = fmaf(p[4 * k + 2], w[4 * k + 2], a2);
        a3 = fmaf(p[4 * k + 3], w[4 * k + 3], a3);
    }
    out[tid] = fcb[o] + (a0 + a1) + (a2 + a3);
}

extern "C" void kernel_launch(void* const* d_in, const int* in_sizes, int n_in,
                              void* d_out, int out_size, void* d_ws, size_t ws_size,
                              hipStream_t stream) {
    (void)in_sizes; (void)n_in; (void)out_size; (void)ws_size;
    char* ws = (char*)d_ws;
    size_t o = 0;
    auto A = [&](size_t b) { size_t r = o; o += (b + 255) & ~(size_t)255; return r; };
    _Float16* h1p = (_Float16*)(ws + A((size_t)NN * 128 * 2));
    _Float16* h2h = (_Float16*)(ws + A((size_t)NN * 64 * 2));
    _Float16* g1h = (_Float16*)(ws + A((size_t)NN * 128 * 2));
    float* f_g2  = (float*)(ws + A((size_t)NN * 64 * 4));
    float* f_asp = (float*)(ws + A((size_t)NN * 4 * 4));
    float* f_ad1 = (float*)(ws + A((size_t)NN * 4 * 4));
    float* f_as2 = (float*)(ws + A((size_t)NN * 4 * 4));
    float* f_ad2 = (float*)(ws + A((size_t)NN * 4 * 4));
    int* i_off   = (int*)(ws + A((size_t)(NN + 1) * 4));
    int* i_cur   = (int*)(ws + A((size_t)NN * 4));
    int* i_deg   = (int*)(ws + A((size_t)NN * 4));
    int* i_bsum  = (int*)(ws + A((size_t)1024 * 4));
    int* i_srcs  = (int*)(ws + A((size_t)ETOT * 4));
    float* f_Mt  = (float*)(ws + A((size_t)6 * 4096 * 4));
    float* f_fb  = (float*)(ws + A((size_t)6 * 64 * 4));
    float* f_f1t = (float*)(ws + A((size_t)4 * 16384 * 4));
    float* f_f2t = (float*)(ws + A((size_t)4 * 16384 * 4));
    _Float16* f_apk = (_Float16*)(ws + A((size_t)APK_TOT * 2));
    _Float16* apw2  = (_Float16*)(ws + A((size_t)8192 * 2));
    float* f_pool= (float*)(ws + A((size_t)NG * 64 * 4));

    const float* x   = (const float*)d_in[0];
    const int* ei    = (const int*)d_in[1];
    const int* batch = (const int*)d_in[2];
    #define F32(i) ((const float*)d_in[i])

    hipMemsetAsync(i_deg, 0, (size_t)NN * 4, stream);
    k_h1<<<NN * 64 / 256, 256, 0, stream>>>(x, F32(3), F32(4), F32(5), h1p);
    k_att1<<<(NN * 4 + 255) / 256, 256, 0, stream>>>(h1p, F32(6), F32(7), f_asp, f_ad1);
    k_count<<<8 * 128, 256, 0, stream>>>(ei, i_deg);
    k_scan1<<<98, 1024, 0, stream>>>(i_deg, i_off, i_bsum);
    k_scan2<<<1, 128, 0, stream>>>(i_bsum);
    k_scan3<<<98, 1024, 0, stream>>>(i_off, i_bsum, i_cur);
    k_scatter<<<8 * 128, 256, 0, stream>>>(ei, i_cur, i_srcs);
    k_gat1<<<NN * 64 / 256, 256, 0, stream>>>(i_off, i_srcs, f_asp, f_ad1, h1p, F32(8), g1h);
    k_wpack<<<32, 256, 0, stream>>>(F32(9), apw2);
    k_h2m<<<(NN / 32 + 3) / 4, 256, 0, stream>>>(g1h, apw2, h2h);
    k_att2<<<(NN * 4 + 255) / 256, 256, 0, stream>>>(h2h, F32(10), F32(11), f_as2, f_ad2);
    k_gat2<<<NN * 64 / 256, 256, 0, stream>>>(i_off, i_srcs, f_as2, f_ad2, h2h, F32(12), f_g2);
    k_fuse<<<24576 / 256, 256, 0, stream>>>(F32(13), F32(14), F32(15), F32(16),
                                            F32(25), F32(26), F32(27), F32(28),
                                            F32(29), F32(30), F32(31), F32(32),
                                            f_Mt, f_fb);
    k_f1t<<<65536 / 256, 256, 0, stream>>>(F32(17), F32(33), f_f1t);
    k_f2t<<<65536 / 256, 256, 0, stream>>>(F32(19), F32(35), f_f2t);
    k_apack<<<APK_TOT / 256, 256, 0, stream>>>(f_Mt, f_f1t, f_f2t, f_apk);
    XQ Q;
    Q.apk = f_apk; Q.fb = f_fb;
    Q.ef1b = F32(18); Q.ef2b = F32(20);
    Q.df1b = F32(34); Q.df2b = F32(36);
    Q.el1g = F32(21); Q.el1b = F32(22); Q.el2g = F32(23); Q.el2b = F32(24);
    Q.dl1g = F32(37); Q.dl1b = F32(38); Q.dl2g = F32(39); Q.dl2b = F32(40);
    Q.dl3g = F32(41); Q.dl3b = F32(42);
    k_xform<<<(NN + 255) / 256, 256, 0, stream>>>(f_g2, Q);
    k_pool<<<NG, 256, 0, stream>>>(f_g2, batch, f_pool);
    k_fc<<<(NG * 33 + 255) / 256, 256, 0, stream>>>(f_pool, F32(43), F32(44), (float*)d_out);
    #undef F32
}

// Round 9
// 634.223 us; speedup vs baseline: 7.8956x; 1.0469x over previous
//
#include <hip/hip_runtime.h>

#define NN 100000
#define NE 1600000
#define NG 1000
#define ETOT (NE + NN)
#define NODES_PER_GRP 12500  // NN/8, XCD-affine binning for count/scatter

typedef _Float16 f16x8 __attribute__((ext_vector_type(8)));
typedef _Float16 f16x4 __attribute__((ext_vector_type(4)));
typedef _Float16 f16x2 __attribute__((ext_vector_type(2)));
typedef float f32x16 __attribute__((ext_vector_type(16)));
#define XROW 72  // xform LDS row stride (halves)

// ---------- h1 paired fp16 + fused att1 (one wave per node) ----------
// h1p[n][jp] = (ch jp, ch jp+64). Lane jp holds c=jp (head jp>>5) and c=jp+64
// (head 2+(jp>>5)); shfl_xor(1..16) reduces within 32-lane halves -> all 4
// as/ad coefficients. asp packed {h0,h2,h1,h3} for gat1's half-wave select.
__global__ void k_h1(const float* __restrict__ x, const float* __restrict__ ffw,
                     const float* __restrict__ ffb, const float* __restrict__ g1w,
                     const float* __restrict__ asw, const float* __restrict__ adw,
                     _Float16* __restrict__ h1p, float* __restrict__ asp,
                     float* __restrict__ ad_) {
    int tid = blockIdx.x * 256 + threadIdx.x;  // NN*64 exact
    int n = __builtin_amdgcn_readfirstlane(tid >> 6);
    int jp = threadIdx.x & 63;
    float xv[4];
#pragma unroll
    for (int k = 0; k < 4; k++) xv[k] = x[n * 4 + k];
    float h0[8];
#pragma unroll
    for (int o = 0; o < 8; o++) {
        float a = ffb[o];
#pragma unroll
        for (int k = 0; k < 4; k++) a = fmaf(xv[k], ffw[o * 4 + k], a);
        h0[o] = a;
    }
    const float* w0 = g1w + jp * 8;
    const float* w1 = g1w + (jp + 64) * 8;
    float a0 = 0.f, a1 = 0.f;
#pragma unroll
    for (int k = 0; k < 8; k++) { a0 = fmaf(h0[k], w0[k], a0); a1 = fmaf(h0[k], w1[k], a1); }
    f16x2 r; r[0] = (_Float16)a0; r[1] = (_Float16)a1;
    *(f16x2*)(h1p + ((size_t)n * 64 + jp) * 2) = r;
    // fused attention coefficients
    float p0 = a0 * asw[jp], p1 = a1 * asw[jp + 64];
    float d0 = a0 * adw[jp], d1 = a1 * adw[jp + 64];
#pragma unroll
    for (int m = 1; m <= 16; m <<= 1) {
        p0 += __shfl_xor(p0, m, 64); p1 += __shfl_xor(p1, m, 64);
        d0 += __shfl_xor(d0, m, 64); d1 += __shfl_xor(d1, m, 64);
    }
    if ((jp & 31) == 0) {
        int half = jp >> 5;  // 0: heads (0,2); 1: heads (1,3)
        *(float2*)(asp + n * 4 + half * 2) = make_float2(p0, p1);
        ad_[n * 4 + half] = d0;
        ad_[n * 4 + 2 + half] = d1;
    }
}

// ---------- layer-2 attention coeffs ----------
__global__ void k_att2(const _Float16* __restrict__ h2h, const float* __restrict__ asw,
                       const float* __restrict__ adw, float* __restrict__ as_,
                       float* __restrict__ ad_) {
    int tid = blockIdx.x * 256 + threadIdx.x;
    if (tid >= NN * 4) return;
    int n = tid >> 2, h = tid & 3;
    const _Float16* hp = h2h + (size_t)n * 64 + h * 16;
    const float* ws_ = asw + h * 16;
    const float* wd_ = adw + h * 16;
    float a = 0.f, d = 0.f;
#pragma unroll
    for (int c = 0; c < 16; c++) {
        float hv = (float)hp[c];
        a = fmaf(hv, ws_[c], a); d = fmaf(hv, wd_[c], d);
    }
    as_[tid] = a; ad_[tid] = d;
}

// ---------- CSR build: XCD-affine binned count & scatter ----------
__global__ void k_count(const int* __restrict__ ei, int* __restrict__ deg) {
    int g = blockIdx.x & 7;
    int bi = blockIdx.x >> 3;
    int nb = gridDim.x >> 3;
    int lo = g * NODES_PER_GRP, hi = lo + NODES_PER_GRP;
    for (int e = bi * 256 + threadIdx.x; e < ETOT; e += nb * 256) {
        int dst = (e < NE) ? ei[NE + e] : (e - NE);
        if (dst >= lo && dst < hi) atomicAdd(&deg[dst], 1);
    }
}

__global__ void k_scan1(const int* __restrict__ deg, int* __restrict__ offs, int* __restrict__ bsum) {
    __shared__ int s[1024];
    int tid = threadIdx.x;
    int i = blockIdx.x * 1024 + tid;
    int v = (i < NN) ? deg[i] : 0;
    s[tid] = v;
    __syncthreads();
    for (int d = 1; d < 1024; d <<= 1) {
        int t = 0;
        if (tid >= d) t = s[tid - d];
        __syncthreads();
        if (tid >= d) s[tid] += t;
        __syncthreads();
    }
    if (i < NN) offs[i] = s[tid] - v;
    if (tid == 1023) bsum[blockIdx.x] = s[tid];
}

__global__ void k_scan2(int* __restrict__ bsum) {
    __shared__ int s[128];
    int tid = threadIdx.x;
    int v = (tid < 98) ? bsum[tid] : 0;
    s[tid] = v;
    __syncthreads();
    for (int d = 1; d < 128; d <<= 1) {
        int t = 0;
        if (tid >= d) t = s[tid - d];
        __syncthreads();
        if (tid >= d) s[tid] += t;
        __syncthreads();
    }
    bsum[tid] = s[tid] - v;
}

__global__ void k_scan3(int* __restrict__ offs, const int* __restrict__ bsum, int* __restrict__ cur) {
    int i = blockIdx.x * 1024 + threadIdx.x;
    if (i < NN) {
        int v = offs[i] + bsum[blockIdx.x];
        offs[i] = v; cur[i] = v;
    }
    if (i == 0) offs[NN] = ETOT;
}

__global__ void k_scatter(const int* __restrict__ ei, int* __restrict__ cur, int* __restrict__ srcs) {
    int g = blockIdx.x & 7;
    int bi = blockIdx.x >> 3;
    int nb = gridDim.x >> 3;
    int lo = g * NODES_PER_GRP, hi = lo + NODES_PER_GRP;
    for (int e = bi * 256 + threadIdx.x; e < ETOT; e += nb * 256) {
        int dst = (e < NE) ? ei[NE + e] : (e - NE);
        if (dst >= lo && dst < hi) {
            int src = (e < NE) ? ei[e] : dst;
            int p = atomicAdd(&cur[dst], 1);
            srcs[p] = src;
        }
    }
}

// ---------- GAT layer 1: scalarized single-pass softmax+aggregate ----------
// src index via readlane (SGPR) -> coeff loads become s_load_dwordx4, h-gather
// becomes scalar-base + lane-offset global_load. Only per-edge VALU left:
// head-select cndmask, leaky, exp, fma accumulate.
__global__ void k_gat1(const int* __restrict__ offs, const int* __restrict__ srcs,
                       const float* __restrict__ asp, const float* __restrict__ ad_,
                       const _Float16* __restrict__ h1p, const float* __restrict__ bias,
                       _Float16* __restrict__ g1h) {
    int wid = __builtin_amdgcn_readfirstlane((blockIdx.x * 256 + threadIdx.x) >> 6);
    int lane = threadIdx.x & 63;
    if (wid >= NN) return;
    int off = offs[wid];
    int deg = offs[wid + 1] - off;
    int hA = lane >> 5;
    float4 adv = *(const float4*)(ad_ + wid * 4);
    float adA = hA ? adv.y : adv.x;   // heads (0|1)
    float adB = hA ? adv.w : adv.z;   // heads (2|3)
    float ws0 = 0.f, ws1 = 0.f, ac0 = 0.f, ac1 = 0.f;
    float ws0b = 0.f, ws1b = 0.f, ac0b = 0.f, ac1b = 0.f;
    for (int base = 0; base < deg; base += 64) {
        int idx = off + base + lane; if (idx >= ETOT) idx = ETOT - 1;
        int sv = srcs[idx];
        int cnt = deg - base; if (cnt > 64) cnt = 64;
        int j = 0;
        for (; j + 2 <= cnt; j += 2) {
            int sa = __builtin_amdgcn_readlane(sv, j);
            int sb = __builtin_amdgcn_readlane(sv, j + 1);
            float4 aa = *(const float4*)(asp + sa * 4);      // s_load: {h0,h2,h1,h3}
            float4 ab = *(const float4*)(asp + sb * 4);
            f16x2 hpa = *(const f16x2*)(h1p + (size_t)sa * 128 + lane * 2);
            f16x2 hpb = *(const f16x2*)(h1p + (size_t)sb * 128 + lane * 2);
            float e0 = (hA ? aa.z : aa.x) + adA; e0 = fmaxf(e0, 0.2f * e0);
            float e1 = (hA ? aa.w : aa.y) + adB; e1 = fmaxf(e1, 0.2f * e1);
            float w0 = __expf(e0), w1 = __expf(e1);
            ws0 += w0; ws1 += w1;
            ac0 = fmaf(w0, (float)hpa[0], ac0); ac1 = fmaf(w1, (float)hpa[1], ac1);
            float e0b = (hA ? ab.z : ab.x) + adA; e0b = fmaxf(e0b, 0.2f * e0b);
            float e1b = (hA ? ab.w : ab.y) + adB; e1b = fmaxf(e1b, 0.2f * e1b);
            float w0b = __expf(e0b), w1b = __expf(e1b);
            ws0b += w0b; ws1b += w1b;
            ac0b = fmaf(w0b, (float)hpb[0], ac0b); ac1b = fmaf(w1b, (float)hpb[1], ac1b);
        }
        if (j < cnt) {
            int sa = __builtin_amdgcn_readlane(sv, j);
            float4 aa = *(const float4*)(asp + sa * 4);
            f16x2 hpa = *(const f16x2*)(h1p + (size_t)sa * 128 + lane * 2);
            float e0 = (hA ? aa.z : aa.x) + adA; e0 = fmaxf(e0, 0.2f * e0);
            float e1 = (hA ? aa.w : aa.y) + adB; e1 = fmaxf(e1, 0.2f * e1);
            float w0 = __expf(e0), w1 = __expf(e1);
            ws0 += w0; ws1 += w1;
            ac0 = fmaf(w0, (float)hpa[0], ac0); ac1 = fmaf(w1, (float)hpa[1], ac1);
        }
    }
    ws0 += ws0b; ws1 += ws1b; ac0 += ac0b; ac1 += ac1b;
    float v0 = ac0 / ws0 + bias[lane];      v0 = fmaxf(v0, 0.01f * v0);
    float v1 = ac1 / ws1 + bias[lane + 64]; v1 = fmaxf(v1, 0.01f * v1);
    g1h[(size_t)wid * 128 + lane] = (_Float16)v0;
    g1h[(size_t)wid * 128 + lane + 64] = (_Float16)v1;
}

// ---------- GAT layer 2: same scalarization ----------
__global__ void k_gat2(const int* __restrict__ offs, const int* __restrict__ srcs,
                       const float* __restrict__ as_, const float* __restrict__ ad_,
                       const _Float16* __restrict__ h2h, const float* __restrict__ bias,
                       float* __restrict__ g2) {
    int wid = __builtin_amdgcn_readfirstlane((blockIdx.x * 256 + threadIdx.x) >> 6);
    int lane = threadIdx.x & 63;
    if (wid >= NN) return;
    int off = offs[wid];
    int deg = offs[wid + 1] - off;
    int hd = lane >> 4;
    float4 adv = *(const float4*)(ad_ + wid * 4);
    float t01 = (hd & 1) ? adv.y : adv.x;
    float t23 = (hd & 1) ? adv.w : adv.z;
    float adA = (hd & 2) ? t23 : t01;
    float ws = 0.f, ac = 0.f, wsb = 0.f, acb = 0.f;
    for (int base = 0; base < deg; base += 64) {
        int idx = off + base + lane; if (idx >= ETOT) idx = ETOT - 1;
        int sv = srcs[idx];
        int cnt = deg - base; if (cnt > 64) cnt = 64;
        int j = 0;
        for (; j + 2 <= cnt; j += 2) {
            int sa = __builtin_amdgcn_readlane(sv, j);
            int sb = __builtin_amdgcn_readlane(sv, j + 1);
            float4 av = *(const float4*)(as_ + sa * 4);
            float4 bv = *(const float4*)(as_ + sb * 4);
            float ha = (float)h2h[(size_t)sa * 64 + lane];
            float hb = (float)h2h[(size_t)sb * 64 + lane];
            float u01 = (hd & 1) ? av.y : av.x, u23 = (hd & 1) ? av.w : av.z;
            float ea = ((hd & 2) ? u23 : u01) + adA; ea = fmaxf(ea, 0.2f * ea);
            float v01 = (hd & 1) ? bv.y : bv.x, v23 = (hd & 1) ? bv.w : bv.z;
            float eb = ((hd & 2) ? v23 : v01) + adA; eb = fmaxf(eb, 0.2f * eb);
            float wa = __expf(ea), wb = __expf(eb);
            ws += wa; ac = fmaf(wa, ha, ac);
            wsb += wb; acb = fmaf(wb, hb, acb);
        }
        if (j < cnt) {
            int sa = __builtin_amdgcn_readlane(sv, j);
            float4 av = *(const float4*)(as_ + sa * 4);
            float u01 = (hd & 1) ? av.y : av.x, u23 = (hd & 1) ? av.w : av.z;
            float ea = ((hd & 2) ? u23 : u01) + adA; ea = fmaxf(ea, 0.2f * ea);
            float wa = __expf(ea);
            ws += wa; ac = fmaf(wa, (float)h2h[(size_t)sa * 64 + lane], ac);
        }
    }
    ws += wsb; ac += acb;
    float v = ac / ws + bias[lane]; v = fmaxf(v, 0.01f * v);
    g2[(size_t)wid * 64 + lane] = v;
}

// ---------- pack gat2_w into MFMA A-fragments (fp16) ----------
__global__ void k_wpack(const float* __restrict__ g2w, _Float16* __restrict__ apw2) {
    int tid = blockIdx.x * 256 + threadIdx.x;  // 8192 exact
    int mtks = tid >> 9, l = (tid >> 3) & 63, d = tid & 7;
    int mt = mtks >> 3, ks = mtks & 7;
    int m = mt * 32 + (l & 31), k = ks * 16 + (l >> 5) * 8 + d;
    apw2[tid] = (_Float16)g2w[m * 128 + k];
}

// ---------- h2[N,64] fp16 = g1h[N,128] @ gat2_w.T via MFMA, 1 wave = 32 nodes ----------
#define GROW 136
#define CROW 72
__global__ __launch_bounds__(256, 2) void k_h2m(const _Float16* __restrict__ g1h,
                                                const _Float16* __restrict__ apw2,
                                                _Float16* __restrict__ h2h) {
    __shared__ _Float16 ls[4 * 32 * GROW];
    const int t = threadIdx.x;
    const int w = t >> 6, l = t & 63;
    const int col = l & 31, hf = l >> 5;
    const int wv = blockIdx.x * 4 + w;
    const int nb = wv * 32;
    if (nb >= NN) return;
    _Float16* g16 = ls + w * (32 * GROW);
    const int r = l >> 1, hb = l & 1;
    {
        int nr = nb + r; if (nr >= NN) nr = NN - 1;
        const _Float16* src = g1h + (size_t)nr * 128 + hb * 64;
        _Float16* dst = g16 + r * GROW + hb * 64;
#pragma unroll
        for (int q = 0; q < 8; q++)
            *(f16x8*)(dst + q * 8) = *(const f16x8*)(src + q * 8);
    }
    f16x8 bf[8];
#pragma unroll
    for (int ks = 0; ks < 8; ks++)
        bf[ks] = *(const f16x8*)(g16 + col * GROW + ks * 16 + hf * 8);
    f32x16 acc0, acc1;
#pragma unroll
    for (int i = 0; i < 16; i++) { acc0[i] = 0.f; acc1[i] = 0.f; }
#pragma unroll
    for (int ks = 0; ks < 8; ks++) {
        f16x8 a0 = *(const f16x8*)(apw2 + ((0 * 8 + ks) * 64 + l) * 8);
        f16x8 a1 = *(const f16x8*)(apw2 + ((1 * 8 + ks) * 64 + l) * 8);
        acc0 = __builtin_amdgcn_mfma_f32_32x32x16_f16(a0, bf[ks], acc0, 0, 0, 0);
        acc1 = __builtin_amdgcn_mfma_f32_32x32x16_f16(a1, bf[ks], acc1, 0, 0, 0);
    }
    _Float16* c16 = g16;
#pragma unroll
    for (int rg = 0; rg < 4; rg++) {
        f16x4 h0, h1;
#pragma unroll
        for (int i = 0; i < 4; i++) { h0[i] = (_Float16)acc0[rg * 4 + i]; h1[i] = (_Float16)acc1[rg * 4 + i]; }
        *(f16x4*)(c16 + col * CROW + rg * 8 + hf * 4) = h0;
        *(f16x4*)(c16 + col * CROW + 32 + rg * 8 + hf * 4) = h1;
    }
    if (nb + r < NN) {
        _Float16* dst = h2h + (size_t)(nb + r) * 64 + hb * 32;
        const _Float16* srow = c16 + r * CROW + hb * 32;
#pragma unroll
        for (int q = 0; q < 4; q++)
            *(f16x8*)(dst + q * 8) = *(const f16x8*)(srow + q * 8);
    }
}

// ---------- fused attention Mt[k][j] (fp32) + fused bias ----------
__global__ void k_fuse(const float* __restrict__ enc_in_w, const float* __restrict__ enc_in_b,
                       const float* __restrict__ enc_out_w, const float* __restrict__ enc_out_b,
                       const float* __restrict__ sa_in_w, const float* __restrict__ sa_in_b,
                       const float* __restrict__ sa_out_w, const float* __restrict__ sa_out_b,
                       const float* __restrict__ ca_in_w, const float* __restrict__ ca_in_b,
                       const float* __restrict__ ca_out_w, const float* __restrict__ ca_out_b,
                       float* __restrict__ Mt, float* __restrict__ fb) {
    int tid = blockIdx.x * 256 + threadIdx.x;
    int p = tid >> 12, r = tid & 4095, j = r >> 6, k = r & 63;
    int li = p & 1;
    const float *iw, *ib, *ow, *ob;
    if (p < 2)      { iw = enc_in_w + li * 12288; ib = enc_in_b + li * 192; ow = enc_out_w + li * 4096; ob = enc_out_b + li * 64; }
    else if (p < 4) { iw = sa_in_w + li * 12288;  ib = sa_in_b + li * 192;  ow = sa_out_w + li * 4096;  ob = sa_out_b + li * 64; }
    else            { iw = ca_in_w + li * 12288;  ib = ca_in_b + li * 192;  ow = ca_out_w + li * 4096;  ob = ca_out_b + li * 64; }
    float a = 0.f;
    for (int m = 0; m < 64; m++) a = fmaf(ow[j * 64 + m], iw[(128 + m) * 64 + k], a);
    Mt[p * 4096 + k * 64 + j] = a;
    if (k == 0) {
        float fa = ob[j];
        for (int m = 0; m < 64; m++) fa = fmaf(ow[j * 64 + m], ib[128 + m], fa);
        fb[p * 64 + j] = fa;
    }
}

// ---------- transpose f2 / f1 ----------
__global__ void k_f2t(const float* __restrict__ enc_f2_w, const float* __restrict__ dec_f2_w,
                      float* __restrict__ f2t) {
    int tid = blockIdx.x * 256 + threadIdx.x;
    int p = tid >> 14, r = tid & 16383;
    int h = r >> 6, j = r & 63;
    const float* src = (p < 2) ? enc_f2_w + p * 16384 : dec_f2_w + (p - 2) * 16384;
    f2t[tid] = src[j * 256 + h];
}

__global__ void k_f1t(const float* __restrict__ enc_f1_w, const float* __restrict__ dec_f1_w,
                      float* __restrict__ f1t) {
    int tid = blockIdx.x * 256 + threadIdx.x;
    int p = tid >> 14, r = tid & 16383;
    int k = r >> 8, i = r & 255;
    const float* src = (p < 2) ? enc_f1_w + p * 16384 : dec_f1_w + (p - 2) * 16384;
    f1t[tid] = src[i * 64 + k];
}

// ---------- pack transformer weights into fp16 MFMA A-fragment order ----------
#define APK_F1 24576
#define APK_F2 90112
#define APK_TOT 155648
__global__ void k_apack(const float* __restrict__ Mt, const float* __restrict__ f1t,
                        const float* __restrict__ f2t, _Float16* __restrict__ apk) {
    int tid = blockIdx.x * 256 + threadIdx.x;
    float v;
    if (tid < APK_F1) {
        int p = tid >> 12, idx = tid & 4095;
        int mt = idx >> 11, ks = (idx >> 9) & 3, l = (idx >> 3) & 63, d = idx & 7;
        int m = mt * 32 + (l & 31), k = ks * 16 + (l >> 5) * 8 + d;
        v = Mt[p * 4096 + k * 64 + m];
    } else if (tid < APK_F2) {
        int r = tid - APK_F1; int pl = r >> 14, idx = r & 16383;
        int mt = idx >> 11, ks = (idx >> 9) & 3, l = (idx >> 3) & 63, d = idx & 7;
        int m = mt * 32 + (l & 31), k = ks * 16 + (l >> 5) * 8 + d;
        v = f1t[pl * 16384 + k * 256 + m];
    } else {
        int r = tid - APK_F2; int pl = r >> 14, idx = r & 16383;
        int mt = idx >> 13, ks = (idx >> 9) & 15, l = (idx >> 3) & 63, d = idx & 7;
        int m = mt * 32 + (l & 31), k = ks * 16 + (l >> 5) * 8 + d;
        v = f2t[pl * 16384 + k * 64 + m];
    }
    apk[tid] = (_Float16)v;
}

// ---------- MFMA transformer: 1 wave = 64 nodes, no barriers ----------
struct XQ {
    const _Float16* apk; const float* fb;
    const float* ef1b; const float* ef2b; const float* df1b; const float* df2b;
    const float* el1g; const float* el1b; const float* el2g; const float* el2b;
    const float* dl1g; const float* dl1b; const float* dl2g; const float* dl2b;
    const float* dl3g; const float* dl3b;
};

__device__ __forceinline__ void xstore(_Float16* xw, const float y[4][16], int col, int hf) {
#pragma unroll
    for (int nt = 0; nt < 2; nt++)
#pragma unroll
        for (int mt = 0; mt < 2; mt++)
#pragma unroll
            for (int rg = 0; rg < 4; rg++) {
                f16x4 h4;
#pragma unroll
                for (int i = 0; i < 4; i++) h4[i] = (_Float16)y[mt * 2 + nt][rg * 4 + i];
                *(f16x4*)(xw + (nt * 32 + col) * XROW + mt * 32 + rg * 8 + hf * 4) = h4;
            }
}

__device__ __forceinline__ void loadbf(const _Float16* xw, f16x8 bf[2][4], int col, int hf) {
#pragma unroll
    for (int nt = 0; nt < 2; nt++)
#pragma unroll
        for (int ks = 0; ks < 4; ks++)
            bf[nt][ks] = *(const f16x8*)(xw + (nt * 32 + col) * XROW + ks * 16 + hf * 8);
}

__device__ __forceinline__ void lnw(float y[4][16], const float* g, const float* b, int hf) {
#pragma unroll
    for (int nt = 0; nt < 2; nt++) {
        float s = 0.f, q = 0.f;
#pragma unroll
        for (int mt = 0; mt < 2; mt++)
#pragma unroll
            for (int r = 0; r < 16; r++) { float v = y[mt * 2 + nt][r]; s += v; q = fmaf(v, v, q); }
        s += __shfl_xor(s, 32, 64);
        q += __shfl_xor(q, 32, 64);
        float m = s * 0.015625f;
        float var = fmaf(q, 0.015625f, -m * m);
        float rs = rsqrtf(var + 1e-5f);
#pragma unroll
        for (int mt = 0; mt < 2; mt++)
#pragma unroll
            for (int rg = 0; rg < 4; rg++) {
                float4 g4 = *(const float4*)(g + mt * 32 + rg * 8 + hf * 4);
                float4 b4 = *(const float4*)(b + mt * 32 + rg * 8 + hf * 4);
                float* yp = &y[mt * 2 + nt][rg * 4];
                yp[0] = fmaf((yp[0] - m) * rs, g4.x, b4.x);
                yp[1] = fmaf((yp[1] - m) * rs, g4.y, b4.y);
                yp[2] = fmaf((yp[2] - m) * rs, g4.z, b4.z);
                yp[3] = fmaf((yp[3] - m) * rs, g4.w, b4.w);
            }
    }
}

__global__ __launch_bounds__(256, 2) void k_xform(float* __restrict__ yio, XQ P) {
    __shared__ _Float16 xs[4 * 64 * XROW];
    const int t = threadIdx.x;
    const int w = t >> 6, l = t & 63;
    const int col = l & 31, hf = l >> 5;
    _Float16* xw = xs + w * (64 * XROW);
    const int nb = blockIdx.x * 256 + w * 64;
    const int nn0 = nb + col, nn1 = nb + 32 + col;
    const int nc0 = nn0 < NN ? nn0 : NN - 1;
    const int nc1 = nn1 < NN ? nn1 : NN - 1;

    float y[4][16];
#pragma unroll
    for (int mt = 0; mt < 2; mt++)
#pragma unroll
        for (int nt = 0; nt < 2; nt++) {
            const float* src = yio + (size_t)(nt ? nc1 : nc0) * 64 + mt * 32 + hf * 4;
#pragma unroll
            for (int rg = 0; rg < 4; rg++) {
                float4 v = *(const float4*)(src + rg * 8);
                float* yp = &y[mt * 2 + nt][rg * 4];
                yp[0] = v.x; yp[1] = v.y; yp[2] = v.z; yp[3] = v.w;
            }
        }
    f16x8 bf[2][4];
    xstore(xw, y, col, hf);
    loadbf(xw, bf, col, hf);

#pragma unroll 1
    for (int layer = 0; layer < 4; layer++) {
        const bool enc = layer < 2;
        const int li = enc ? layer : layer - 2;
        const int nat = enc ? 1 : 2;
#pragma unroll 1
        for (int at = 0; at < nat; at++) {
            const int p = enc ? layer : (at == 0 ? 2 + li : 4 + li);
            const _Float16* apA = P.apk + p * 4096;
            const float* fbp = P.fb + p * 64;
            f32x16 acc[4];
#pragma unroll
            for (int mt = 0; mt < 2; mt++) {
                f32x16 a;
#pragma unroll
                for (int rg = 0; rg < 4; rg++) {
                    float4 b4 = *(const float4*)(fbp + mt * 32 + rg * 8 + hf * 4);
                    a[rg * 4 + 0] = b4.x; a[rg * 4 + 1] = b4.y; a[rg * 4 + 2] = b4.z; a[rg * 4 + 3] = b4.w;
                }
                acc[mt * 2 + 0] = a; acc[mt * 2 + 1] = a;
            }
#pragma unroll
            for (int mt = 0; mt < 2; mt++)
#pragma unroll
                for (int ks = 0; ks < 4; ks++) {
                    f16x8 af = *(const f16x8*)(apA + ((mt * 4 + ks) * 64 + l) * 8);
                    acc[mt * 2 + 0] = __builtin_amdgcn_mfma_f32_32x32x16_f16(af, bf[0][ks], acc[mt * 2 + 0], 0, 0, 0);
                    acc[mt * 2 + 1] = __builtin_amdgcn_mfma_f32_32x32x16_f16(af, bf[1][ks], acc[mt * 2 + 1], 0, 0, 0);
                }
#pragma unroll
            for (int ti = 0; ti < 4; ti++)
#pragma unroll
                for (int r = 0; r < 16; r++) y[ti][r] += acc[ti][r];
            const float *g, *b;
            if (enc)          { g = P.el1g + li * 64; b = P.el1b + li * 64; }
            else if (at == 0) { g = P.dl1g + li * 64; b = P.dl1b + li * 64; }
            else              { g = P.dl2g + li * 64; b = P.dl2b + li * 64; }
            lnw(y, g, b, hf);
            xstore(xw, y, col, hf);
            loadbf(xw, bf, col, hf);
        }
        const int pl = enc ? layer : 2 + li;
        const _Float16* apF1 = P.apk + APK_F1 + pl * 16384;
        const _Float16* apF2 = P.apk + APK_F2 + pl * 16384;
        const float* f1bp = (enc ? P.ef1b : P.df1b) + li * 256;
        const float* f2bp = (enc ? P.ef2b : P.df2b) + li * 64;
        f32x16 out[4];
#pragma unroll
        for (int mt = 0; mt < 2; mt++) {
            f32x16 a;
#pragma unroll
            for (int rg = 0; rg < 4; rg++) {
                float4 b4 = *(const float4*)(f2bp + mt * 32 + rg * 8 + hf * 4);
                a[rg * 4 + 0] = b4.x; a[rg * 4 + 1] = b4.y; a[rg * 4 + 2] = b4.z; a[rg * 4 + 3] = b4.w;
            }
            out[mt * 2 + 0] = a; out[mt * 2 + 1] = a;
        }
#pragma unroll 1
        for (int c = 0; c < 4; c++) {
            f32x16 ha[4];
#pragma unroll
            for (int hmt = 0; hmt < 2; hmt++) {
                f32x16 a;
#pragma unroll
                for (int rg = 0; rg < 4; rg++) {
                    float4 b4 = *(const float4*)(f1bp + c * 64 + hmt * 32 + rg * 8 + hf * 4);
                    a[rg * 4 + 0] = b4.x; a[rg * 4 + 1] = b4.y; a[rg * 4 + 2] = b4.z; a[rg * 4 + 3] = b4.w;
                }
                ha[hmt * 2 + 0] = a; ha[hmt * 2 + 1] = a;
            }
#pragma unroll
            for (int hmt = 0; hmt < 2; hmt++)
#pragma unroll
                for (int ks = 0; ks < 4; ks++) {
                    f16x8 af = *(const f16x8*)(apF1 + (((2 * c + hmt) * 4 + ks) * 64 + l) * 8);
                    ha[hmt * 2 + 0] = __builtin_amdgcn_mfma_f32_32x32x16_f16(af, bf[0][ks], ha[hmt * 2 + 0], 0, 0, 0);
                    ha[hmt * 2 + 1] = __builtin_amdgcn_mfma_f32_32x32x16_f16(af, bf[1][ks], ha[hmt * 2 + 1], 0, 0, 0);
                }
#pragma unroll
            for (int nt = 0; nt < 2; nt++)
#pragma unroll
                for (int hmt = 0; hmt < 2; hmt++)
#pragma unroll
                    for (int rg = 0; rg < 4; rg++) {
                        f16x4 h4;
#pragma unroll
                        for (int i = 0; i < 4; i++)
                            h4[i] = (_Float16)fmaxf(ha[hmt * 2 + nt][rg * 4 + i], 0.f);
                        *(f16x4*)(xw + (nt * 32 + col) * XROW + hmt * 32 + rg * 8 + hf * 4) = h4;
                    }
#pragma unroll
            for (int ksl = 0; ksl < 4; ksl++) {
                f16x8 hbf0 = *(const f16x8*)(xw + col * XROW + ksl * 16 + hf * 8);
                f16x8 hbf1 = *(const f16x8*)(xw + (32 + col) * XROW + ksl * 16 + hf * 8);
#pragma unroll
                for (int mt = 0; mt < 2; mt++) {
                    f16x8 af = *(const f16x8*)(apF2 + ((mt * 16 + c * 4 + ksl) * 64 + l) * 8);
                    out[mt * 2 + 0] = __builtin_amdgcn_mfma_f32_32x32x16_f16(af, hbf0, out[mt * 2 + 0], 0, 0, 0);
                    out[mt * 2 + 1] = __builtin_amdgcn_mfma_f32_32x32x16_f16(af, hbf1, out[mt * 2 + 1], 0, 0, 0);
                }
            }
        }
#pragma unroll
        for (int ti = 0; ti < 4; ti++)
#pragma unroll
            for (int r = 0; r < 16; r++) y[ti][r] += out[ti][r];
        const float* g2 = (enc ? P.el2g : P.dl3g) + li * 64;
        const float* b2 = (enc ? P.el2b : P.dl3b) + li * 64;
        lnw(y, g2, b2, hf);
        if (layer < 3) {
            xstore(xw, y, col, hf);
            loadbf(xw, bf, col, hf);
        }
    }
#pragma unroll
    for (int mt = 0; mt < 2; mt++)
#pragma unroll
        for (int nt = 0; nt < 2; nt++) {
            int n = nt ? nn1 : nn0;
            if (n < NN) {
                float* dst = yio + (size_t)n * 64 + mt * 32 + hf * 4;
#pragma unroll
                for (int rg = 0; rg < 4; rg++) {
                    const float* yp = &y[mt * 2 + nt][rg * 4];
                    *(float4*)(dst + rg * 8) = make_float4(yp[0], yp[1], yp[2], yp[3]);
                }
            }
        }
}

// ---------- global mean pool ----------
__global__ void k_pool(const float* __restrict__ y, const int* __restrict__ batch,
                       float* __restrict__ pooled) {
    int b = blockIdx.x;
    int t = threadIdx.x;
    int ch = t & 63, r = t >> 6;
    int lo = 0, hi = NN;
    while (lo < hi) { int mid = (lo + hi) >> 1; if (batch[mid] < b) lo = mid + 1; else hi = mid; }
    int st = lo;
    hi = NN;
    while (lo < hi) { int mid = (lo + hi) >> 1; if (batch[mid] < b + 1) lo = mid + 1; else hi = mid; }
    int en = lo;
    float s = 0.f;
    for (int i = st + r; i < en; i += 4) s += y[(size_t)i * 64 + ch];
    __shared__ float red[256];
    red[t] = s;
    __syncthreads();
    if (t < 64) {
        float tot = red[t] + red[t + 64] + red[t + 128] + red[t + 192];
        int cnt = en - st; if (cnt < 1) cnt = 1;
        pooled[b * 64 + t] = tot / (float)cnt;
    }
}

// ---------- final fc ----------
__global__ void k_fc(const float* __restrict__ pooled, const float* __restrict__ fcw,
                     const float* __restrict__ fcb, float* __restrict__ out) {
    int tid = blockIdx.x * 256 + threadIdx.x;
    if (tid >= NG * 33) return;
    int g = tid / 33, o = tid - g * 33;
    const float* p = pooled + g * 64;
    const float* w = fcw + o * 64;
    float a0 = 0.f, a1 = 0.f, a2 = 0.f, a3 = 0.f;
#pragma unroll
    for (int k = 0; k < 16; k++) {
        a0 = fmaf(p[4 * k], w[4 * k], a0);
        a1 = fmaf(p[4 * k + 1], w[4 * k + 1], a1);
        a2 = fmaf(p[4 * k + 2], w[4 * k + 2], a2);
        a3 = fmaf(p[4 * k + 3], w[4 * k + 3], a3);
    }
    out[tid] = fcb[o] + (a0 + a1) + (a2 + a3);
}

extern "C" void kernel_launch(void* const* d_in, const int* in_sizes, int n_in,
                              void* d_out, int out_size, void* d_ws, size_t ws_size,
                              hipStream_t stream) {
    (void)in_sizes; (void)n_in; (void)out_size; (void)ws_size;
    char* ws = (char*)d_ws;
    size_t o = 0;
    auto A = [&](size_t b) { size_t r = o; o += (b + 255) & ~(size_t)255; return r; };
    _Float16* h1p = (_Float16*)(ws + A((size_t)NN * 128 * 2));
    _Float16* h2h = (_Float16*)(ws + A((size_t)NN * 64 * 2));
    _Float16* g1h = (_Float16*)(ws + A((size_t)NN * 128 * 2));
    float* f_g2  = (float*)(ws + A((size_t)NN * 64 * 4));
    float* f_asp = (float*)(ws + A((size_t)NN * 4 * 4));
    float* f_ad1 = (float*)(ws + A((size_t)NN * 4 * 4));
    float* f_as2 = (float*)(ws + A((size_t)NN * 4 * 4));
    float* f_ad2 = (float*)(ws + A((size_t)NN * 4 * 4));
    int* i_off   = (int*)(ws + A((size_t)(NN + 1) * 4));
    int* i_cur   = (int*)(ws + A((size_t)NN * 4));
    int* i_deg   = (int*)(ws + A((size_t)NN * 4));
    int* i_bsum  = (int*)(ws + A((size_t)1024 * 4));
    int* i_srcs  = (int*)(ws + A((size_t)ETOT * 4));
    float* f_Mt  = (float*)(ws + A((size_t)6 * 4096 * 4));
    float* f_fb  = (float*)(ws + A((size_t)6 * 64 * 4));
    float* f_f1t = (float*)(ws + A((size_t)4 * 16384 * 4));
    float* f_f2t = (float*)(ws + A((size_t)4 * 16384 * 4));
    _Float16* f_apk = (_Float16*)(ws + A((size_t)APK_TOT * 2));
    _Float16* apw2  = (_Float16*)(ws + A((size_t)8192 * 2));
    float* f_pool= (float*)(ws + A((size_t)NG * 64 * 4));

    const float* x   = (const float*)d_in[0];
    const int* ei    = (const int*)d_in[1];
    const int* batch = (const int*)d_in[2];
    #define F32(i) ((const float*)d_in[i])

    hipMemsetAsync(i_deg, 0, (size_t)NN * 4, stream);
    k_h1<<<NN * 64 / 256, 256, 0, stream>>>(x, F32(3), F32(4), F32(5), F32(6), F32(7),
                                            h1p, f_asp, f_ad1);
    k_count<<<8 * 128, 256, 0, stream>>>(ei, i_deg);
    k_scan1<<<98, 1024, 0, stream>>>(i_deg, i_off, i_bsum);
    k_scan2<<<1, 128, 0, stream>>>(i_bsum);
    k_scan3<<<98, 1024, 0, stream>>>(i_off, i_bsum, i_cur);
    k_scatter<<<8 * 128, 256, 0, stream>>>(ei, i_cur, i_srcs);
    k_gat1<<<NN * 64 / 256, 256, 0, stream>>>(i_off, i_srcs, f_asp, f_ad1, h1p, F32(8), g1h);
    k_wpack<<<32, 256, 0, stream>>>(F32(9), apw2);
    k_h2m<<<(NN / 32 + 3) / 4, 256, 0, stream>>>(g1h, apw2, h2h);
    k_att2<<<(NN * 4 + 255) / 256, 256, 0, stream>>>(h2h, F32(10), F32(11), f_as2, f_ad2);
    k_gat2<<<NN * 64 / 256, 256, 0, stream>>>(i_off, i_srcs, f_as2, f_ad2, h2h, F32(12), f_g2);
    k_fuse<<<24576 / 256, 256, 0, stream>>>(F32(13), F32(14), F32(15), F32(16),
                                            F32(25), F32(26), F32(27), F32(28),
                                            F32(29), F32(30), F32(31), F32(32),
                                            f_Mt, f_fb);
    k_f1t<<<65536 / 256, 256, 0, stream>>>(F32(17), F32(33), f_f1t);
    k_f2t<<<65536 / 256, 256, 0, stream>>>(F32(19), F32(35), f_f2t);
    k_apack<<<APK_TOT / 256, 256, 0, stream>>>(f_Mt, f_f1t, f_f2t, f_apk);
    XQ Q;
    Q.apk = f_apk; Q.fb = f_fb;
    Q.ef1b = F32(18); Q.ef2b = F32(20);
    Q.df1b = F32(34); Q.df2b = F32(36);
    Q.el1g = F32(21); Q.el1b = F32(22); Q.el2g = F32(23); Q.el2b = F32(24);
    Q.dl1g = F32(37); Q.dl1b = F32(38); Q.dl2g = F32(39); Q.dl2b = F32(40);
    Q.dl3g = F32(41); Q.dl3b = F32(42);
    k_xform<<<(NN + 255) / 256, 256, 0, stream>>>(f_g2, Q);
    k_pool<<<NG, 256, 0, stream>>>(f_g2, batch, f_pool);
    k_fc<<<(NG * 33 + 255) / 256, 256, 0, stream>>>(f_pool, F32(43), F32(44), (float*)d_out);
    #undef F32
}